// Round 7
// baseline (203.064 us; speedup 1.0000x reference)
//
#include <hip/hip_runtime.h>
#include <math.h>

#define TOKENS 4096
#define DMODEL 768
#define NHEADS 12
#define HDIM   64
#define QKV_N  2304          // 3*DMODEL
#define ATTN_SCALE 0.125f    // HDIM^-0.5
// fold log2(e) into Q so softmax uses v_exp_f32 (2^x) directly
#define QSCALE_LOG2E (0.125f * 1.44269504088896340736f)

typedef __attribute__((ext_vector_type(8))) short bf16x8;   // 8 bf16 = 4 VGPRs
typedef __attribute__((ext_vector_type(4))) float floatx4;

__device__ __forceinline__ ushort f2bf(float f) {
    union { float f; unsigned u; } cv; cv.f = f;
    unsigned u = cv.u;
    u += 0x7fffu + ((u >> 16) & 1u);   // round-to-nearest-even
    return (ushort)(u >> 16);
}

// pack two fp32 -> two bf16 (RNE) in one dword via v_cvt_pk_bf16_f32
__device__ __forceinline__ unsigned cvt_pk_bf16(float a, float b) {
    unsigned r;
    asm("v_cvt_pk_bf16_f32 %0, %1, %2" : "=v"(r) : "v"(a), "v"(b));
    return r;
}

// async 16B global->LDS (lane i lands at ldsbase + i*16)
__device__ __forceinline__ void gl2lds16(const ushort* g, ushort* l) {
    __builtin_amdgcn_global_load_lds(
        (const __attribute__((address_space(1))) void*)g,
        (__attribute__((address_space(3))) void*)l, 16, 0, 0);
}

// fragment read (64-ushort rows): logical chunk c of row r at phys (c ^ (r&7))
__device__ __forceinline__ bf16x8 frag(const ushort* ls, int row, int chunk) {
    return *(const bf16x8*)(ls + row * 64 + ((chunk ^ (row & 7)) * 8));
}

// ---------------------------------------------------------------------------
// fp32 -> bf16 elementwise (x)
// ---------------------------------------------------------------------------
__global__ __launch_bounds__(256) void cvt_bf16_kernel(
    const float* __restrict__ in, ushort* __restrict__ out, int n4)
{
    const int i = blockIdx.x * 256 + threadIdx.x;
    if (i < n4) {
        const float4 v = ((const float4*)in)[i];
        ushort4 h;
        h.x = f2bf(v.x); h.y = f2bf(v.y); h.z = f2bf(v.z); h.w = f2bf(v.w);
        ((ushort4*)out)[i] = h;
    }
}

// ---------------------------------------------------------------------------
// fp32 [R][C] -> bf16 [C][R] transpose-convert (weights -> B^T operand layout)
// ---------------------------------------------------------------------------
__global__ __launch_bounds__(256) void transpose_cvt_kernel(
    const float* __restrict__ in, ushort* __restrict__ out, int R, int C)
{
    __shared__ ushort tile[32][33];
    const int tx  = threadIdx.x & 31;
    const int ty8 = threadIdx.x >> 5;           // 0..7
    const int c0 = blockIdx.x * 32;
    const int r0 = blockIdx.y * 32;
    #pragma unroll
    for (int p = 0; p < 4; ++p) {
        const int r = ty8 + p * 8;
        tile[r][tx] = f2bf(in[(size_t)(r0 + r) * C + c0 + tx]);
    }
    __syncthreads();
    #pragma unroll
    for (int p = 0; p < 4; ++p) {
        const int c = ty8 + p * 8;
        out[(size_t)(c0 + c) * R + r0 + tx] = tile[tx][c];
    }
}

// ---------------------------------------------------------------------------
// MFMA GEMM body (m97 recipe): 128 x (NT*32) tile, BK=64, 4 waves 2x2.
// ---------------------------------------------------------------------------
template<int NT>
__device__ __forceinline__ void gemm_body_async(
    const ushort* __restrict__ A, const ushort* __restrict__ Bt, int K,
    int m0, int n0, floatx4 acc[4][NT], ushort* ls)
{
    ushort* lsA = ls;
    ushort* lsB = ls + 8192;

    const int tid  = threadIdx.x;
    const int lane = tid & 63;
    const int wave = tid >> 6;
    const int wm = wave >> 1, wn = wave & 1;
    const int quad = lane >> 4, l16 = lane & 15;

    const int lrow = lane >> 3;          // 0..7
    const int csw  = ((lane & 7) ^ lrow) * 8;   // swizzled global chunk (ushorts)

    const ushort* gA = A  + (size_t)(m0 + wave * 32 + lrow) * K + csw;
    const ushort* gB = Bt + (size_t)(n0 + wave * NT * 8 + lrow) * K + csw;
    ushort* lA = lsA + (wave * 32) * 64;
    ushort* lB = lsB + (wave * NT * 8) * 64;

    for (int k0 = 0; k0 < K; k0 += 64) {
        __syncthreads();
        #pragma unroll
        for (int p = 0; p < 4; ++p)
            gl2lds16(gA + (size_t)p * 8 * K + k0, lA + p * 8 * 64);
        #pragma unroll
        for (int p = 0; p < NT; ++p)
            gl2lds16(gB + (size_t)p * 8 * K + k0, lB + p * 8 * 64);
        __syncthreads();

        #pragma unroll
        for (int ks = 0; ks < 2; ++ks) {
            bf16x8 af[4], bfr[NT];
            #pragma unroll
            for (int mt = 0; mt < 4; ++mt)
                af[mt] = frag(lsA, wm * 64 + mt * 16 + l16, ks * 4 + quad);
            #pragma unroll
            for (int nt = 0; nt < NT; ++nt)
                bfr[nt] = frag(lsB, wn * NT * 16 + nt * 16 + l16, ks * 4 + quad);
            #pragma unroll
            for (int mt = 0; mt < 4; ++mt)
                #pragma unroll
                for (int nt = 0; nt < NT; ++nt)
                    acc[mt][nt] = __builtin_amdgcn_mfma_f32_16x16x32_bf16(
                        af[mt], bfr[nt], acc[mt][nt], 0, 0, 0);
        }
    }
}

// ---------------------------------------------------------------------------
// qkv GEMM: 128x128 tiles. Epilogue re-tiles through LDS (stride 136).
// ---------------------------------------------------------------------------
__global__ __launch_bounds__(256) void gemm_qkv_mfma(
    const ushort* __restrict__ Xb, const ushort* __restrict__ Wt,
    ushort* __restrict__ Qb, ushort* __restrict__ Kb, ushort* __restrict__ Vt)
{
    __shared__ __align__(16) ushort ls[16384];   // 32 KB: GEMM tiles + retile
    const int m0 = blockIdx.y * 128;
    const int n0 = blockIdx.x * 128;

    floatx4 acc[4][4] = {};
    gemm_body_async<4>(Xb, Wt, DMODEL, m0, n0, acc, ls);

    const int tid  = threadIdx.x;
    const int lane = tid & 63;
    const int wave = tid >> 6;
    const int wm = wave >> 1, wn = wave & 1;
    const int quad = lane >> 4, l16 = lane & 15;

    if (n0 < 2 * DMODEL) {
        // ---- Q or K: two passes over 64-row halves ----
        const float scale = (n0 < DMODEL) ? QSCALE_LOG2E : 1.0f;
        ushort* outp = (n0 < DMODEL) ? Qb : Kb;
        const int colg = (n0 < DMODEL) ? n0 : n0 - DMODEL;
        #pragma unroll
        for (int p = 0; p < 2; ++p) {
            __syncthreads();
            if (wm == p) {
                #pragma unroll
                for (int mt = 0; mt < 4; ++mt)
                    #pragma unroll
                    for (int nt = 0; nt < 4; ++nt) {
                        const int row = mt * 16 + quad * 4;
                        const int col = wn * 64 + nt * 16 + l16;
                        #pragma unroll
                        for (int r = 0; r < 4; ++r)
                            ls[(row + r) * 136 + col] = f2bf(acc[mt][nt][r] * scale);
                    }
            }
            __syncthreads();
            #pragma unroll
            for (int p2 = 0; p2 < 4; ++p2) {
                const int row = (tid >> 4) + p2 * 16;
                const int c8  = (tid & 15) * 8;
                *(uint4*)(outp + (size_t)(m0 + p * 64 + row) * DMODEL + colg + c8) =
                    *(const uint4*)(ls + row * 136 + c8);
            }
        }
    } else {
        // ---- V transposed: two passes over 64-hd halves ----
        const int hd0 = n0 - 2 * DMODEL;
        #pragma unroll
        for (int p = 0; p < 2; ++p) {
            __syncthreads();
            if (wn == p) {
                #pragma unroll
                for (int mt = 0; mt < 4; ++mt)
                    #pragma unroll
                    for (int nt = 0; nt < 4; ++nt) {
                        const int hd  = nt * 16 + l16;
                        const int tok = wm * 64 + mt * 16 + quad * 4;
                        #pragma unroll
                        for (int r = 0; r < 4; ++r)
                            ls[hd * 136 + tok + r] = f2bf(acc[mt][nt][r]);
                    }
            }
            __syncthreads();
            #pragma unroll
            for (int p2 = 0; p2 < 4; ++p2) {
                const int row = (tid >> 4) + p2 * 16;    // local hd
                const int c8  = (tid & 15) * 8;          // token chunk
                *(uint4*)(Vt + (size_t)(hd0 + p * 64 + row) * TOKENS + m0 + c8) =
                    *(const uint4*)(ls + row * 136 + c8);
            }
        }
    }
}

// ---------------------------------------------------------------------------
// proj GEMM: 128x64 tiles (grid 384), direct fp32 stores (full 64B sectors).
// ---------------------------------------------------------------------------
__global__ __launch_bounds__(256) void gemm_proj_mfma(
    const ushort* __restrict__ Ab, const ushort* __restrict__ Wt,
    const float* __restrict__ bias, float* __restrict__ out)
{
    __shared__ __align__(16) ushort ls[12288];   // 16 KB A + 8 KB B
    const int m0 = blockIdx.y * 128;
    const int n0 = blockIdx.x * 64;

    floatx4 acc[4][2] = {};
    gemm_body_async<2>(Ab, Wt, DMODEL, m0, n0, acc, ls);

    const int lane = threadIdx.x & 63;
    const int wave = threadIdx.x >> 6;
    const int wm = wave >> 1, wn = wave & 1;
    const int quad = lane >> 4, l16 = lane & 15;
    const int row0 = m0 + wm * 64 + quad * 4;
    const int col0 = n0 + wn * 32;

    #pragma unroll
    for (int nt = 0; nt < 2; ++nt) {
        const int col = col0 + nt * 16 + l16;
        const float bv = bias[col];
        #pragma unroll
        for (int mt = 0; mt < 4; ++mt)
            #pragma unroll
            for (int r = 0; r < 4; ++r)
                out[(size_t)(row0 + mt * 16 + r) * DMODEL + col] =
                    acc[mt][nt][r] + bv;
    }
}

// ---------------------------------------------------------------------------
// MFMA flash attention v8 — v7 + XCD head-locality swizzle + V bank fix.
//
// r6 post-mortem: occupancy lever dead (r3: 2x occ -> worse; r6: +64% occ ->
// -6%); wall = per-wave latency. Two MEASURED wrongs remained:
//   (a) FETCH 53MB vs ~19-25MB ideal: (i0,h) grid round-robins XCDs x-major
//       -> every XCD touches all 12 heads (12MB KV >> 4MB L2) -> thrash +
//       L3-latency KV fetches. Fix: T1 bijective swizzle w=(lin&7)*96+lin>>3
//       (768 = 8 XCDs x 96): each XCD serves <=2 heads (2MB <= L2).
//   (b) 10M bank-conflict cycles (21% of CU time): V b64 read at
//       row*32B + quad*8B -> bank-pair 8*(row&3)+2*quad -> lanes l16,l16+4,
//       l16+8,l16+12 collide = 4-way (1.58x). Fix: 1-bit PAIR swizzle at
//       16B DMA granularity (rule #21 both-sides): logical token-pair l of
//       d-row r stored at physical pair l^((r>>2)&1); staging pre-applies
//       ((lane&1)^((lane>>3)&1)); read uses loop-invariant vo. 4-way->2-way
//       (2-way is free, m136).
// Everything else identical to r6 (barrier-free wave-private, 16-key chunks,
// even/odd P pairing, counted vmcnt(4), setprio, 51.5KB LDS, 3 blocks/CU).
// ---------------------------------------------------------------------------
__global__ __launch_bounds__(256, 3) void attn_mfma_kernel(
    const ushort* __restrict__ Qb, const ushort* __restrict__ Kb,
    const ushort* __restrict__ Vt, ushort* __restrict__ attn_out)
{
    // main loop: 4 waves x 6144 ushorts (K0,K1 @0,1024; V0..V3 @2048+s*1024)
    // epilogue:  3 x [64][66] f32 + 192 f32 = 12864 floats = 25728 ushorts
    __shared__ __align__(16) ushort lds[25728];   // 51.5 KB

    const int tid  = threadIdx.x;
    const int wave = tid >> 6;
    const int lane = tid & 63;
    const int quad = lane >> 4;
    const int l16  = lane & 15;

    // XCD head-locality swizzle (T1, bijective: 768 = 8 XCDs x 96 blocks)
    const int lin = blockIdx.x + blockIdx.y * 64;    // dispatch-linear id
    const int wsw = (lin & 7) * 96 + (lin >> 3);     // chunked per-XCD remap
    const int h   = wsw >> 6;                        // head 0..11
    const int i0  = (wsw & 63) * 64;                 // query-tile base

    // Q fragments: all 4 q-tiles register-resident (B-operand: col=l16)
    bf16x8 qf[4][2];
    #pragma unroll
    for (int jt = 0; jt < 4; ++jt) {
        const ushort* qb = Qb + (size_t)(i0 + jt * 16 + l16) * DMODEL + h * HDIM;
        qf[jt][0] = *(const bf16x8*)(qb + quad * 8);
        qf[jt][1] = *(const bf16x8*)(qb + 32 + quad * 8);
    }

    bf16x8 ones;
    #pragma unroll
    for (int i = 0; i < 8; ++i) ones[i] = (short)0x3F80;   // bf16 1.0

    floatx4 O[4][4] = {};    // [q-tile][d-tile], partial over this wave's keys
    floatx4 Ol[4]   = {};    // [q-tile] partial row-sums

    ushort* wls = lds + wave * 6144;                 // private region

    // K staging source (3-bit XOR chunk pre-swizzle; wave's key = t*64+wave*16+row)
    const int lrow8 = lane >> 3;                     // 0..7
    const int csw8  = ((lane & 7) ^ lrow8) * 8;
    const ushort* gK0 = Kb + (size_t)(wave * 16 + lrow8) * DMODEL + h * HDIM + csw8;
    const ushort* gK1 = gK0 + (size_t)8 * DMODEL;

    // V staging source: lane -> d=lane>>1, PHYSICAL tok-pair=lane&1 holds
    // LOGICAL pair (lane&1)^((d>>2)&1) = (lane&1)^((lane>>3)&1)
    const ushort* gV0 = Vt + (size_t)(h * HDIM + (lane >> 1)) * TOKENS
                           + wave * 16 + (((lane & 1) ^ ((lane >> 3) & 1)) * 8);
    const ushort* gV1 = gV0 + (size_t)32 * TOKENS;

    // V read offset (loop-invariant): logical pair quad>>1 of row nt*16+l16
    // sits at physical pair (quad>>1)^((l16>>2)&1); 8B half = quad&1
    const int vo = ((quad >> 1) ^ ((l16 >> 2) & 1)) * 8 + (quad & 1) * 4;

    // persistent P operand, packed across an even/odd chunk pair
    union { bf16x8 v; unsigned u[4]; } pa[4];

    // prologue: stage t=0 (K -> buf0, V -> slot0); 4 DMA outstanding
    gl2lds16(gK0, wls);
    gl2lds16(gK1, wls + 512);
    gl2lds16(gV0, wls + 2048);
    gl2lds16(gV1, wls + 2048 + 512);

    for (int u = 0; u < 32; ++u) {                   // pair u: t0=2u, t1=2u+1
        const int s0 = (u & 1) << 1;                 // V slot of t0 (0 or 2)
        ushort* Kc0 = wls;
        ushort* Kc1 = wls + 1024;
        ushort* V0  = wls + 2048 + s0 * 1024;
        ushort* V1  = wls + 2048 + (s0 + 1) * 1024;
        ushort* Vn  = wls + 2048 + ((s0 + 2) & 3) * 1024;

        // ======== t0 = 2u (even): prefetch t1, QK on Kc0 -> pa low half ====
        {
            const size_t t1 = (size_t)(2 * u + 1) * 64;
            gl2lds16(gK0 + t1 * DMODEL, Kc1);
            gl2lds16(gK1 + t1 * DMODEL, Kc1 + 512);
            gl2lds16(gV0 + t1, V1);
            gl2lds16(gV1 + t1, V1 + 512);
        }
        asm volatile("s_waitcnt vmcnt(4)" ::: "memory");   // t0's 4 DMA done
        __builtin_amdgcn_sched_barrier(0);

        {
            const bf16x8 a0 = frag(Kc0, l16, quad);
            const bf16x8 a1 = frag(Kc0, l16, 4 + quad);
            __builtin_amdgcn_s_setprio(1);
            #pragma unroll
            for (int jt = 0; jt < 4; ++jt) {
                floatx4 s = {0.f, 0.f, 0.f, 0.f};
                s = __builtin_amdgcn_mfma_f32_16x16x32_bf16(a0, qf[jt][0], s, 0, 0, 0);
                s = __builtin_amdgcn_mfma_f32_16x16x32_bf16(a1, qf[jt][1], s, 0, 0, 0);
                pa[jt].u[0] = cvt_pk_bf16(__builtin_amdgcn_exp2f(s[0]),
                                          __builtin_amdgcn_exp2f(s[1]));
                pa[jt].u[1] = cvt_pk_bf16(__builtin_amdgcn_exp2f(s[2]),
                                          __builtin_amdgcn_exp2f(s[3]));
            }
            __builtin_amdgcn_s_setprio(0);
        }

        // ======== t1 = 2u+1 (odd): prefetch next t0, QK on Kc1 -> pa high,
        //          then PV + Ol over the 32-key pair ========================
        if (u < 31) {
            const size_t t2 = (size_t)(2 * u + 2) * 64;
            gl2lds16(gK0 + t2 * DMODEL, Kc0);
            gl2lds16(gK1 + t2 * DMODEL, Kc0 + 512);
            gl2lds16(gV0 + t2, Vn);
            gl2lds16(gV1 + t2, Vn + 512);
            asm volatile("s_waitcnt vmcnt(4)" ::: "memory");  // t1's 4 DMA done
        } else {
            asm volatile("s_waitcnt vmcnt(0)" ::: "memory");
        }
        __builtin_amdgcn_sched_barrier(0);

        {
            const bf16x8 a0 = frag(Kc1, l16, quad);
            const bf16x8 a1 = frag(Kc1, l16, 4 + quad);
            __builtin_amdgcn_s_setprio(1);
            #pragma unroll
            for (int jt = 0; jt < 4; ++jt) {
                floatx4 s = {0.f, 0.f, 0.f, 0.f};
                s = __builtin_amdgcn_mfma_f32_16x16x32_bf16(a0, qf[jt][0], s, 0, 0, 0);
                s = __builtin_amdgcn_mfma_f32_16x16x32_bf16(a1, qf[jt][1], s, 0, 0, 0);
                pa[jt].u[2] = cvt_pk_bf16(__builtin_amdgcn_exp2f(s[0]),
                                          __builtin_amdgcn_exp2f(s[1]));
                pa[jt].u[3] = cvt_pk_bf16(__builtin_amdgcn_exp2f(s[2]),
                                          __builtin_amdgcn_exp2f(s[3]));
            }
            __builtin_amdgcn_s_setprio(0);
        }

        __builtin_amdgcn_s_setprio(1);
        #pragma unroll
        for (int nt = 0; nt < 4; ++nt) {
            const int ro = (nt * 16 + l16) * 16 + vo;   // pair-swizzled slot
            union { bf16x8 v; uint2 d[2]; } vu;
            vu.d[0] = *(const uint2*)(V0 + ro);   // even-chunk tokens (k-slots 0-3)
            vu.d[1] = *(const uint2*)(V1 + ro);   // odd-chunk tokens  (k-slots 4-7)
            #pragma unroll
            for (int jt = 0; jt < 4; ++jt)
                O[jt][nt] = __builtin_amdgcn_mfma_f32_16x16x32_bf16(
                    pa[jt].v, vu.v, O[jt][nt], 0, 0, 0);
        }
        #pragma unroll
        for (int jt = 0; jt < 4; ++jt)
            Ol[jt] = __builtin_amdgcn_mfma_f32_16x16x32_bf16(
                pa[jt].v, ones, Ol[jt], 0, 0, 0);
        __builtin_amdgcn_s_setprio(0);
    }

    // ---- cross-wave reduction + store (proven 4-way epilogue) ----
    __syncthreads();                       // all compute done, LDS reusable
    float* Of  = (float*)lds;              // 3 regions of [64][66] f32
    float* Olf = ((float*)lds) + 3 * 64 * 66;   // 3 x [64] f32
    if (wave != 0) {
        const int rg = (wave - 1) * 64 * 66;
        #pragma unroll
        for (int jt = 0; jt < 4; ++jt) {
            #pragma unroll
            for (int nt = 0; nt < 4; ++nt)
                #pragma unroll
                for (int r = 0; r < 4; ++r)
                    Of[rg + (jt * 16 + quad * 4 + r) * 66 + nt * 16 + l16] = O[jt][nt][r];
            if (l16 == 0) {
                #pragma unroll
                for (int r = 0; r < 4; ++r)
                    Olf[(wave - 1) * 64 + jt * 16 + quad * 4 + r] = Ol[jt][r];
            }
        }
    }
    __syncthreads();
    if (wave == 0) {
        #pragma unroll
        for (int jt = 0; jt < 4; ++jt) {
            const int qr = jt * 16 + quad * 4;
            float linv[4];
            #pragma unroll
            for (int r = 0; r < 4; ++r) {
                const float l = Ol[jt][r] + Olf[qr + r] + Olf[64 + qr + r]
                              + Olf[128 + qr + r];
                linv[r] = __builtin_amdgcn_rcpf(l);
            }
            #pragma unroll
            for (int nt = 0; nt < 4; ++nt) {
                const int d = h * HDIM + nt * 16 + l16;
                #pragma unroll
                for (int r = 0; r < 4; ++r) {
                    const float o = O[jt][nt][r]
                        + Of[(qr + r) * 66 + nt * 16 + l16]
                        + Of[64 * 66 + (qr + r) * 66 + nt * 16 + l16]
                        + Of[2 * 64 * 66 + (qr + r) * 66 + nt * 16 + l16];
                    attn_out[(size_t)(i0 + qr + r) * DMODEL + d] = f2bf(o * linv[r]);
                }
            }
        }
    }
}

// ---------------------------------------------------------------------------
extern "C" void kernel_launch(void* const* d_in, const int* in_sizes, int n_in,
                              void* d_out, int out_size, void* d_ws, size_t ws_size,
                              hipStream_t stream)
{
    const float* x     = (const float*)d_in[0];
    const float* Wqkv  = (const float*)d_in[1];
    const float* Wproj = (const float*)d_in[2];
    const float* bproj = (const float*)d_in[3];
    float* out = (float*)d_out;

    ushort* Xb     = (ushort*)d_ws;                          // [4096][768]
    ushort* WqkvT  = Xb    + (size_t)TOKENS * DMODEL;        // [2304][768]
    ushort* WprojT = WqkvT + (size_t)QKV_N * DMODEL;         // [768][768]
    ushort* Qb     = WprojT + (size_t)DMODEL * DMODEL;       // [4096][768]
    ushort* Kb     = Qb    + (size_t)TOKENS * DMODEL;        // [4096][768]
    ushort* Vt     = Kb    + (size_t)TOKENS * DMODEL;        // [768][4096]
    ushort* attn   = Vt    + (size_t)TOKENS * DMODEL;        // [4096][768]

    cvt_bf16_kernel<<<dim3(TOKENS * DMODEL / 4 / 256), 256, 0, stream>>>(
        x, Xb, TOKENS * DMODEL / 4);
    transpose_cvt_kernel<<<dim3(QKV_N / 32, DMODEL / 32), 256, 0, stream>>>(
        Wqkv, WqkvT, DMODEL, QKV_N);
    transpose_cvt_kernel<<<dim3(DMODEL / 32, DMODEL / 32), 256, 0, stream>>>(
        Wproj, WprojT, DMODEL, DMODEL);

    gemm_qkv_mfma<<<dim3(QKV_N / 128, TOKENS / 128), 256, 0, stream>>>(
        Xb, WqkvT, Qb, Kb, Vt);

    attn_mfma_kernel<<<dim3(TOKENS / 64, NHEADS), 256, 0, stream>>>(
        Qb, Kb, Vt, attn);

    gemm_proj_mfma<<<dim3(DMODEL / 64, TOKENS / 128), 256, 0, stream>>>(
        attn, WprojT, bproj, out);
}

// Round 9
// 196.299 us; speedup vs baseline: 1.0345x; 1.0345x over previous
//
#include <hip/hip_runtime.h>
#include <math.h>

#define TOKENS 4096
#define DMODEL 768
#define NHEADS 12
#define HDIM   64
#define QKV_N  2304          // 3*DMODEL
#define ATTN_SCALE 0.125f    // HDIM^-0.5
// fold log2(e) into Q so softmax uses v_exp_f32 (2^x) directly
#define QSCALE_LOG2E (0.125f * 1.44269504088896340736f)

typedef __attribute__((ext_vector_type(8))) short bf16x8;   // 8 bf16 = 4 VGPRs
typedef __attribute__((ext_vector_type(4))) float floatx4;

__device__ __forceinline__ ushort f2bf(float f) {
    union { float f; unsigned u; } cv; cv.f = f;
    unsigned u = cv.u;
    u += 0x7fffu + ((u >> 16) & 1u);   // round-to-nearest-even
    return (ushort)(u >> 16);
}

// pack two fp32 -> two bf16 (RNE) in one dword via v_cvt_pk_bf16_f32
__device__ __forceinline__ unsigned cvt_pk_bf16(float a, float b) {
    unsigned r;
    asm("v_cvt_pk_bf16_f32 %0, %1, %2" : "=v"(r) : "v"(a), "v"(b));
    return r;
}

// async 16B global->LDS (lane i lands at ldsbase + i*16)
__device__ __forceinline__ void gl2lds16(const ushort* g, ushort* l) {
    __builtin_amdgcn_global_load_lds(
        (const __attribute__((address_space(1))) void*)g,
        (__attribute__((address_space(3))) void*)l, 16, 0, 0);
}

// fragment read (64-ushort rows): logical chunk c of row r at phys (c ^ (r&7))
__device__ __forceinline__ bf16x8 frag(const ushort* ls, int row, int chunk) {
    return *(const bf16x8*)(ls + row * 64 + ((chunk ^ (row & 7)) * 8));
}

// ---------------------------------------------------------------------------
// fused prep: fp32->bf16 cvt of x  +  both weight transpose-converts.
// One launch instead of three.
// ---------------------------------------------------------------------------
__global__ __launch_bounds__(256) void prep_kernel(
    const float* __restrict__ x, const float* __restrict__ Wqkv,
    const float* __restrict__ Wproj, ushort* __restrict__ Xb,
    ushort* __restrict__ WqkvT, ushort* __restrict__ WprojT)
{
    __shared__ ushort tile[32][33];
    const int bid = blockIdx.x;
    const int tid = threadIdx.x;

    if (bid < 3072) {                     // ---- cvt x: 3072*256*4 = 4096*768
        const int i = bid * 256 + tid;
        const float4 v = ((const float4*)x)[i];
        ushort4 h;
        h.x = f2bf(v.x); h.y = f2bf(v.y); h.z = f2bf(v.z); h.w = f2bf(v.w);
        ((ushort4*)Xb)[i] = h;
        return;
    }

    const float* in; ushort* out; int C, bx, by;
    if (bid < 3072 + 1728) {              // ---- Wqkv [768][2304] -> [2304][768]
        const int b = bid - 3072;
        in = Wqkv; out = WqkvT; C = QKV_N;
        bx = b % 72; by = b / 72;
    } else {                              // ---- Wproj [768][768] -> [768][768]
        const int b = bid - 4800;
        in = Wproj; out = WprojT; C = DMODEL;
        bx = b % 24; by = b / 24;
    }
    const int R  = DMODEL;
    const int tx = tid & 31;
    const int ty8 = tid >> 5;             // 0..7
    const int c0 = bx * 32;
    const int r0 = by * 32;
    #pragma unroll
    for (int p = 0; p < 4; ++p) {
        const int r = ty8 + p * 8;
        tile[r][tx] = f2bf(in[(size_t)(r0 + r) * C + c0 + tx]);
    }
    __syncthreads();
    #pragma unroll
    for (int p = 0; p < 4; ++p) {
        const int c = ty8 + p * 8;
        out[(size_t)(c0 + c) * R + r0 + tx] = tile[tx][c];
    }
}

// ---------------------------------------------------------------------------
// MFMA GEMM body (m97 recipe): 128 x (NT*32) tile, BK=64, 4 waves 2x2.
// ---------------------------------------------------------------------------
template<int NT>
__device__ __forceinline__ void gemm_body_async(
    const ushort* __restrict__ A, const ushort* __restrict__ Bt, int K,
    int m0, int n0, floatx4 acc[4][NT], ushort* ls)
{
    ushort* lsA = ls;
    ushort* lsB = ls + 8192;

    const int tid  = threadIdx.x;
    const int lane = tid & 63;
    const int wave = tid >> 6;
    const int wm = wave >> 1, wn = wave & 1;
    const int quad = lane >> 4, l16 = lane & 15;

    const int lrow = lane >> 3;          // 0..7
    const int csw  = ((lane & 7) ^ lrow) * 8;   // swizzled global chunk (ushorts)

    const ushort* gA = A  + (size_t)(m0 + wave * 32 + lrow) * K + csw;
    const ushort* gB = Bt + (size_t)(n0 + wave * NT * 8 + lrow) * K + csw;
    ushort* lA = lsA + (wave * 32) * 64;
    ushort* lB = lsB + (wave * NT * 8) * 64;

    for (int k0 = 0; k0 < K; k0 += 64) {
        __syncthreads();
        #pragma unroll
        for (int p = 0; p < 4; ++p)
            gl2lds16(gA + (size_t)p * 8 * K + k0, lA + p * 8 * 64);
        #pragma unroll
        for (int p = 0; p < NT; ++p)
            gl2lds16(gB + (size_t)p * 8 * K + k0, lB + p * 8 * 64);
        __syncthreads();

        #pragma unroll
        for (int ks = 0; ks < 2; ++ks) {
            bf16x8 af[4], bfr[NT];
            #pragma unroll
            for (int mt = 0; mt < 4; ++mt)
                af[mt] = frag(lsA, wm * 64 + mt * 16 + l16, ks * 4 + quad);
            #pragma unroll
            for (int nt = 0; nt < NT; ++nt)
                bfr[nt] = frag(lsB, wn * NT * 16 + nt * 16 + l16, ks * 4 + quad);
            #pragma unroll
            for (int mt = 0; mt < 4; ++mt)
                #pragma unroll
                for (int nt = 0; nt < NT; ++nt)
                    acc[mt][nt] = __builtin_amdgcn_mfma_f32_16x16x32_bf16(
                        af[mt], bfr[nt], acc[mt][nt], 0, 0, 0);
        }
    }
}

// ---------------------------------------------------------------------------
// qkv GEMM: 128x128 tiles, XCD m-strip swizzle (576 = 8 XCDs x 72; each XCD
// owns 4 M-rows x all 18 N-tiles -> its B (3.5MB) + A panels fit its 4MB L2,
// repricing the per-iter vmcnt drains from L3 to L2 latency).
// ---------------------------------------------------------------------------
__global__ __launch_bounds__(256) void gemm_qkv_mfma(
    const ushort* __restrict__ Xb, const ushort* __restrict__ Wt,
    ushort* __restrict__ Qb, ushort* __restrict__ Kb, ushort* __restrict__ Vt)
{
    __shared__ __align__(16) ushort ls[16384];   // 32 KB: GEMM tiles + retile
    const int lin = blockIdx.x + blockIdx.y * 18;     // dispatch-linear id
    const int w   = (lin & 7) * 72 + (lin >> 3);      // bijective XCD chunking
    const int m0  = (w / 18) * 128;
    const int n0  = (w % 18) * 128;

    floatx4 acc[4][4] = {};
    gemm_body_async<4>(Xb, Wt, DMODEL, m0, n0, acc, ls);

    const int tid  = threadIdx.x;
    const int lane = tid & 63;
    const int wave = tid >> 6;
    const int wm = wave >> 1, wn = wave & 1;
    const int quad = lane >> 4, l16 = lane & 15;

    if (n0 < 2 * DMODEL) {
        // ---- Q or K: two passes over 64-row halves ----
        const float scale = (n0 < DMODEL) ? QSCALE_LOG2E : 1.0f;
        ushort* outp = (n0 < DMODEL) ? Qb : Kb;
        const int colg = (n0 < DMODEL) ? n0 : n0 - DMODEL;
        #pragma unroll
        for (int p = 0; p < 2; ++p) {
            __syncthreads();
            if (wm == p) {
                #pragma unroll
                for (int mt = 0; mt < 4; ++mt)
                    #pragma unroll
                    for (int nt = 0; nt < 4; ++nt) {
                        const int row = mt * 16 + quad * 4;
                        const int col = wn * 64 + nt * 16 + l16;
                        #pragma unroll
                        for (int r = 0; r < 4; ++r)
                            ls[(row + r) * 136 + col] = f2bf(acc[mt][nt][r] * scale);
                    }
            }
            __syncthreads();
            #pragma unroll
            for (int p2 = 0; p2 < 4; ++p2) {
                const int row = (tid >> 4) + p2 * 16;
                const int c8  = (tid & 15) * 8;
                *(uint4*)(outp + (size_t)(m0 + p * 64 + row) * DMODEL + colg + c8) =
                    *(const uint4*)(ls + row * 136 + c8);
            }
        }
    } else {
        // ---- V transposed: two passes over 64-hd halves ----
        const int hd0 = n0 - 2 * DMODEL;
        #pragma unroll
        for (int p = 0; p < 2; ++p) {
            __syncthreads();
            if (wn == p) {
                #pragma unroll
                for (int mt = 0; mt < 4; ++mt)
                    #pragma unroll
                    for (int nt = 0; nt < 4; ++nt) {
                        const int hd  = nt * 16 + l16;
                        const int tok = wm * 64 + mt * 16 + quad * 4;
                        #pragma unroll
                        for (int r = 0; r < 4; ++r)
                            ls[hd * 136 + tok + r] = f2bf(acc[mt][nt][r]);
                    }
            }
            __syncthreads();
            #pragma unroll
            for (int p2 = 0; p2 < 4; ++p2) {
                const int row = (tid >> 4) + p2 * 16;    // local hd
                const int c8  = (tid & 15) * 8;          // token chunk
                *(uint4*)(Vt + (size_t)(hd0 + p * 64 + row) * TOKENS + m0 + c8) =
                    *(const uint4*)(ls + row * 136 + c8);
            }
        }
    }
}

// ---------------------------------------------------------------------------
// proj GEMM: 128x64 tiles, XCD m-strip swizzle (384 = 8 x 48; 4 M-rows x
// all 12 N-tiles per XCD -> B 1.2MB + A panels L2-resident).
// ---------------------------------------------------------------------------
__global__ __launch_bounds__(256) void gemm_proj_mfma(
    const ushort* __restrict__ Ab, const ushort* __restrict__ Wt,
    const float* __restrict__ bias, float* __restrict__ out)
{
    __shared__ __align__(16) ushort ls[12288];   // 16 KB A + 8 KB B
    const int lin = blockIdx.x + blockIdx.y * 12;
    const int w   = (lin & 7) * 48 + (lin >> 3);
    const int m0  = (w / 12) * 128;
    const int n0  = (w % 12) * 64;

    floatx4 acc[4][2] = {};
    gemm_body_async<2>(Ab, Wt, DMODEL, m0, n0, acc, ls);

    const int lane = threadIdx.x & 63;
    const int wave = threadIdx.x >> 6;
    const int wm = wave >> 1, wn = wave & 1;
    const int quad = lane >> 4, l16 = lane & 15;
    const int row0 = m0 + wm * 64 + quad * 4;
    const int col0 = n0 + wn * 32;

    #pragma unroll
    for (int nt = 0; nt < 2; ++nt) {
        const int col = col0 + nt * 16 + l16;
        const float bv = bias[col];
        #pragma unroll
        for (int mt = 0; mt < 4; ++mt)
            #pragma unroll
            for (int r = 0; r < 4; ++r)
                out[(size_t)(row0 + mt * 16 + r) * DMODEL + col] =
                    acc[mt][nt][r] + bv;
    }
}

// ---------------------------------------------------------------------------
// MFMA flash attention — EXACT r7 kernel (harness-verified, 77.5us).
//
// r8 post-mortem: hoisting V reads across phases (+16 live VGPRs) and
// removing the sched_barrier(0) fences broke the counted-vmcnt contract
// (likely via scratch spill ops entering the vmcnt stream) -> absmax fail.
// SESSION RULE: counted-vmcnt kernels must not casually change register
// pressure / scheduling freedom; revalidate the count on any such edit.
// This is the r7 version verbatim: sched_barrier(0) after each waitcnt,
// V reads in the PV section, no cross-phase vu live range.
// ---------------------------------------------------------------------------
__global__ __launch_bounds__(256, 3) void attn_mfma_kernel(
    const ushort* __restrict__ Qb, const ushort* __restrict__ Kb,
    const ushort* __restrict__ Vt, ushort* __restrict__ attn_out)
{
    // main loop: 4 waves x 6144 ushorts (K0,K1 @0,1024; V0..V3 @2048+s*1024)
    // epilogue:  3 x [64][66] f32 + 192 f32 = 12864 floats = 25728 ushorts
    __shared__ __align__(16) ushort lds[25728];   // 51.5 KB

    const int tid  = threadIdx.x;
    const int wave = tid >> 6;
    const int lane = tid & 63;
    const int quad = lane >> 4;
    const int l16  = lane & 15;

    // XCD head-locality swizzle (bijective: 768 = 8 XCDs x 96 blocks)
    const int lin = blockIdx.x + blockIdx.y * 64;    // dispatch-linear id
    const int wsw = (lin & 7) * 96 + (lin >> 3);     // chunked per-XCD remap
    const int h   = wsw >> 6;                        // head 0..11
    const int i0  = (wsw & 63) * 64;                 // query-tile base

    // Q fragments: all 4 q-tiles register-resident (B-operand: col=l16)
    bf16x8 qf[4][2];
    #pragma unroll
    for (int jt = 0; jt < 4; ++jt) {
        const ushort* qb = Qb + (size_t)(i0 + jt * 16 + l16) * DMODEL + h * HDIM;
        qf[jt][0] = *(const bf16x8*)(qb + quad * 8);
        qf[jt][1] = *(const bf16x8*)(qb + 32 + quad * 8);
    }

    bf16x8 ones;
    #pragma unroll
    for (int i = 0; i < 8; ++i) ones[i] = (short)0x3F80;   // bf16 1.0

    floatx4 O[4][4] = {};    // [q-tile][d-tile], partial over this wave's keys
    floatx4 Ol[4]   = {};    // [q-tile] partial row-sums

    ushort* wls = lds + wave * 6144;                 // private region

    // K staging source (3-bit XOR chunk pre-swizzle; wave's key = t*64+wave*16+row)
    const int lrow8 = lane >> 3;                     // 0..7
    const int csw8  = ((lane & 7) ^ lrow8) * 8;
    const ushort* gK0 = Kb + (size_t)(wave * 16 + lrow8) * DMODEL + h * HDIM + csw8;
    const ushort* gK1 = gK0 + (size_t)8 * DMODEL;

    // V staging source: lane -> d=lane>>1, PHYSICAL tok-pair=lane&1 holds
    // LOGICAL pair (lane&1)^((d>>2)&1) = (lane&1)^((lane>>3)&1)
    const ushort* gV0 = Vt + (size_t)(h * HDIM + (lane >> 1)) * TOKENS
                           + wave * 16 + (((lane & 1) ^ ((lane >> 3) & 1)) * 8);
    const ushort* gV1 = gV0 + (size_t)32 * TOKENS;

    // V read offset (loop-invariant): logical pair quad>>1 of row nt*16+l16
    // sits at physical pair (quad>>1)^((l16>>2)&1); 8B half = quad&1
    const int vo = ((quad >> 1) ^ ((l16 >> 2) & 1)) * 8 + (quad & 1) * 4;

    // persistent P operand, packed across an even/odd chunk pair
    union { bf16x8 v; unsigned u[4]; } pa[4];

    // prologue: stage t=0 (K -> buf0, V -> slot0); 4 DMA outstanding
    gl2lds16(gK0, wls);
    gl2lds16(gK1, wls + 512);
    gl2lds16(gV0, wls + 2048);
    gl2lds16(gV1, wls + 2048 + 512);

    for (int u = 0; u < 32; ++u) {                   // pair u: t0=2u, t1=2u+1
        const int s0 = (u & 1) << 1;                 // V slot of t0 (0 or 2)
        ushort* Kc0 = wls;
        ushort* Kc1 = wls + 1024;
        ushort* V0  = wls + 2048 + s0 * 1024;
        ushort* V1  = wls + 2048 + (s0 + 1) * 1024;
        ushort* Vn  = wls + 2048 + ((s0 + 2) & 3) * 1024;

        // ======== t0 = 2u (even): prefetch t1, QK on Kc0 -> pa low half ====
        {
            const size_t t1 = (size_t)(2 * u + 1) * 64;
            gl2lds16(gK0 + t1 * DMODEL, Kc1);
            gl2lds16(gK1 + t1 * DMODEL, Kc1 + 512);
            gl2lds16(gV0 + t1, V1);
            gl2lds16(gV1 + t1, V1 + 512);
        }
        asm volatile("s_waitcnt vmcnt(4)" ::: "memory");   // t0's 4 DMA done
        __builtin_amdgcn_sched_barrier(0);

        {
            const bf16x8 a0 = frag(Kc0, l16, quad);
            const bf16x8 a1 = frag(Kc0, l16, 4 + quad);
            __builtin_amdgcn_s_setprio(1);
            #pragma unroll
            for (int jt = 0; jt < 4; ++jt) {
                floatx4 s = {0.f, 0.f, 0.f, 0.f};
                s = __builtin_amdgcn_mfma_f32_16x16x32_bf16(a0, qf[jt][0], s, 0, 0, 0);
                s = __builtin_amdgcn_mfma_f32_16x16x32_bf16(a1, qf[jt][1], s, 0, 0, 0);
                pa[jt].u[0] = cvt_pk_bf16(__builtin_amdgcn_exp2f(s[0]),
                                          __builtin_amdgcn_exp2f(s[1]));
                pa[jt].u[1] = cvt_pk_bf16(__builtin_amdgcn_exp2f(s[2]),
                                          __builtin_amdgcn_exp2f(s[3]));
            }
            __builtin_amdgcn_s_setprio(0);
        }

        // ======== t1 = 2u+1 (odd): prefetch next t0, QK on Kc1 -> pa high,
        //          then PV + Ol over the 32-key pair ========================
        if (u < 31) {
            const size_t t2 = (size_t)(2 * u + 2) * 64;
            gl2lds16(gK0 + t2 * DMODEL, Kc0);
            gl2lds16(gK1 + t2 * DMODEL, Kc0 + 512);
            gl2lds16(gV0 + t2, Vn);
            gl2lds16(gV1 + t2, Vn + 512);
            asm volatile("s_waitcnt vmcnt(4)" ::: "memory");  // t1's 4 DMA done
        } else {
            asm volatile("s_waitcnt vmcnt(0)" ::: "memory");
        }
        __builtin_amdgcn_sched_barrier(0);

        {
            const bf16x8 a0 = frag(Kc1, l16, quad);
            const bf16x8 a1 = frag(Kc1, l16, 4 + quad);
            __builtin_amdgcn_s_setprio(1);
            #pragma unroll
            for (int jt = 0; jt < 4; ++jt) {
                floatx4 s = {0.f, 0.f, 0.f, 0.f};
                s = __builtin_amdgcn_mfma_f32_16x16x32_bf16(a0, qf[jt][0], s, 0, 0, 0);
                s = __builtin_amdgcn_mfma_f32_16x16x32_bf16(a1, qf[jt][1], s, 0, 0, 0);
                pa[jt].u[2] = cvt_pk_bf16(__builtin_amdgcn_exp2f(s[0]),
                                          __builtin_amdgcn_exp2f(s[1]));
                pa[jt].u[3] = cvt_pk_bf16(__builtin_amdgcn_exp2f(s[2]),
                                          __builtin_amdgcn_exp2f(s[3]));
            }
            __builtin_amdgcn_s_setprio(0);
        }

        __builtin_amdgcn_s_setprio(1);
        #pragma unroll
        for (int nt = 0; nt < 4; ++nt) {
            const int ro = (nt * 16 + l16) * 16 + vo;   // pair-swizzled slot
            union { bf16x8 v; uint2 d[2]; } vu;
            vu.d[0] = *(const uint2*)(V0 + ro);   // even-chunk tokens (k-slots 0-3)
            vu.d[1] = *(const uint2*)(V1 + ro);   // odd-chunk tokens  (k-slots 4-7)
            #pragma unroll
            for (int jt = 0; jt < 4; ++jt)
                O[jt][nt] = __builtin_amdgcn_mfma_f32_16x16x32_bf16(
                    pa[jt].v, vu.v, O[jt][nt], 0, 0, 0);
        }
        #pragma unroll
        for (int jt = 0; jt < 4; ++jt)
            Ol[jt] = __builtin_amdgcn_mfma_f32_16x16x32_bf16(
                pa[jt].v, ones, Ol[jt], 0, 0, 0);
        __builtin_amdgcn_s_setprio(0);
    }

    // ---- cross-wave reduction + store (proven 4-way epilogue) ----
    __syncthreads();                       // all compute done, LDS reusable
    float* Of  = (float*)lds;              // 3 regions of [64][66] f32
    float* Olf = ((float*)lds) + 3 * 64 * 66;   // 3 x [64] f32
    if (wave != 0) {
        const int rg = (wave - 1) * 64 * 66;
        #pragma unroll
        for (int jt = 0; jt < 4; ++jt) {
            #pragma unroll
            for (int nt = 0; nt < 4; ++nt)
                #pragma unroll
                for (int r = 0; r < 4; ++r)
                    Of[rg + (jt * 16 + quad * 4 + r) * 66 + nt * 16 + l16] = O[jt][nt][r];
            if (l16 == 0) {
                #pragma unroll
                for (int r = 0; r < 4; ++r)
                    Olf[(wave - 1) * 64 + jt * 16 + quad * 4 + r] = Ol[jt][r];
            }
        }
    }
    __syncthreads();
    if (wave == 0) {
        #pragma unroll
        for (int jt = 0; jt < 4; ++jt) {
            const int qr = jt * 16 + quad * 4;
            float linv[4];
            #pragma unroll
            for (int r = 0; r < 4; ++r) {
                const float l = Ol[jt][r] + Olf[qr + r] + Olf[64 + qr + r]
                              + Olf[128 + qr + r];
                linv[r] = __builtin_amdgcn_rcpf(l);
            }
            #pragma unroll
            for (int nt = 0; nt < 4; ++nt) {
                const int d = h * HDIM + nt * 16 + l16;
                #pragma unroll
                for (int r = 0; r < 4; ++r) {
                    const float o = O[jt][nt][r]
                        + Of[(qr + r) * 66 + nt * 16 + l16]
                        + Of[64 * 66 + (qr + r) * 66 + nt * 16 + l16]
                        + Of[2 * 64 * 66 + (qr + r) * 66 + nt * 16 + l16];
                    attn_out[(size_t)(i0 + qr + r) * DMODEL + d] = f2bf(o * linv[r]);
                }
            }
        }
    }
}

// ---------------------------------------------------------------------------
extern "C" void kernel_launch(void* const* d_in, const int* in_sizes, int n_in,
                              void* d_out, int out_size, void* d_ws, size_t ws_size,
                              hipStream_t stream)
{
    const float* x     = (const float*)d_in[0];
    const float* Wqkv  = (const float*)d_in[1];
    const float* Wproj = (const float*)d_in[2];
    const float* bproj = (const float*)d_in[3];
    float* out = (float*)d_out;

    ushort* Xb     = (ushort*)d_ws;                          // [4096][768]
    ushort* WqkvT  = Xb    + (size_t)TOKENS * DMODEL;        // [2304][768]
    ushort* WprojT = WqkvT + (size_t)QKV_N * DMODEL;         // [768][768]
    ushort* Qb     = WprojT + (size_t)DMODEL * DMODEL;       // [4096][768]
    ushort* Kb     = Qb    + (size_t)TOKENS * DMODEL;        // [4096][768]
    ushort* Vt     = Kb    + (size_t)TOKENS * DMODEL;        // [768][4096]
    ushort* attn   = Vt    + (size_t)TOKENS * DMODEL;        // [4096][768]

    prep_kernel<<<dim3(5376), 256, 0, stream>>>(
        x, Wqkv, Wproj, Xb, WqkvT, WprojT);

    gemm_qkv_mfma<<<dim3(QKV_N / 128, TOKENS / 128), 256, 0, stream>>>(
        Xb, WqkvT, Qb, Kb, Vt);

    attn_mfma_kernel<<<dim3(TOKENS / 64, NHEADS), 256, 0, stream>>>(
        Qb, Kb, Vt, attn);

    gemm_proj_mfma<<<dim3(DMODEL / 64, TOKENS / 128), 256, 0, stream>>>(
        attn, WprojT, bproj, out);
}

// Round 10
// 186.272 us; speedup vs baseline: 1.0901x; 1.0538x over previous
//
#include <hip/hip_runtime.h>
#include <math.h>

#define TOKENS 4096
#define DMODEL 768
#define NHEADS 12
#define HDIM   64
#define QKV_N  2304          // 3*DMODEL
#define ATTN_SCALE 0.125f    // HDIM^-0.5
// fold log2(e) into Q so softmax uses v_exp_f32 (2^x) directly
#define QSCALE_LOG2E (0.125f * 1.44269504088896340736f)

typedef __attribute__((ext_vector_type(8))) short bf16x8;   // 8 bf16 = 4 VGPRs
typedef __attribute__((ext_vector_type(4))) float floatx4;

__device__ __forceinline__ ushort f2bf(float f) {
    union { float f; unsigned u; } cv; cv.f = f;
    unsigned u = cv.u;
    u += 0x7fffu + ((u >> 16) & 1u);   // round-to-nearest-even
    return (ushort)(u >> 16);
}

// pack two fp32 -> two bf16 (RNE) in one dword via v_cvt_pk_bf16_f32
__device__ __forceinline__ unsigned cvt_pk_bf16(float a, float b) {
    unsigned r;
    asm("v_cvt_pk_bf16_f32 %0, %1, %2" : "=v"(r) : "v"(a), "v"(b));
    return r;
}

// async 16B global->LDS (lane i lands at ldsbase + i*16)
__device__ __forceinline__ void gl2lds16(const ushort* g, ushort* l) {
    __builtin_amdgcn_global_load_lds(
        (const __attribute__((address_space(1))) void*)g,
        (__attribute__((address_space(3))) void*)l, 16, 0, 0);
}

// fragment read (64-ushort rows): logical chunk c of row r at phys (c ^ (r&7))
__device__ __forceinline__ bf16x8 frag(const ushort* ls, int row, int chunk) {
    return *(const bf16x8*)(ls + row * 64 + ((chunk ^ (row & 7)) * 8));
}

// ---------------------------------------------------------------------------
// fused prep: fp32->bf16 cvt of x  +  both weight transpose-converts.
// One launch instead of three.
// ---------------------------------------------------------------------------
__global__ __launch_bounds__(256) void prep_kernel(
    const float* __restrict__ x, const float* __restrict__ Wqkv,
    const float* __restrict__ Wproj, ushort* __restrict__ Xb,
    ushort* __restrict__ WqkvT, ushort* __restrict__ WprojT)
{
    __shared__ ushort tile[32][33];
    const int bid = blockIdx.x;
    const int tid = threadIdx.x;

    if (bid < 3072) {                     // ---- cvt x: 3072*256*4 = 4096*768
        const int i = bid * 256 + tid;
        const float4 v = ((const float4*)x)[i];
        ushort4 h;
        h.x = f2bf(v.x); h.y = f2bf(v.y); h.z = f2bf(v.z); h.w = f2bf(v.w);
        ((ushort4*)Xb)[i] = h;
        return;
    }

    const float* in; ushort* out; int C, bx, by;
    if (bid < 3072 + 1728) {              // ---- Wqkv [768][2304] -> [2304][768]
        const int b = bid - 3072;
        in = Wqkv; out = WqkvT; C = QKV_N;
        bx = b % 72; by = b / 72;
    } else {                              // ---- Wproj [768][768] -> [768][768]
        const int b = bid - 4800;
        in = Wproj; out = WprojT; C = DMODEL;
        bx = b % 24; by = b / 24;
    }
    const int R  = DMODEL;
    const int tx = tid & 31;
    const int ty8 = tid >> 5;             // 0..7
    const int c0 = bx * 32;
    const int r0 = by * 32;
    #pragma unroll
    for (int p = 0; p < 4; ++p) {
        const int r = ty8 + p * 8;
        tile[r][tx] = f2bf(in[(size_t)(r0 + r) * C + c0 + tx]);
    }
    __syncthreads();
    #pragma unroll
    for (int p = 0; p < 4; ++p) {
        const int c = ty8 + p * 8;
        out[(size_t)(c0 + c) * R + r0 + tx] = tile[tx][c];
    }
}

// ---------------------------------------------------------------------------
// MFMA GEMM body (m97 recipe): 128 x (NT*32) tile, BK=64, 4 waves 2x2.
// ---------------------------------------------------------------------------
template<int NT>
__device__ __forceinline__ void gemm_body_async(
    const ushort* __restrict__ A, const ushort* __restrict__ Bt, int K,
    int m0, int n0, floatx4 acc[4][NT], ushort* ls)
{
    ushort* lsA = ls;
    ushort* lsB = ls + 8192;

    const int tid  = threadIdx.x;
    const int lane = tid & 63;
    const int wave = tid >> 6;
    const int wm = wave >> 1, wn = wave & 1;
    const int quad = lane >> 4, l16 = lane & 15;

    const int lrow = lane >> 3;          // 0..7
    const int csw  = ((lane & 7) ^ lrow) * 8;   // swizzled global chunk (ushorts)

    const ushort* gA = A  + (size_t)(m0 + wave * 32 + lrow) * K + csw;
    const ushort* gB = Bt + (size_t)(n0 + wave * NT * 8 + lrow) * K + csw;
    ushort* lA = lsA + (wave * 32) * 64;
    ushort* lB = lsB + (wave * NT * 8) * 64;

    for (int k0 = 0; k0 < K; k0 += 64) {
        __syncthreads();
        #pragma unroll
        for (int p = 0; p < 4; ++p)
            gl2lds16(gA + (size_t)p * 8 * K + k0, lA + p * 8 * 64);
        #pragma unroll
        for (int p = 0; p < NT; ++p)
            gl2lds16(gB + (size_t)p * 8 * K + k0, lB + p * 8 * 64);
        __syncthreads();

        #pragma unroll
        for (int ks = 0; ks < 2; ++ks) {
            bf16x8 af[4], bfr[NT];
            #pragma unroll
            for (int mt = 0; mt < 4; ++mt)
                af[mt] = frag(lsA, wm * 64 + mt * 16 + l16, ks * 4 + quad);
            #pragma unroll
            for (int nt = 0; nt < NT; ++nt)
                bfr[nt] = frag(lsB, wn * NT * 16 + nt * 16 + l16, ks * 4 + quad);
            #pragma unroll
            for (int mt = 0; mt < 4; ++mt)
                #pragma unroll
                for (int nt = 0; nt < NT; ++nt)
                    acc[mt][nt] = __builtin_amdgcn_mfma_f32_16x16x32_bf16(
                        af[mt], bfr[nt], acc[mt][nt], 0, 0, 0);
        }
    }
}

// ---------------------------------------------------------------------------
// qkv GEMM: 128x128 tiles, XCD m-strip swizzle (576 = 8 XCDs x 72).
// Epilogue: SINGLE-pass LDS re-tile (was 2 passes): all 4 waves write the
// full [128][136] retile concurrently, one barrier pair instead of two,
// then 8 store rounds of 256B-contiguous uint4 per 16 lanes.
// ---------------------------------------------------------------------------
__global__ __launch_bounds__(256) void gemm_qkv_mfma(
    const ushort* __restrict__ Xb, const ushort* __restrict__ Wt,
    ushort* __restrict__ Qb, ushort* __restrict__ Kb, ushort* __restrict__ Vt)
{
    __shared__ __align__(16) ushort ls[17408];   // 34 KB: GEMM tiles (32KB) | retile 128x136
    const int lin = blockIdx.x + blockIdx.y * 18;     // dispatch-linear id
    const int w   = (lin & 7) * 72 + (lin >> 3);      // bijective XCD chunking
    const int m0  = (w / 18) * 128;
    const int n0  = (w % 18) * 128;

    floatx4 acc[4][4] = {};
    gemm_body_async<4>(Xb, Wt, DMODEL, m0, n0, acc, ls);

    const int tid  = threadIdx.x;
    const int lane = tid & 63;
    const int wave = tid >> 6;
    const int wm = wave >> 1, wn = wave & 1;
    const int quad = lane >> 4, l16 = lane & 15;

    if (n0 < 2 * DMODEL) {
        // ---- Q or K: single pass over all 128 rows ----
        const float scale = (n0 < DMODEL) ? QSCALE_LOG2E : 1.0f;
        ushort* outp = (n0 < DMODEL) ? Qb : Kb;
        const int colg = (n0 < DMODEL) ? n0 : n0 - DMODEL;
        __syncthreads();                    // all waves done reading GEMM tiles
        #pragma unroll
        for (int mt = 0; mt < 4; ++mt)
            #pragma unroll
            for (int nt = 0; nt < 4; ++nt) {
                const int row = wm * 64 + mt * 16 + quad * 4;
                const int col = wn * 64 + nt * 16 + l16;
                #pragma unroll
                for (int r = 0; r < 4; ++r)
                    ls[(row + r) * 136 + col] = f2bf(acc[mt][nt][r] * scale);
            }
        __syncthreads();
        #pragma unroll
        for (int p2 = 0; p2 < 8; ++p2) {
            const int row = (tid >> 4) + p2 * 16;
            const int c8  = (tid & 15) * 8;
            *(uint4*)(outp + (size_t)(m0 + row) * DMODEL + colg + c8) =
                *(const uint4*)(ls + row * 136 + c8);
        }
    } else {
        // ---- V transposed: single pass over all 128 hd-rows ----
        const int hd0 = n0 - 2 * DMODEL;
        __syncthreads();
        #pragma unroll
        for (int mt = 0; mt < 4; ++mt)
            #pragma unroll
            for (int nt = 0; nt < 4; ++nt) {
                const int hd  = wn * 64 + nt * 16 + l16;
                const int tok = wm * 64 + mt * 16 + quad * 4;
                #pragma unroll
                for (int r = 0; r < 4; ++r)
                    ls[hd * 136 + tok + r] = f2bf(acc[mt][nt][r]);
            }
        __syncthreads();
        #pragma unroll
        for (int p2 = 0; p2 < 8; ++p2) {
            const int row = (tid >> 4) + p2 * 16;    // local hd
            const int c8  = (tid & 15) * 8;          // token chunk
            *(uint4*)(Vt + (size_t)(hd0 + row) * TOKENS + m0 + c8) =
                *(const uint4*)(ls + row * 136 + c8);
        }
    }
}

// ---------------------------------------------------------------------------
// proj GEMM: 128x64 tiles, XCD m-strip swizzle (384 = 8 x 48).
// ---------------------------------------------------------------------------
__global__ __launch_bounds__(256) void gemm_proj_mfma(
    const ushort* __restrict__ Ab, const ushort* __restrict__ Wt,
    const float* __restrict__ bias, float* __restrict__ out)
{
    __shared__ __align__(16) ushort ls[12288];   // 16 KB A + 8 KB B
    const int lin = blockIdx.x + blockIdx.y * 12;
    const int w   = (lin & 7) * 48 + (lin >> 3);
    const int m0  = (w / 12) * 128;
    const int n0  = (w % 12) * 64;

    floatx4 acc[4][2] = {};
    gemm_body_async<2>(Ab, Wt, DMODEL, m0, n0, acc, ls);

    const int lane = threadIdx.x & 63;
    const int wave = threadIdx.x >> 6;
    const int wm = wave >> 1, wn = wave & 1;
    const int quad = lane >> 4, l16 = lane & 15;
    const int row0 = m0 + wm * 64 + quad * 4;
    const int col0 = n0 + wn * 32;

    #pragma unroll
    for (int nt = 0; nt < 2; ++nt) {
        const int col = col0 + nt * 16 + l16;
        const float bv = bias[col];
        #pragma unroll
        for (int mt = 0; mt < 4; ++mt)
            #pragma unroll
            for (int r = 0; r < 4; ++r)
                out[(size_t)(row0 + mt * 16 + r) * DMODEL + col] =
                    acc[mt][nt][r] + bv;
    }
}

// ---------------------------------------------------------------------------
// MFMA flash attention — r9-verified kernel MINUS the two sched_barrier(0).
//
// Rationale: the "memory" clobber on the vmcnt asm already forbids ANY
// memory op (ds_read, global_load_lds) from crossing it in either
// direction, so LDS reads stay below their guarding waits; only
// register-only ops (MFMA/exp2/cvt, ordered by SSA dataflow) may migrate.
// Removing the sched_barriers unlocks compiler software-pipelining of
// exp2/pack of phase k with addressing/K-frags of phase k+1 — the chain
// overlap r7's falsifier identified as the remaining attn wall.
// VGPR pressure is untouched (r8 lesson: no cross-phase live ranges).
// ---------------------------------------------------------------------------
__global__ __launch_bounds__(256, 3) void attn_mfma_kernel(
    const ushort* __restrict__ Qb, const ushort* __restrict__ Kb,
    const ushort* __restrict__ Vt, ushort* __restrict__ attn_out)
{
    // main loop: 4 waves x 6144 ushorts (K0,K1 @0,1024; V0..V3 @2048+s*1024)
    // epilogue:  3 x [64][66] f32 + 192 f32 = 12864 floats = 25728 ushorts
    __shared__ __align__(16) ushort lds[25728];   // 51.5 KB

    const int tid  = threadIdx.x;
    const int wave = tid >> 6;
    const int lane = tid & 63;
    const int quad = lane >> 4;
    const int l16  = lane & 15;

    // XCD head-locality swizzle (bijective: 768 = 8 XCDs x 96 blocks)
    const int lin = blockIdx.x + blockIdx.y * 64;    // dispatch-linear id
    const int wsw = (lin & 7) * 96 + (lin >> 3);     // chunked per-XCD remap
    const int h   = wsw >> 6;                        // head 0..11
    const int i0  = (wsw & 63) * 64;                 // query-tile base

    // Q fragments: all 4 q-tiles register-resident (B-operand: col=l16)
    bf16x8 qf[4][2];
    #pragma unroll
    for (int jt = 0; jt < 4; ++jt) {
        const ushort* qb = Qb + (size_t)(i0 + jt * 16 + l16) * DMODEL + h * HDIM;
        qf[jt][0] = *(const bf16x8*)(qb + quad * 8);
        qf[jt][1] = *(const bf16x8*)(qb + 32 + quad * 8);
    }

    bf16x8 ones;
    #pragma unroll
    for (int i = 0; i < 8; ++i) ones[i] = (short)0x3F80;   // bf16 1.0

    floatx4 O[4][4] = {};    // [q-tile][d-tile], partial over this wave's keys
    floatx4 Ol[4]   = {};    // [q-tile] partial row-sums

    ushort* wls = lds + wave * 6144;                 // private region

    // K staging source (3-bit XOR chunk pre-swizzle; wave's key = t*64+wave*16+row)
    const int lrow8 = lane >> 3;                     // 0..7
    const int csw8  = ((lane & 7) ^ lrow8) * 8;
    const ushort* gK0 = Kb + (size_t)(wave * 16 + lrow8) * DMODEL + h * HDIM + csw8;
    const ushort* gK1 = gK0 + (size_t)8 * DMODEL;

    // V staging source: lane -> d=lane>>1, PHYSICAL tok-pair=lane&1 holds
    // LOGICAL pair (lane&1)^((d>>2)&1) = (lane&1)^((lane>>3)&1)
    const ushort* gV0 = Vt + (size_t)(h * HDIM + (lane >> 1)) * TOKENS
                           + wave * 16 + (((lane & 1) ^ ((lane >> 3) & 1)) * 8);
    const ushort* gV1 = gV0 + (size_t)32 * TOKENS;

    // V read offset (loop-invariant): logical pair quad>>1 of row nt*16+l16
    // sits at physical pair (quad>>1)^((l16>>2)&1); 8B half = quad&1
    const int vo = ((quad >> 1) ^ ((l16 >> 2) & 1)) * 8 + (quad & 1) * 4;

    // persistent P operand, packed across an even/odd chunk pair
    union { bf16x8 v; unsigned u[4]; } pa[4];

    // prologue: stage t=0 (K -> buf0, V -> slot0); 4 DMA outstanding
    gl2lds16(gK0, wls);
    gl2lds16(gK1, wls + 512);
    gl2lds16(gV0, wls + 2048);
    gl2lds16(gV1, wls + 2048 + 512);

    for (int u = 0; u < 32; ++u) {                   // pair u: t0=2u, t1=2u+1
        const int s0 = (u & 1) << 1;                 // V slot of t0 (0 or 2)
        ushort* Kc0 = wls;
        ushort* Kc1 = wls + 1024;
        ushort* V0  = wls + 2048 + s0 * 1024;
        ushort* V1  = wls + 2048 + (s0 + 1) * 1024;
        ushort* Vn  = wls + 2048 + ((s0 + 2) & 3) * 1024;

        // ======== t0 = 2u (even): prefetch t1, QK on Kc0 -> pa low half ====
        {
            const size_t t1 = (size_t)(2 * u + 1) * 64;
            gl2lds16(gK0 + t1 * DMODEL, Kc1);
            gl2lds16(gK1 + t1 * DMODEL, Kc1 + 512);
            gl2lds16(gV0 + t1, V1);
            gl2lds16(gV1 + t1, V1 + 512);
        }
        asm volatile("s_waitcnt vmcnt(4)" ::: "memory");   // t0's 4 DMA done

        {
            const bf16x8 a0 = frag(Kc0, l16, quad);
            const bf16x8 a1 = frag(Kc0, l16, 4 + quad);
            __builtin_amdgcn_s_setprio(1);
            #pragma unroll
            for (int jt = 0; jt < 4; ++jt) {
                floatx4 s = {0.f, 0.f, 0.f, 0.f};
                s = __builtin_amdgcn_mfma_f32_16x16x32_bf16(a0, qf[jt][0], s, 0, 0, 0);
                s = __builtin_amdgcn_mfma_f32_16x16x32_bf16(a1, qf[jt][1], s, 0, 0, 0);
                pa[jt].u[0] = cvt_pk_bf16(__builtin_amdgcn_exp2f(s[0]),
                                          __builtin_amdgcn_exp2f(s[1]));
                pa[jt].u[1] = cvt_pk_bf16(__builtin_amdgcn_exp2f(s[2]),
                                          __builtin_amdgcn_exp2f(s[3]));
            }
            __builtin_amdgcn_s_setprio(0);
        }

        // ======== t1 = 2u+1 (odd): prefetch next t0, QK on Kc1 -> pa high,
        //          then PV + Ol over the 32-key pair ========================
        if (u < 31) {
            const size_t t2 = (size_t)(2 * u + 2) * 64;
            gl2lds16(gK0 + t2 * DMODEL, Kc0);
            gl2lds16(gK1 + t2 * DMODEL, Kc0 + 512);
            gl2lds16(gV0 + t2, Vn);
            gl2lds16(gV1 + t2, Vn + 512);
            asm volatile("s_waitcnt vmcnt(4)" ::: "memory");  // t1's 4 DMA done
        } else {
            asm volatile("s_waitcnt vmcnt(0)" ::: "memory");
        }

        {
            const bf16x8 a0 = frag(Kc1, l16, quad);
            const bf16x8 a1 = frag(Kc1, l16, 4 + quad);
            __builtin_amdgcn_s_setprio(1);
            #pragma unroll
            for (int jt = 0; jt < 4; ++jt) {
                floatx4 s = {0.f, 0.f, 0.f, 0.f};
                s = __builtin_amdgcn_mfma_f32_16x16x32_bf16(a0, qf[jt][0], s, 0, 0, 0);
                s = __builtin_amdgcn_mfma_f32_16x16x32_bf16(a1, qf[jt][1], s, 0, 0, 0);
                pa[jt].u[2] = cvt_pk_bf16(__builtin_amdgcn_exp2f(s[0]),
                                          __builtin_amdgcn_exp2f(s[1]));
                pa[jt].u[3] = cvt_pk_bf16(__builtin_amdgcn_exp2f(s[2]),
                                          __builtin_amdgcn_exp2f(s[3]));
            }
            __builtin_amdgcn_s_setprio(0);
        }

        __builtin_amdgcn_s_setprio(1);
        #pragma unroll
        for (int nt = 0; nt < 4; ++nt) {
            const int ro = (nt * 16 + l16) * 16 + vo;   // pair-swizzled slot
            union { bf16x8 v; uint2 d[2]; } vu;
            vu.d[0] = *(const uint2*)(V0 + ro);   // even-chunk tokens (k-slots 0-3)
            vu.d[1] = *(const uint2*)(V1 + ro);   // odd-chunk tokens  (k-slots 4-7)
            #pragma unroll
            for (int jt = 0; jt < 4; ++jt)
                O[jt][nt] = __builtin_amdgcn_mfma_f32_16x16x32_bf16(
                    pa[jt].v, vu.v, O[jt][nt], 0, 0, 0);
        }
        #pragma unroll
        for (int jt = 0; jt < 4; ++jt)
            Ol[jt] = __builtin_amdgcn_mfma_f32_16x16x32_bf16(
                pa[jt].v, ones, Ol[jt], 0, 0, 0);
        __builtin_amdgcn_s_setprio(0);
    }

    // ---- cross-wave reduction + store (proven 4-way epilogue) ----
    __syncthreads();                       // all compute done, LDS reusable
    float* Of  = (float*)lds;              // 3 regions of [64][66] f32
    float* Olf = ((float*)lds) + 3 * 64 * 66;   // 3 x [64] f32
    if (wave != 0) {
        const int rg = (wave - 1) * 64 * 66;
        #pragma unroll
        for (int jt = 0; jt < 4; ++jt) {
            #pragma unroll
            for (int nt = 0; nt < 4; ++nt)
                #pragma unroll
                for (int r = 0; r < 4; ++r)
                    Of[rg + (jt * 16 + quad * 4 + r) * 66 + nt * 16 + l16] = O[jt][nt][r];
            if (l16 == 0) {
                #pragma unroll
                for (int r = 0; r < 4; ++r)
                    Olf[(wave - 1) * 64 + jt * 16 + quad * 4 + r] = Ol[jt][r];
            }
        }
    }
    __syncthreads();
    if (wave == 0) {
        #pragma unroll
        for (int jt = 0; jt < 4; ++jt) {
            const int qr = jt * 16 + quad * 4;
            float linv[4];
            #pragma unroll
            for (int r = 0; r < 4; ++r) {
                const float l = Ol[jt][r] + Olf[qr + r] + Olf[64 + qr + r]
                              + Olf[128 + qr + r];
                linv[r] = __builtin_amdgcn_rcpf(l);
            }
            #pragma unroll
            for (int nt = 0; nt < 4; ++nt) {
                const int d = h * HDIM + nt * 16 + l16;
                #pragma unroll
                for (int r = 0; r < 4; ++r) {
                    const float o = O[jt][nt][r]
                        + Of[(qr + r) * 66 + nt * 16 + l16]
                        + Of[64 * 66 + (qr + r) * 66 + nt * 16 + l16]
                        + Of[2 * 64 * 66 + (qr + r) * 66 + nt * 16 + l16];
                    attn_out[(size_t)(i0 + qr + r) * DMODEL + d] = f2bf(o * linv[r]);
                }
            }
        }
    }
}

// ---------------------------------------------------------------------------
extern "C" void kernel_launch(void* const* d_in, const int* in_sizes, int n_in,
                              void* d_out, int out_size, void* d_ws, size_t ws_size,
                              hipStream_t stream)
{
    const float* x     = (const float*)d_in[0];
    const float* Wqkv  = (const float*)d_in[1];
    const float* Wproj = (const float*)d_in[2];
    const float* bproj = (const float*)d_in[3];
    float* out = (float*)d_out;

    ushort* Xb     = (ushort*)d_ws;                          // [4096][768]
    ushort* WqkvT  = Xb    + (size_t)TOKENS * DMODEL;        // [2304][768]
    ushort* WprojT = WqkvT + (size_t)QKV_N * DMODEL;         // [768][768]
    ushort* Qb     = WprojT + (size_t)DMODEL * DMODEL;       // [4096][768]
    ushort* Kb     = Qb    + (size_t)TOKENS * DMODEL;        // [4096][768]
    ushort* Vt     = Kb    + (size_t)TOKENS * DMODEL;        // [768][4096]
    ushort* attn   = Vt    + (size_t)TOKENS * DMODEL;        // [4096][768]

    prep_kernel<<<dim3(5376), 256, 0, stream>>>(
        x, Wqkv, Wproj, Xb, WqkvT, WprojT);

    gemm_qkv_mfma<<<dim3(QKV_N / 128, TOKENS / 128), 256, 0, stream>>>(
        Xb, WqkvT, Qb, Kb, Vt);

    attn_mfma_kernel<<<dim3(TOKENS / 64, NHEADS), 256, 0, stream>>>(
        Qb, Kb, Vt, attn);

    gemm_proj_mfma<<<dim3(DMODEL / 64, TOKENS / 128), 256, 0, stream>>>(
        attn, WprojT, bproj, out);
}

// Round 11
// 181.365 us; speedup vs baseline: 1.1196x; 1.0271x over previous
//
#include <hip/hip_runtime.h>
#include <math.h>

#define TOKENS 4096
#define DMODEL 768
#define NHEADS 12
#define HDIM   64
#define QKV_N  2304          // 3*DMODEL
#define ATTN_SCALE 0.125f    // HDIM^-0.5
// fold log2(e) into Q so softmax uses v_exp_f32 (2^x) directly
#define QSCALE_LOG2E (0.125f * 1.44269504088896340736f)

typedef __attribute__((ext_vector_type(8))) short bf16x8;   // 8 bf16 = 4 VGPRs
typedef __attribute__((ext_vector_type(4))) float floatx4;

__device__ __forceinline__ ushort f2bf(float f) {
    union { float f; unsigned u; } cv; cv.f = f;
    unsigned u = cv.u;
    u += 0x7fffu + ((u >> 16) & 1u);   // round-to-nearest-even
    return (ushort)(u >> 16);
}

// pack two fp32 -> two bf16 (RNE) in one dword via v_cvt_pk_bf16_f32
__device__ __forceinline__ unsigned cvt_pk_bf16(float a, float b) {
    unsigned r;
    asm("v_cvt_pk_bf16_f32 %0, %1, %2" : "=v"(r) : "v"(a), "v"(b));
    return r;
}

// async 16B global->LDS (lane i lands at ldsbase + i*16)
__device__ __forceinline__ void gl2lds16(const ushort* g, ushort* l) {
    __builtin_amdgcn_global_load_lds(
        (const __attribute__((address_space(1))) void*)g,
        (__attribute__((address_space(3))) void*)l, 16, 0, 0);
}

// fragment read (64-ushort rows): logical chunk c of row r at phys (c ^ (r&7))
__device__ __forceinline__ bf16x8 frag(const ushort* ls, int row, int chunk) {
    return *(const bf16x8*)(ls + row * 64 + ((chunk ^ (row & 7)) * 8));
}

// ---------------------------------------------------------------------------
// fused prep: fp32->bf16 cvt of x  +  both weight transpose-converts.
// ---------------------------------------------------------------------------
__global__ __launch_bounds__(256) void prep_kernel(
    const float* __restrict__ x, const float* __restrict__ Wqkv,
    const float* __restrict__ Wproj, ushort* __restrict__ Xb,
    ushort* __restrict__ WqkvT, ushort* __restrict__ WprojT)
{
    __shared__ ushort tile[32][33];
    const int bid = blockIdx.x;
    const int tid = threadIdx.x;

    if (bid < 3072) {                     // ---- cvt x: 3072*256*4 = 4096*768
        const int i = bid * 256 + tid;
        const float4 v = ((const float4*)x)[i];
        ushort4 h;
        h.x = f2bf(v.x); h.y = f2bf(v.y); h.z = f2bf(v.z); h.w = f2bf(v.w);
        ((ushort4*)Xb)[i] = h;
        return;
    }

    const float* in; ushort* out; int C, bx, by;
    if (bid < 3072 + 1728) {              // ---- Wqkv [768][2304] -> [2304][768]
        const int b = bid - 3072;
        in = Wqkv; out = WqkvT; C = QKV_N;
        bx = b % 72; by = b / 72;
    } else {                              // ---- Wproj [768][768] -> [768][768]
        const int b = bid - 4800;
        in = Wproj; out = WprojT; C = DMODEL;
        bx = b % 24; by = b / 24;
    }
    const int R  = DMODEL;
    const int tx = tid & 31;
    const int ty8 = tid >> 5;             // 0..7
    const int c0 = bx * 32;
    const int r0 = by * 32;
    #pragma unroll
    for (int p = 0; p < 4; ++p) {
        const int r = ty8 + p * 8;
        tile[r][tx] = f2bf(in[(size_t)(r0 + r) * C + c0 + tx]);
    }
    __syncthreads();
    #pragma unroll
    for (int p = 0; p < 4; ++p) {
        const int c = ty8 + p * 8;
        out[(size_t)(c0 + c) * R + r0 + tx] = tile[tx][c];
    }
}

// ---------------------------------------------------------------------------
// MFMA GEMM body v2 — 2-PHASE double-buffered pipeline (T3 minimum recipe):
//   prologue: STAGE(buf0, tile0); barrier.
//   iter t:   STAGE(buf[t+1&1], tile t+1)   <- issued BEFORE compute
//             ds_read+MFMA on buf[t&1]       <- covers the DMA latency
//             __syncthreads()                <- vmcnt(0) drains the prefetch
// One barrier per K-step (was 2) and zero exposed staging latency. At K=768
// (12 iters) the old structure exposed ~600-900cy x 12 per block; catalog
// analog (m248v2, 2ph @ K=1024): 655-682 TF refcheck'd.
// Buffer: A[128][64] @0 (16KB-eq) + B[32*NT][64] @8192; BUF=8192+2048*NT.
// ---------------------------------------------------------------------------
template<int NT>
__device__ __forceinline__ void gemm_body_2ph(
    const ushort* __restrict__ A, const ushort* __restrict__ Bt, int K,
    int m0, int n0, floatx4 acc[4][NT], ushort* ls)
{
    const int BUF = 8192 + 2048 * NT;    // ushorts per buffer

    const int tid  = threadIdx.x;
    const int lane = tid & 63;
    const int wave = tid >> 6;
    const int wm = wave >> 1, wn = wave & 1;
    const int quad = lane >> 4, l16 = lane & 15;

    const int lrow = lane >> 3;          // 0..7
    const int csw  = ((lane & 7) ^ lrow) * 8;   // swizzled global chunk (ushorts)

    const ushort* gA = A  + (size_t)(m0 + wave * 32 + lrow) * K + csw;
    const ushort* gB = Bt + (size_t)(n0 + wave * NT * 8 + lrow) * K + csw;
    const int lAoff = (wave * 32) * 64;
    const int lBoff = 8192 + (wave * NT * 8) * 64;

    // prologue: stage tile 0 into buffer 0
    #pragma unroll
    for (int p = 0; p < 4; ++p)
        gl2lds16(gA + (size_t)p * 8 * K, ls + lAoff + p * 8 * 64);
    #pragma unroll
    for (int p = 0; p < NT; ++p)
        gl2lds16(gB + (size_t)p * 8 * K, ls + lBoff + p * 8 * 64);
    __syncthreads();                     // drain + publish tile 0

    const int NK = K / 64;
    for (int t = 0; t < NK; ++t) {
        ushort* cb = ls + (t & 1) * BUF;
        ushort* nb = ls + ((t + 1) & 1) * BUF;

        if (t + 1 < NK) {                // issue next tile's DMA (no wait)
            const int k1 = (t + 1) * 64;
            #pragma unroll
            for (int p = 0; p < 4; ++p)
                gl2lds16(gA + (size_t)p * 8 * K + k1, nb + lAoff + p * 8 * 64);
            #pragma unroll
            for (int p = 0; p < NT; ++p)
                gl2lds16(gB + (size_t)p * 8 * K + k1, nb + lBoff + p * 8 * 64);
        }

        const ushort* lsA = cb;
        const ushort* lsB = cb + 8192;
        #pragma unroll
        for (int ks = 0; ks < 2; ++ks) {
            bf16x8 af[4], bfr[NT];
            #pragma unroll
            for (int mt = 0; mt < 4; ++mt)
                af[mt] = frag(lsA, wm * 64 + mt * 16 + l16, ks * 4 + quad);
            #pragma unroll
            for (int nt = 0; nt < NT; ++nt)
                bfr[nt] = frag(lsB, wn * NT * 16 + nt * 16 + l16, ks * 4 + quad);
            #pragma unroll
            for (int mt = 0; mt < 4; ++mt)
                #pragma unroll
                for (int nt = 0; nt < NT; ++nt)
                    acc[mt][nt] = __builtin_amdgcn_mfma_f32_16x16x32_bf16(
                        af[mt], bfr[nt], acc[mt][nt], 0, 0, 0);
        }

        __syncthreads();                 // vmcnt(0): prefetch landed; publish
    }
}

// ---------------------------------------------------------------------------
// qkv GEMM: 128x128 tiles, XCD m-strip swizzle (576 = 8 XCDs x 72),
// 2-phase double-buffered body (64 KB LDS), single-pass retile epilogue.
// ---------------------------------------------------------------------------
__global__ __launch_bounds__(256) void gemm_qkv_mfma(
    const ushort* __restrict__ Xb, const ushort* __restrict__ Wt,
    ushort* __restrict__ Qb, ushort* __restrict__ Kb, ushort* __restrict__ Vt)
{
    __shared__ __align__(16) ushort ls[32768];   // 64 KB: 2 x 32 KB tile bufs
    const int lin = blockIdx.x + blockIdx.y * 18;     // dispatch-linear id
    const int w   = (lin & 7) * 72 + (lin >> 3);      // bijective XCD chunking
    const int m0  = (w / 18) * 128;
    const int n0  = (w % 18) * 128;

    floatx4 acc[4][4] = {};
    gemm_body_2ph<4>(Xb, Wt, DMODEL, m0, n0, acc, ls);

    const int tid  = threadIdx.x;
    const int lane = tid & 63;
    const int wave = tid >> 6;
    const int wm = wave >> 1, wn = wave & 1;
    const int quad = lane >> 4, l16 = lane & 15;

    if (n0 < 2 * DMODEL) {
        // ---- Q or K: single pass over all 128 rows ----
        const float scale = (n0 < DMODEL) ? QSCALE_LOG2E : 1.0f;
        ushort* outp = (n0 < DMODEL) ? Qb : Kb;
        const int colg = (n0 < DMODEL) ? n0 : n0 - DMODEL;
        __syncthreads();                    // all waves done with GEMM tiles
        #pragma unroll
        for (int mt = 0; mt < 4; ++mt)
            #pragma unroll
            for (int nt = 0; nt < 4; ++nt) {
                const int row = wm * 64 + mt * 16 + quad * 4;
                const int col = wn * 64 + nt * 16 + l16;
                #pragma unroll
                for (int r = 0; r < 4; ++r)
                    ls[(row + r) * 136 + col] = f2bf(acc[mt][nt][r] * scale);
            }
        __syncthreads();
        #pragma unroll
        for (int p2 = 0; p2 < 8; ++p2) {
            const int row = (tid >> 4) + p2 * 16;
            const int c8  = (tid & 15) * 8;
            *(uint4*)(outp + (size_t)(m0 + row) * DMODEL + colg + c8) =
                *(const uint4*)(ls + row * 136 + c8);
        }
    } else {
        // ---- V transposed: single pass over all 128 hd-rows ----
        const int hd0 = n0 - 2 * DMODEL;
        __syncthreads();
        #pragma unroll
        for (int mt = 0; mt < 4; ++mt)
            #pragma unroll
            for (int nt = 0; nt < 4; ++nt) {
                const int hd  = wn * 64 + nt * 16 + l16;
                const int tok = wm * 64 + mt * 16 + quad * 4;
                #pragma unroll
                for (int r = 0; r < 4; ++r)
                    ls[hd * 136 + tok + r] = f2bf(acc[mt][nt][r]);
            }
        __syncthreads();
        #pragma unroll
        for (int p2 = 0; p2 < 8; ++p2) {
            const int row = (tid >> 4) + p2 * 16;    // local hd
            const int c8  = (tid & 15) * 8;          // token chunk
            *(uint4*)(Vt + (size_t)(hd0 + row) * TOKENS + m0 + c8) =
                *(const uint4*)(ls + row * 136 + c8);
        }
    }
}

// ---------------------------------------------------------------------------
// proj GEMM: 128x64 tiles, XCD m-strip swizzle (384 = 8 x 48),
// 2-phase double-buffered body (48 KB LDS).
// ---------------------------------------------------------------------------
__global__ __launch_bounds__(256) void gemm_proj_mfma(
    const ushort* __restrict__ Ab, const ushort* __restrict__ Wt,
    const float* __restrict__ bias, float* __restrict__ out)
{
    __shared__ __align__(16) ushort ls[24576];   // 48 KB: 2 x 24 KB tile bufs
    const int lin = blockIdx.x + blockIdx.y * 12;
    const int w   = (lin & 7) * 48 + (lin >> 3);
    const int m0  = (w / 12) * 128;
    const int n0  = (w % 12) * 64;

    floatx4 acc[4][2] = {};
    gemm_body_2ph<2>(Ab, Wt, DMODEL, m0, n0, acc, ls);

    const int lane = threadIdx.x & 63;
    const int wave = threadIdx.x >> 6;
    const int wm = wave >> 1, wn = wave & 1;
    const int quad = lane >> 4, l16 = lane & 15;
    const int row0 = m0 + wm * 64 + quad * 4;
    const int col0 = n0 + wn * 32;

    #pragma unroll
    for (int nt = 0; nt < 2; ++nt) {
        const int col = col0 + nt * 16 + l16;
        const float bv = bias[col];
        #pragma unroll
        for (int mt = 0; mt < 4; ++mt)
            #pragma unroll
            for (int r = 0; r < 4; ++r)
                out[(size_t)(row0 + mt * 16 + r) * DMODEL + col] =
                    acc[mt][nt][r] + bv;
    }
}

// ---------------------------------------------------------------------------
// MFMA flash attention — r10-verified kernel VERBATIM (186.3us session best;
// attn ~76.4us = structural floor of this design per r7/r9/r10 triangulation).
// ---------------------------------------------------------------------------
__global__ __launch_bounds__(256, 3) void attn_mfma_kernel(
    const ushort* __restrict__ Qb, const ushort* __restrict__ Kb,
    const ushort* __restrict__ Vt, ushort* __restrict__ attn_out)
{
    // main loop: 4 waves x 6144 ushorts (K0,K1 @0,1024; V0..V3 @2048+s*1024)
    // epilogue:  3 x [64][66] f32 + 192 f32 = 12864 floats = 25728 ushorts
    __shared__ __align__(16) ushort lds[25728];   // 51.5 KB

    const int tid  = threadIdx.x;
    const int wave = tid >> 6;
    const int lane = tid & 63;
    const int quad = lane >> 4;
    const int l16  = lane & 15;

    // XCD head-locality swizzle (bijective: 768 = 8 XCDs x 96 blocks)
    const int lin = blockIdx.x + blockIdx.y * 64;    // dispatch-linear id
    const int wsw = (lin & 7) * 96 + (lin >> 3);     // chunked per-XCD remap
    const int h   = wsw >> 6;                        // head 0..11
    const int i0  = (wsw & 63) * 64;                 // query-tile base

    // Q fragments: all 4 q-tiles register-resident (B-operand: col=l16)
    bf16x8 qf[4][2];
    #pragma unroll
    for (int jt = 0; jt < 4; ++jt) {
        const ushort* qb = Qb + (size_t)(i0 + jt * 16 + l16) * DMODEL + h * HDIM;
        qf[jt][0] = *(const bf16x8*)(qb + quad * 8);
        qf[jt][1] = *(const bf16x8*)(qb + 32 + quad * 8);
    }

    bf16x8 ones;
    #pragma unroll
    for (int i = 0; i < 8; ++i) ones[i] = (short)0x3F80;   // bf16 1.0

    floatx4 O[4][4] = {};    // [q-tile][d-tile], partial over this wave's keys
    floatx4 Ol[4]   = {};    // [q-tile] partial row-sums

    ushort* wls = lds + wave * 6144;                 // private region

    // K staging source (3-bit XOR chunk pre-swizzle; wave's key = t*64+wave*16+row)
    const int lrow8 = lane >> 3;                     // 0..7
    const int csw8  = ((lane & 7) ^ lrow8) * 8;
    const ushort* gK0 = Kb + (size_t)(wave * 16 + lrow8) * DMODEL + h * HDIM + csw8;
    const ushort* gK1 = gK0 + (size_t)8 * DMODEL;

    // V staging source: lane -> d=lane>>1, PHYSICAL tok-pair=lane&1 holds
    // LOGICAL pair (lane&1)^((d>>2)&1) = (lane&1)^((lane>>3)&1)
    const ushort* gV0 = Vt + (size_t)(h * HDIM + (lane >> 1)) * TOKENS
                           + wave * 16 + (((lane & 1) ^ ((lane >> 3) & 1)) * 8);
    const ushort* gV1 = gV0 + (size_t)32 * TOKENS;

    // V read offset (loop-invariant): logical pair quad>>1 of row nt*16+l16
    // sits at physical pair (quad>>1)^((l16>>2)&1); 8B half = quad&1
    const int vo = ((quad >> 1) ^ ((l16 >> 2) & 1)) * 8 + (quad & 1) * 4;

    // persistent P operand, packed across an even/odd chunk pair
    union { bf16x8 v; unsigned u[4]; } pa[4];

    // prologue: stage t=0 (K -> buf0, V -> slot0); 4 DMA outstanding
    gl2lds16(gK0, wls);
    gl2lds16(gK1, wls + 512);
    gl2lds16(gV0, wls + 2048);
    gl2lds16(gV1, wls + 2048 + 512);

    for (int u = 0; u < 32; ++u) {                   // pair u: t0=2u, t1=2u+1
        const int s0 = (u & 1) << 1;                 // V slot of t0 (0 or 2)
        ushort* Kc0 = wls;
        ushort* Kc1 = wls + 1024;
        ushort* V0  = wls + 2048 + s0 * 1024;
        ushort* V1  = wls + 2048 + (s0 + 1) * 1024;
        ushort* Vn  = wls + 2048 + ((s0 + 2) & 3) * 1024;

        // ======== t0 = 2u (even): prefetch t1, QK on Kc0 -> pa low half ====
        {
            const size_t t1 = (size_t)(2 * u + 1) * 64;
            gl2lds16(gK0 + t1 * DMODEL, Kc1);
            gl2lds16(gK1 + t1 * DMODEL, Kc1 + 512);
            gl2lds16(gV0 + t1, V1);
            gl2lds16(gV1 + t1, V1 + 512);
        }
        asm volatile("s_waitcnt vmcnt(4)" ::: "memory");   // t0's 4 DMA done

        {
            const bf16x8 a0 = frag(Kc0, l16, quad);
            const bf16x8 a1 = frag(Kc0, l16, 4 + quad);
            __builtin_amdgcn_s_setprio(1);
            #pragma unroll
            for (int jt = 0; jt < 4; ++jt) {
                floatx4 s = {0.f, 0.f, 0.f, 0.f};
                s = __builtin_amdgcn_mfma_f32_16x16x32_bf16(a0, qf[jt][0], s, 0, 0, 0);
                s = __builtin_amdgcn_mfma_f32_16x16x32_bf16(a1, qf[jt][1], s, 0, 0, 0);
                pa[jt].u[0] = cvt_pk_bf16(__builtin_amdgcn_exp2f(s[0]),
                                          __builtin_amdgcn_exp2f(s[1]));
                pa[jt].u[1] = cvt_pk_bf16(__builtin_amdgcn_exp2f(s[2]),
                                          __builtin_amdgcn_exp2f(s[3]));
            }
            __builtin_amdgcn_s_setprio(0);
        }

        // ======== t1 = 2u+1 (odd): prefetch next t0, QK on Kc1 -> pa high,
        //          then PV + Ol over the 32-key pair ========================
        if (u < 31) {
            const size_t t2 = (size_t)(2 * u + 2) * 64;
            gl2lds16(gK0 + t2 * DMODEL, Kc0);
            gl2lds16(gK1 + t2 * DMODEL, Kc0 + 512);
            gl2lds16(gV0 + t2, Vn);
            gl2lds16(gV1 + t2, Vn + 512);
            asm volatile("s_waitcnt vmcnt(4)" ::: "memory");  // t1's 4 DMA done
        } else {
            asm volatile("s_waitcnt vmcnt(0)" ::: "memory");
        }

        {
            const bf16x8 a0 = frag(Kc1, l16, quad);
            const bf16x8 a1 = frag(Kc1, l16, 4 + quad);
            __builtin_amdgcn_s_setprio(1);
            #pragma unroll
            for (int jt = 0; jt < 4; ++jt) {
                floatx4 s = {0.f, 0.f, 0.f, 0.f};
                s = __builtin_amdgcn_mfma_f32_16x16x32_bf16(a0, qf[jt][0], s, 0, 0, 0);
                s = __builtin_amdgcn_mfma_f32_16x16x32_bf16(a1, qf[jt][1], s, 0, 0, 0);
                pa[jt].u[2] = cvt_pk_bf16(__builtin_amdgcn_exp2f(s[0]),
                                          __builtin_amdgcn_exp2f(s[1]));
                pa[jt].u[3] = cvt_pk_bf16(__builtin_amdgcn_exp2f(s[2]),
                                          __builtin_amdgcn_exp2f(s[3]));
            }
            __builtin_amdgcn_s_setprio(0);
        }

        __builtin_amdgcn_s_setprio(1);
        #pragma unroll
        for (int nt = 0; nt < 4; ++nt) {
            const int ro = (nt * 16 + l16) * 16 + vo;   // pair-swizzled slot
            union { bf16x8 v; uint2 d[2]; } vu;
            vu.d[0] = *(const uint2*)(V0 + ro);   // even-chunk tokens (k-slots 0-3)
            vu.d[1] = *(const uint2*)(V1 + ro);   // odd-chunk tokens  (k-slots 4-7)
            #pragma unroll
            for (int jt = 0; jt < 4; ++jt)
                O[jt][nt] = __builtin_amdgcn_mfma_f32_16x16x32_bf16(
                    pa[jt].v, vu.v, O[jt][nt], 0, 0, 0);
        }
        #pragma unroll
        for (int jt = 0; jt < 4; ++jt)
            Ol[jt] = __builtin_amdgcn_mfma_f32_16x16x32_bf16(
                pa[jt].v, ones, Ol[jt], 0, 0, 0);
        __builtin_amdgcn_s_setprio(0);
    }

    // ---- cross-wave reduction + store (proven 4-way epilogue) ----
    __syncthreads();                       // all compute done, LDS reusable
    float* Of  = (float*)lds;              // 3 regions of [64][66] f32
    float* Olf = ((float*)lds) + 3 * 64 * 66;   // 3 x [64] f32
    if (wave != 0) {
        const int rg = (wave - 1) * 64 * 66;
        #pragma unroll
        for (int jt = 0; jt < 4; ++jt) {
            #pragma unroll
            for (int nt = 0; nt < 4; ++nt)
                #pragma unroll
                for (int r = 0; r < 4; ++r)
                    Of[rg + (jt * 16 + quad * 4 + r) * 66 + nt * 16 + l16] = O[jt][nt][r];
            if (l16 == 0) {
                #pragma unroll
                for (int r = 0; r < 4; ++r)
                    Olf[(wave - 1) * 64 + jt * 16 + quad * 4 + r] = Ol[jt][r];
            }
        }
    }
    __syncthreads();
    if (wave == 0) {
        #pragma unroll
        for (int jt = 0; jt < 4; ++jt) {
            const int qr = jt * 16 + quad * 4;
            float linv[4];
            #pragma unroll
            for (int r = 0; r < 4; ++r) {
                const float l = Ol[jt][r] + Olf[qr + r] + Olf[64 + qr + r]
                              + Olf[128 + qr + r];
                linv[r] = __builtin_amdgcn_rcpf(l);
            }
            #pragma unroll
            for (int nt = 0; nt < 4; ++nt) {
                const int d = h * HDIM + nt * 16 + l16;
                #pragma unroll
                for (int r = 0; r < 4; ++r) {
                    const float o = O[jt][nt][r]
                        + Of[(qr + r) * 66 + nt * 16 + l16]
                        + Of[64 * 66 + (qr + r) * 66 + nt * 16 + l16]
                        + Of[2 * 64 * 66 + (qr + r) * 66 + nt * 16 + l16];
                    attn_out[(size_t)(i0 + qr + r) * DMODEL + d] = f2bf(o * linv[r]);
                }
            }
        }
    }
}

// ---------------------------------------------------------------------------
extern "C" void kernel_launch(void* const* d_in, const int* in_sizes, int n_in,
                              void* d_out, int out_size, void* d_ws, size_t ws_size,
                              hipStream_t stream)
{
    const float* x     = (const float*)d_in[0];
    const float* Wqkv  = (const float*)d_in[1];
    const float* Wproj = (const float*)d_in[2];
    const float* bproj = (const float*)d_in[3];
    float* out = (float*)d_out;

    ushort* Xb     = (ushort*)d_ws;                          // [4096][768]
    ushort* WqkvT  = Xb    + (size_t)TOKENS * DMODEL;        // [2304][768]
    ushort* WprojT = WqkvT + (size_t)QKV_N * DMODEL;         // [768][768]
    ushort* Qb     = WprojT + (size_t)DMODEL * DMODEL;       // [4096][768]
    ushort* Kb     = Qb    + (size_t)TOKENS * DMODEL;        // [4096][768]
    ushort* Vt     = Kb    + (size_t)TOKENS * DMODEL;        // [768][4096]
    ushort* attn   = Vt    + (size_t)TOKENS * DMODEL;        // [4096][768]

    prep_kernel<<<dim3(5376), 256, 0, stream>>>(
        x, Wqkv, Wproj, Xb, WqkvT, WprojT);

    gemm_qkv_mfma<<<dim3(QKV_N / 128, TOKENS / 128), 256, 0, stream>>>(
        Xb, WqkvT, Qb, Kb, Vt);

    attn_mfma_kernel<<<dim3(TOKENS / 64, NHEADS), 256, 0, stream>>>(
        Qb, Kb, Vt, attn);

    gemm_proj_mfma<<<dim3(DMODEL / 64, TOKENS / 128), 256, 0, stream>>>(
        attn, WprojT, bproj, out);
}

// Round 12
// 180.158 us; speedup vs baseline: 1.1271x; 1.0067x over previous
//
#include <hip/hip_runtime.h>
#include <math.h>

#define TOKENS 4096
#define DMODEL 768
#define NHEADS 12
#define HDIM   64
#define QKV_N  2304          // 3*DMODEL
#define ATTN_SCALE 0.125f    // HDIM^-0.5
// fold log2(e) into Q so softmax uses v_exp_f32 (2^x) directly
#define QSCALE_LOG2E (0.125f * 1.44269504088896340736f)

typedef __attribute__((ext_vector_type(8))) short bf16x8;   // 8 bf16 = 4 VGPRs
typedef __attribute__((ext_vector_type(4))) float floatx4;

__device__ __forceinline__ ushort f2bf(float f) {
    union { float f; unsigned u; } cv; cv.f = f;
    unsigned u = cv.u;
    u += 0x7fffu + ((u >> 16) & 1u);   // round-to-nearest-even
    return (ushort)(u >> 16);
}

// pack two fp32 -> two bf16 (RNE) in one dword via v_cvt_pk_bf16_f32
__device__ __forceinline__ unsigned cvt_pk_bf16(float a, float b) {
    unsigned r;
    asm("v_cvt_pk_bf16_f32 %0, %1, %2" : "=v"(r) : "v"(a), "v"(b));
    return r;
}

// async 16B global->LDS (lane i lands at ldsbase + i*16)
__device__ __forceinline__ void gl2lds16(const ushort* g, ushort* l) {
    __builtin_amdgcn_global_load_lds(
        (const __attribute__((address_space(1))) void*)g,
        (__attribute__((address_space(3))) void*)l, 16, 0, 0);
}

// fragment read (64-ushort rows): logical chunk c of row r at phys (c ^ (r&7))
__device__ __forceinline__ bf16x8 frag(const ushort* ls, int row, int chunk) {
    return *(const bf16x8*)(ls + row * 64 + ((chunk ^ (row & 7)) * 8));
}

// ---------------------------------------------------------------------------
// fused prep: fp32->bf16 cvt of x  +  both weight transpose-converts.
// ---------------------------------------------------------------------------
__global__ __launch_bounds__(256) void prep_kernel(
    const float* __restrict__ x, const float* __restrict__ Wqkv,
    const float* __restrict__ Wproj, ushort* __restrict__ Xb,
    ushort* __restrict__ WqkvT, ushort* __restrict__ WprojT)
{
    __shared__ ushort tile[32][33];
    const int bid = blockIdx.x;
    const int tid = threadIdx.x;

    if (bid < 3072) {                     // ---- cvt x: 3072*256*4 = 4096*768
        const int i = bid * 256 + tid;
        const float4 v = ((const float4*)x)[i];
        ushort4 h;
        h.x = f2bf(v.x); h.y = f2bf(v.y); h.z = f2bf(v.z); h.w = f2bf(v.w);
        ((ushort4*)Xb)[i] = h;
        return;
    }

    const float* in; ushort* out; int C, bx, by;
    if (bid < 3072 + 1728) {              // ---- Wqkv [768][2304] -> [2304][768]
        const int b = bid - 3072;
        in = Wqkv; out = WqkvT; C = QKV_N;
        bx = b % 72; by = b / 72;
    } else {                              // ---- Wproj [768][768] -> [768][768]
        const int b = bid - 4800;
        in = Wproj; out = WprojT; C = DMODEL;
        bx = b % 24; by = b / 24;
    }
    const int R  = DMODEL;
    const int tx = tid & 31;
    const int ty8 = tid >> 5;             // 0..7
    const int c0 = bx * 32;
    const int r0 = by * 32;
    #pragma unroll
    for (int p = 0; p < 4; ++p) {
        const int r = ty8 + p * 8;
        tile[r][tx] = f2bf(in[(size_t)(r0 + r) * C + c0 + tx]);
    }
    __syncthreads();
    #pragma unroll
    for (int p = 0; p < 4; ++p) {
        const int c = ty8 + p * 8;
        out[(size_t)(c0 + c) * R + r0 + tx] = tile[tx][c];
    }
}

// ---------------------------------------------------------------------------
// MFMA GEMM body — 2-PHASE double-buffered (r11-verified sync), 4 waves.
// Used by proj only now.
// ---------------------------------------------------------------------------
template<int NT>
__device__ __forceinline__ void gemm_body_2ph(
    const ushort* __restrict__ A, const ushort* __restrict__ Bt, int K,
    int m0, int n0, floatx4 acc[4][NT], ushort* ls)
{
    const int BUF = 8192 + 2048 * NT;    // ushorts per buffer

    const int tid  = threadIdx.x;
    const int lane = tid & 63;
    const int wave = tid >> 6;
    const int wm = wave >> 1, wn = wave & 1;
    const int quad = lane >> 4, l16 = lane & 15;

    const int lrow = lane >> 3;          // 0..7
    const int csw  = ((lane & 7) ^ lrow) * 8;   // swizzled global chunk (ushorts)

    const ushort* gA = A  + (size_t)(m0 + wave * 32 + lrow) * K + csw;
    const ushort* gB = Bt + (size_t)(n0 + wave * NT * 8 + lrow) * K + csw;
    const int lAoff = (wave * 32) * 64;
    const int lBoff = 8192 + (wave * NT * 8) * 64;

    // prologue: stage tile 0 into buffer 0
    #pragma unroll
    for (int p = 0; p < 4; ++p)
        gl2lds16(gA + (size_t)p * 8 * K, ls + lAoff + p * 8 * 64);
    #pragma unroll
    for (int p = 0; p < NT; ++p)
        gl2lds16(gB + (size_t)p * 8 * K, ls + lBoff + p * 8 * 64);
    __syncthreads();                     // drain + publish tile 0

    const int NK = K / 64;
    for (int t = 0; t < NK; ++t) {
        ushort* cb = ls + (t & 1) * BUF;
        ushort* nb = ls + ((t + 1) & 1) * BUF;

        if (t + 1 < NK) {                // issue next tile's DMA (no wait)
            const int k1 = (t + 1) * 64;
            #pragma unroll
            for (int p = 0; p < 4; ++p)
                gl2lds16(gA + (size_t)p * 8 * K + k1, nb + lAoff + p * 8 * 64);
            #pragma unroll
            for (int p = 0; p < NT; ++p)
                gl2lds16(gB + (size_t)p * 8 * K + k1, nb + lBoff + p * 8 * 64);
        }

        const ushort* lsA = cb;
        const ushort* lsB = cb + 8192;
        #pragma unroll
        for (int ks = 0; ks < 2; ++ks) {
            bf16x8 af[4], bfr[NT];
            #pragma unroll
            for (int mt = 0; mt < 4; ++mt)
                af[mt] = frag(lsA, wm * 64 + mt * 16 + l16, ks * 4 + quad);
            #pragma unroll
            for (int nt = 0; nt < NT; ++nt)
                bfr[nt] = frag(lsB, wn * NT * 16 + nt * 16 + l16, ks * 4 + quad);
            #pragma unroll
            for (int mt = 0; mt < 4; ++mt)
                #pragma unroll
                for (int nt = 0; nt < NT; ++nt)
                    acc[mt][nt] = __builtin_amdgcn_mfma_f32_16x16x32_bf16(
                        af[mt], bfr[nt], acc[mt][nt], 0, 0, 0);
        }

        __syncthreads();                 // vmcnt(0): prefetch landed; publish
    }
}

// ---------------------------------------------------------------------------
// qkv GEMM v2: 128M x 256N tile, 512 threads / 8 waves (2M x 4N, 64x64 out
// per wave), 2-phase double-buffered (2 x 48KB = 96KB LDS, 1 block/CU),
// XCD m-strip swizzle (288 = 8 XCDs x 36). Rationale (r11 post-mortem):
// same per-CU MFMA work as 2x128^2 blocks but -25% staging bytes, half the
// prologue/epilogue instances, 2x B-panel reuse — attacks the m102 mid-shape
// collapse (~300 TF) of the 128^2 structure.
// Sync is the r11-proven stage->compute->__syncthreads (no counted vmcnt).
// ---------------------------------------------------------------------------
__global__ __launch_bounds__(512, 1) void gemm_qkv_mfma(
    const ushort* __restrict__ Xb, const ushort* __restrict__ Wt,
    ushort* __restrict__ Qb, ushort* __restrict__ Kb, ushort* __restrict__ Vt)
{
    // per buffer: A[128][64] = 8192 ushorts @0, B[256][64] = 16384 @8192
    // BUF = 24576 ushorts (48KB); 2 buffers = 96KB. Epilogue reuses (<=70KB).
    __shared__ __align__(16) ushort ls[49152];

    const int lin = blockIdx.x;                       // 0..287
    const int w   = (lin & 7) * 36 + (lin >> 3);      // bijective XCD chunking
    const int m0  = (w / 9) * 128;
    const int n0  = (w % 9) * 256;
    const int K   = DMODEL;

    const int tid  = threadIdx.x;
    const int lane = tid & 63;
    const int wave = tid >> 6;          // 0..7
    const int wm2  = wave >> 2;         // 0..1  (64-row M slice)
    const int wn4  = wave & 3;          // 0..3  (64-col N slice)
    const int quad = lane >> 4, l16 = lane & 15;

    const int lrow = lane >> 3;          // 0..7
    const int csw  = ((lane & 7) ^ lrow) * 8;   // swizzled global chunk

    const ushort* gA = Xb + (size_t)(m0 + wave * 16 + lrow) * K + csw;
    const ushort* gB = Wt + (size_t)(n0 + wave * 32 + lrow) * K + csw;
    const int lAoff = (wave * 16) * 64;          // A rows wave*16..+15
    const int lBoff = 8192 + (wave * 32) * 64;   // B rows wave*32..+31
    const int BUF = 24576;

    floatx4 acc[4][4] = {};

    // prologue: stage tile 0 into buffer 0 (A: 2 instr/wave, B: 4)
    #pragma unroll
    for (int p = 0; p < 2; ++p)
        gl2lds16(gA + (size_t)p * 8 * K, ls + lAoff + p * 8 * 64);
    #pragma unroll
    for (int p = 0; p < 4; ++p)
        gl2lds16(gB + (size_t)p * 8 * K, ls + lBoff + p * 8 * 64);
    __syncthreads();

    const int NK = K / 64;               // 12
    for (int t = 0; t < NK; ++t) {
        ushort* cb = ls + (t & 1) * BUF;
        ushort* nb = ls + ((t + 1) & 1) * BUF;

        if (t + 1 < NK) {                // issue next tile's DMA (no wait)
            const int k1 = (t + 1) * 64;
            #pragma unroll
            for (int p = 0; p < 2; ++p)
                gl2lds16(gA + (size_t)p * 8 * K + k1, nb + lAoff + p * 8 * 64);
            #pragma unroll
            for (int p = 0; p < 4; ++p)
                gl2lds16(gB + (size_t)p * 8 * K + k1, nb + lBoff + p * 8 * 64);
        }

        const ushort* lsA = cb;
        const ushort* lsB = cb + 8192;
        #pragma unroll
        for (int ks = 0; ks < 2; ++ks) {
            bf16x8 af[4], bfr[4];
            #pragma unroll
            for (int mt = 0; mt < 4; ++mt)
                af[mt] = frag(lsA, wm2 * 64 + mt * 16 + l16, ks * 4 + quad);
            #pragma unroll
            for (int nt = 0; nt < 4; ++nt)
                bfr[nt] = frag(lsB, wn4 * 64 + nt * 16 + l16, ks * 4 + quad);
            #pragma unroll
            for (int mt = 0; mt < 4; ++mt)
                #pragma unroll
                for (int nt = 0; nt < 4; ++nt)
                    acc[mt][nt] = __builtin_amdgcn_mfma_f32_16x16x32_bf16(
                        af[mt], bfr[nt], acc[mt][nt], 0, 0, 0);
        }

        __syncthreads();                 // prefetch landed; publish
    }

    // ---- epilogue ----
    if (n0 < 2 * DMODEL) {
        // Q or K tile (256 cols within one of Q/K: 768 = 3*256 exact)
        const float scale = (n0 < DMODEL) ? QSCALE_LOG2E : 1.0f;
        ushort* outp = (n0 < DMODEL) ? Qb : Kb;
        const int colg = (n0 < DMODEL) ? n0 : n0 - DMODEL;
        // retile [128][264] (67.5KB, fits the 96KB buffer)
        #pragma unroll
        for (int mt = 0; mt < 4; ++mt)
            #pragma unroll
            for (int nt = 0; nt < 4; ++nt) {
                const int row = wm2 * 64 + mt * 16 + quad * 4;
                const int col = wn4 * 64 + nt * 16 + l16;
                #pragma unroll
                for (int r = 0; r < 4; ++r)
                    ls[(row + r) * 264 + col] = f2bf(acc[mt][nt][r] * scale);
            }
        __syncthreads();
        #pragma unroll
        for (int p2 = 0; p2 < 8; ++p2) {
            const int row = (tid >> 5) + p2 * 16;     // 0..127
            const int c16 = (tid & 31) * 8;           // 0..248
            *(uint4*)(outp + (size_t)(m0 + row) * DMODEL + colg + c16) =
                *(const uint4*)(ls + row * 264 + c16);
        }
    } else {
        // V transposed tile: 256 hd-rows x 128 tokens; retile [256][136]
        const int hd0 = n0 - 2 * DMODEL;              // 0 / 256 / 512
        #pragma unroll
        for (int mt = 0; mt < 4; ++mt)
            #pragma unroll
            for (int nt = 0; nt < 4; ++nt) {
                const int hd  = wn4 * 64 + nt * 16 + l16;      // 0..255
                const int tok = wm2 * 64 + mt * 16 + quad * 4; // 0..127
                #pragma unroll
                for (int r = 0; r < 4; ++r)
                    ls[hd * 136 + tok + r] = f2bf(acc[mt][nt][r]);
            }
        __syncthreads();
        #pragma unroll
        for (int p2 = 0; p2 < 8; ++p2) {
            const int row = (tid >> 4) + p2 * 32;     // 0..255 (local hd)
            const int c8  = (tid & 15) * 8;           // 0..120 (token chunk)
            *(uint4*)(Vt + (size_t)(hd0 + row) * TOKENS + m0 + c8) =
                *(const uint4*)(ls + row * 136 + c8);
        }
    }
}

// ---------------------------------------------------------------------------
// proj GEMM: 128x64 tiles, XCD m-strip swizzle (384 = 8 x 48),
// 2-phase double-buffered body (48 KB LDS). Unchanged from r11.
// ---------------------------------------------------------------------------
__global__ __launch_bounds__(256) void gemm_proj_mfma(
    const ushort* __restrict__ Ab, const ushort* __restrict__ Wt,
    const float* __restrict__ bias, float* __restrict__ out)
{
    __shared__ __align__(16) ushort ls[24576];   // 48 KB: 2 x 24 KB tile bufs
    const int lin = blockIdx.x + blockIdx.y * 12;
    const int w   = (lin & 7) * 48 + (lin >> 3);
    const int m0  = (w / 12) * 128;
    const int n0  = (w % 12) * 64;

    floatx4 acc[4][2] = {};
    gemm_body_2ph<2>(Ab, Wt, DMODEL, m0, n0, acc, ls);

    const int lane = threadIdx.x & 63;
    const int wave = threadIdx.x >> 6;
    const int wm = wave >> 1, wn = wave & 1;
    const int quad = lane >> 4, l16 = lane & 15;
    const int row0 = m0 + wm * 64 + quad * 4;
    const int col0 = n0 + wn * 32;

    #pragma unroll
    for (int nt = 0; nt < 2; ++nt) {
        const int col = col0 + nt * 16 + l16;
        const float bv = bias[col];
        #pragma unroll
        for (int mt = 0; mt < 4; ++mt)
            #pragma unroll
            for (int r = 0; r < 4; ++r)
                out[(size_t)(row0 + mt * 16 + r) * DMODEL + col] =
                    acc[mt][nt][r] + bv;
    }
}

// ---------------------------------------------------------------------------
// MFMA flash attention — r10/r11-verified kernel VERBATIM (attn ~77us =
// structural floor of this design per r7/r9/r10/r11 quadrangulation).
// ---------------------------------------------------------------------------
__global__ __launch_bounds__(256, 3) void attn_mfma_kernel(
    const ushort* __restrict__ Qb, const ushort* __restrict__ Kb,
    const ushort* __restrict__ Vt, ushort* __restrict__ attn_out)
{
    // main loop: 4 waves x 6144 ushorts (K0,K1 @0,1024; V0..V3 @2048+s*1024)
    // epilogue:  3 x [64][66] f32 + 192 f32 = 12864 floats = 25728 ushorts
    __shared__ __align__(16) ushort lds[25728];   // 51.5 KB

    const int tid  = threadIdx.x;
    const int wave = tid >> 6;
    const int lane = tid & 63;
    const int quad = lane >> 4;
    const int l16  = lane & 15;

    // XCD head-locality swizzle (bijective: 768 = 8 XCDs x 96 blocks)
    const int lin = blockIdx.x + blockIdx.y * 64;    // dispatch-linear id
    const int wsw = (lin & 7) * 96 + (lin >> 3);     // chunked per-XCD remap
    const int h   = wsw >> 6;                        // head 0..11
    const int i0  = (wsw & 63) * 64;                 // query-tile base

    // Q fragments: all 4 q-tiles register-resident (B-operand: col=l16)
    bf16x8 qf[4][2];
    #pragma unroll
    for (int jt = 0; jt < 4; ++jt) {
        const ushort* qb = Qb + (size_t)(i0 + jt * 16 + l16) * DMODEL + h * HDIM;
        qf[jt][0] = *(const bf16x8*)(qb + quad * 8);
        qf[jt][1] = *(const bf16x8*)(qb + 32 + quad * 8);
    }

    bf16x8 ones;
    #pragma unroll
    for (int i = 0; i < 8; ++i) ones[i] = (short)0x3F80;   // bf16 1.0

    floatx4 O[4][4] = {};    // [q-tile][d-tile], partial over this wave's keys
    floatx4 Ol[4]   = {};    // [q-tile] partial row-sums

    ushort* wls = lds + wave * 6144;                 // private region

    // K staging source (3-bit XOR chunk pre-swizzle; wave's key = t*64+wave*16+row)
    const int lrow8 = lane >> 3;                     // 0..7
    const int csw8  = ((lane & 7) ^ lrow8) * 8;
    const ushort* gK0 = Kb + (size_t)(wave * 16 + lrow8) * DMODEL + h * HDIM + csw8;
    const ushort* gK1 = gK0 + (size_t)8 * DMODEL;

    // V staging source: lane -> d=lane>>1, PHYSICAL tok-pair=lane&1 holds
    // LOGICAL pair (lane&1)^((d>>2)&1) = (lane&1)^((lane>>3)&1)
    const ushort* gV0 = Vt + (size_t)(h * HDIM + (lane >> 1)) * TOKENS
                           + wave * 16 + (((lane & 1) ^ ((lane >> 3) & 1)) * 8);
    const ushort* gV1 = gV0 + (size_t)32 * TOKENS;

    // V read offset (loop-invariant): logical pair quad>>1 of row nt*16+l16
    // sits at physical pair (quad>>1)^((l16>>2)&1); 8B half = quad&1
    const int vo = ((quad >> 1) ^ ((l16 >> 2) & 1)) * 8 + (quad & 1) * 4;

    // persistent P operand, packed across an even/odd chunk pair
    union { bf16x8 v; unsigned u[4]; } pa[4];

    // prologue: stage t=0 (K -> buf0, V -> slot0); 4 DMA outstanding
    gl2lds16(gK0, wls);
    gl2lds16(gK1, wls + 512);
    gl2lds16(gV0, wls + 2048);
    gl2lds16(gV1, wls + 2048 + 512);

    for (int u = 0; u < 32; ++u) {                   // pair u: t0=2u, t1=2u+1
        const int s0 = (u & 1) << 1;                 // V slot of t0 (0 or 2)
        ushort* Kc0 = wls;
        ushort* Kc1 = wls + 1024;
        ushort* V0  = wls + 2048 + s0 * 1024;
        ushort* V1  = wls + 2048 + (s0 + 1) * 1024;
        ushort* Vn  = wls + 2048 + ((s0 + 2) & 3) * 1024;

        // ======== t0 = 2u (even): prefetch t1, QK on Kc0 -> pa low half ====
        {
            const size_t t1 = (size_t)(2 * u + 1) * 64;
            gl2lds16(gK0 + t1 * DMODEL, Kc1);
            gl2lds16(gK1 + t1 * DMODEL, Kc1 + 512);
            gl2lds16(gV0 + t1, V1);
            gl2lds16(gV1 + t1, V1 + 512);
        }
        asm volatile("s_waitcnt vmcnt(4)" ::: "memory");   // t0's 4 DMA done

        {
            const bf16x8 a0 = frag(Kc0, l16, quad);
            const bf16x8 a1 = frag(Kc0, l16, 4 + quad);
            __builtin_amdgcn_s_setprio(1);
            #pragma unroll
            for (int jt = 0; jt < 4; ++jt) {
                floatx4 s = {0.f, 0.f, 0.f, 0.f};
                s = __builtin_amdgcn_mfma_f32_16x16x32_bf16(a0, qf[jt][0], s, 0, 0, 0);
                s = __builtin_amdgcn_mfma_f32_16x16x32_bf16(a1, qf[jt][1], s, 0, 0, 0);
                pa[jt].u[0] = cvt_pk_bf16(__builtin_amdgcn_exp2f(s[0]),
                                          __builtin_amdgcn_exp2f(s[1]));
                pa[jt].u[1] = cvt_pk_bf16(__builtin_amdgcn_exp2f(s[2]),
                                          __builtin_amdgcn_exp2f(s[3]));
            }
            __builtin_amdgcn_s_setprio(0);
        }

        // ======== t1 = 2u+1 (odd): prefetch next t0, QK on Kc1 -> pa high,
        //          then PV + Ol over the 32-key pair ========================
        if (u < 31) {
            const size_t t2 = (size_t)(2 * u + 2) * 64;
            gl2lds16(gK0 + t2 * DMODEL, Kc0);
            gl2lds16(gK1 + t2 * DMODEL, Kc0 + 512);
            gl2lds16(gV0 + t2, Vn);
            gl2lds16(gV1 + t2, Vn + 512);
            asm volatile("s_waitcnt vmcnt(4)" ::: "memory");  // t1's 4 DMA done
        } else {
            asm volatile("s_waitcnt vmcnt(0)" ::: "memory");
        }

        {
            const bf16x8 a0 = frag(Kc1, l16, quad);
            const bf16x8 a1 = frag(Kc1, l16, 4 + quad);
            __builtin_amdgcn_s_setprio(1);
            #pragma unroll
            for (int jt = 0; jt < 4; ++jt) {
                floatx4 s = {0.f, 0.f, 0.f, 0.f};
                s = __builtin_amdgcn_mfma_f32_16x16x32_bf16(a0, qf[jt][0], s, 0, 0, 0);
                s = __builtin_amdgcn_mfma_f32_16x16x32_bf16(a1, qf[jt][1], s, 0, 0, 0);
                pa[jt].u[2] = cvt_pk_bf16(__builtin_amdgcn_exp2f(s[0]),
                                          __builtin_amdgcn_exp2f(s[1]));
                pa[jt].u[3] = cvt_pk_bf16(__builtin_amdgcn_exp2f(s[2]),
                                          __builtin_amdgcn_exp2f(s[3]));
            }
            __builtin_amdgcn_s_setprio(0);
        }

        __builtin_amdgcn_s_setprio(1);
        #pragma unroll
        for (int nt = 0; nt < 4; ++nt) {
            const int ro = (nt * 16 + l16) * 16 + vo;   // pair-swizzled slot
            union { bf16x8 v; uint2 d[2]; } vu;
            vu.d[0] = *(const uint2*)(V0 + ro);   // even-chunk tokens (k-slots 0-3)
            vu.d[1] = *(const uint2*)(V1 + ro);   // odd-chunk tokens  (k-slots 4-7)
            #pragma unroll
            for (int jt = 0; jt < 4; ++jt)
                O[jt][nt] = __builtin_amdgcn_mfma_f32_16x16x32_bf16(
                    pa[jt].v, vu.v, O[jt][nt], 0, 0, 0);
        }
        #pragma unroll
        for (int jt = 0; jt < 4; ++jt)
            Ol[jt] = __builtin_amdgcn_mfma_f32_16x16x32_bf16(
                pa[jt].v, ones, Ol[jt], 0, 0, 0);
        __builtin_amdgcn_s_setprio(0);
    }

    // ---- cross-wave reduction + store (proven 4-way epilogue) ----
    __syncthreads();                       // all compute done, LDS reusable
    float* Of  = (float*)lds;              // 3 regions of [64][66] f32
    float* Olf = ((float*)lds) + 3 * 64 * 66;   // 3 x [64] f32
    if (wave != 0) {
        const int rg = (wave - 1) * 64 * 66;
        #pragma unroll
        for (int jt = 0; jt < 4; ++jt) {
            #pragma unroll
            for (int nt = 0; nt < 4; ++nt)
                #pragma unroll
                for (int r = 0; r < 4; ++r)
                    Of[rg + (jt * 16 + quad * 4 + r) * 66 + nt * 16 + l16] = O[jt][nt][r];
            if (l16 == 0) {
                #pragma unroll
                for (int r = 0; r < 4; ++r)
                    Olf[(wave - 1) * 64 + jt * 16 + quad * 4 + r] = Ol[jt][r];
            }
        }
    }
    __syncthreads();
    if (wave == 0) {
        #pragma unroll
        for (int jt = 0; jt < 4; ++jt) {
            const int qr = jt * 16 + quad * 4;
            float linv[4];
            #pragma unroll
            for (int r = 0; r < 4; ++r) {
                const float l = Ol[jt][r] + Olf[qr + r] + Olf[64 + qr + r]
                              + Olf[128 + qr + r];
                linv[r] = __builtin_amdgcn_rcpf(l);
            }
            #pragma unroll
            for (int nt = 0; nt < 4; ++nt) {
                const int d = h * HDIM + nt * 16 + l16;
                #pragma unroll
                for (int r = 0; r < 4; ++r) {
                    const float o = O[jt][nt][r]
                        + Of[(qr + r) * 66 + nt * 16 + l16]
                        + Of[64 * 66 + (qr + r) * 66 + nt * 16 + l16]
                        + Of[2 * 64 * 66 + (qr + r) * 66 + nt * 16 + l16];
                    attn_out[(size_t)(i0 + qr + r) * DMODEL + d] = f2bf(o * linv[r]);
                }
            }
        }
    }
}

// ---------------------------------------------------------------------------
extern "C" void kernel_launch(void* const* d_in, const int* in_sizes, int n_in,
                              void* d_out, int out_size, void* d_ws, size_t ws_size,
                              hipStream_t stream)
{
    const float* x     = (const float*)d_in[0];
    const float* Wqkv  = (const float*)d_in[1];
    const float* Wproj = (const float*)d_in[2];
    const float* bproj = (const float*)d_in[3];
    float* out = (float*)d_out;

    ushort* Xb     = (ushort*)d_ws;                          // [4096][768]
    ushort* WqkvT  = Xb    + (size_t)TOKENS * DMODEL;        // [2304][768]
    ushort* WprojT = WqkvT + (size_t)QKV_N * DMODEL;         // [768][768]
    ushort* Qb     = WprojT + (size_t)DMODEL * DMODEL;       // [4096][768]
    ushort* Kb     = Qb    + (size_t)TOKENS * DMODEL;        // [4096][768]
    ushort* Vt     = Kb    + (size_t)TOKENS * DMODEL;        // [768][4096]
    ushort* attn   = Vt    + (size_t)TOKENS * DMODEL;        // [4096][768]

    prep_kernel<<<dim3(5376), 256, 0, stream>>>(
        x, Wqkv, Wproj, Xb, WqkvT, WprojT);

    gemm_qkv_mfma<<<dim3(288), 512, 0, stream>>>(
        Xb, WqkvT, Qb, Kb, Vt);

    attn_mfma_kernel<<<dim3(TOKENS / 64, NHEADS), 256, 0, stream>>>(
        Qb, Kb, Vt, attn);

    gemm_proj_mfma<<<dim3(DMODEL / 64, TOKENS / 128), 256, 0, stream>>>(
        attn, WprojT, bproj, out);
}

// Round 13
// 176.564 us; speedup vs baseline: 1.1501x; 1.0204x over previous
//
#include <hip/hip_runtime.h>
#include <math.h>

#define TOKENS 4096
#define DMODEL 768
#define NHEADS 12
#define HDIM   64
#define QKV_N  2304          // 3*DMODEL
#define ATTN_SCALE 0.125f    // HDIM^-0.5
// fold log2(e) into Q so softmax uses v_exp_f32 (2^x) directly
#define QSCALE_LOG2E (0.125f * 1.44269504088896340736f)

typedef __attribute__((ext_vector_type(8))) short bf16x8;   // 8 bf16 = 4 VGPRs
typedef __attribute__((ext_vector_type(4))) float floatx4;

__device__ __forceinline__ ushort f2bf(float f) {
    union { float f; unsigned u; } cv; cv.f = f;
    unsigned u = cv.u;
    u += 0x7fffu + ((u >> 16) & 1u);   // round-to-nearest-even
    return (ushort)(u >> 16);
}

// pack two fp32 -> two bf16 (RNE) in one dword via v_cvt_pk_bf16_f32
__device__ __forceinline__ unsigned cvt_pk_bf16(float a, float b) {
    unsigned r;
    asm("v_cvt_pk_bf16_f32 %0, %1, %2" : "=v"(r) : "v"(a), "v"(b));
    return r;
}

// async 16B global->LDS (lane i lands at ldsbase + i*16)
__device__ __forceinline__ void gl2lds16(const ushort* g, ushort* l) {
    __builtin_amdgcn_global_load_lds(
        (const __attribute__((address_space(1))) void*)g,
        (__attribute__((address_space(3))) void*)l, 16, 0, 0);
}

// fragment read (64-ushort rows): logical chunk c of row r at phys (c ^ (r&7))
__device__ __forceinline__ bf16x8 frag(const ushort* ls, int row, int chunk) {
    return *(const bf16x8*)(ls + row * 64 + ((chunk ^ (row & 7)) * 8));
}

// fragment read (32-ushort rows, BK=32): phys chunk = c ^ (row&3), c in 0..3
__device__ __forceinline__ bf16x8 frag32(const ushort* ls, int row, int chunk) {
    return *(const bf16x8*)(ls + row * 32 + ((chunk ^ (row & 3)) * 8));
}

// ---------------------------------------------------------------------------
// fused prep: fp32->bf16 cvt of x  +  both weight transpose-converts.
// ---------------------------------------------------------------------------
__global__ __launch_bounds__(256) void prep_kernel(
    const float* __restrict__ x, const float* __restrict__ Wqkv,
    const float* __restrict__ Wproj, ushort* __restrict__ Xb,
    ushort* __restrict__ WqkvT, ushort* __restrict__ WprojT)
{
    __shared__ ushort tile[32][33];
    const int bid = blockIdx.x;
    const int tid = threadIdx.x;

    if (bid < 3072) {                     // ---- cvt x: 3072*256*4 = 4096*768
        const int i = bid * 256 + tid;
        const float4 v = ((const float4*)x)[i];
        ushort4 h;
        h.x = f2bf(v.x); h.y = f2bf(v.y); h.z = f2bf(v.z); h.w = f2bf(v.w);
        ((ushort4*)Xb)[i] = h;
        return;
    }

    const float* in; ushort* out; int C, bx, by;
    if (bid < 3072 + 1728) {              // ---- Wqkv [768][2304] -> [2304][768]
        const int b = bid - 3072;
        in = Wqkv; out = WqkvT; C = QKV_N;
        bx = b % 72; by = b / 72;
    } else {                              // ---- Wproj [768][768] -> [768][768]
        const int b = bid - 4800;
        in = Wproj; out = WprojT; C = DMODEL;
        bx = b % 24; by = b / 24;
    }
    const int R  = DMODEL;
    const int tx = tid & 31;
    const int ty8 = tid >> 5;             // 0..7
    const int c0 = bx * 32;
    const int r0 = by * 32;
    #pragma unroll
    for (int p = 0; p < 4; ++p) {
        const int r = ty8 + p * 8;
        tile[r][tx] = f2bf(in[(size_t)(r0 + r) * C + c0 + tx]);
    }
    __syncthreads();
    #pragma unroll
    for (int p = 0; p < 4; ++p) {
        const int c = ty8 + p * 8;
        out[(size_t)(c0 + c) * R + r0 + tx] = tile[tx][c];
    }
}

// ---------------------------------------------------------------------------
// MFMA GEMM body — 2-PHASE double-buffered, BK=64 (r11-verified). proj uses.
// ---------------------------------------------------------------------------
template<int NT>
__device__ __forceinline__ void gemm_body_2ph(
    const ushort* __restrict__ A, const ushort* __restrict__ Bt, int K,
    int m0, int n0, floatx4 acc[4][NT], ushort* ls)
{
    const int BUF = 8192 + 2048 * NT;    // ushorts per buffer

    const int tid  = threadIdx.x;
    const int lane = tid & 63;
    const int wave = tid >> 6;
    const int wm = wave >> 1, wn = wave & 1;
    const int quad = lane >> 4, l16 = lane & 15;

    const int lrow = lane >> 3;          // 0..7
    const int csw  = ((lane & 7) ^ lrow) * 8;   // swizzled global chunk (ushorts)

    const ushort* gA = A  + (size_t)(m0 + wave * 32 + lrow) * K + csw;
    const ushort* gB = Bt + (size_t)(n0 + wave * NT * 8 + lrow) * K + csw;
    const int lAoff = (wave * 32) * 64;
    const int lBoff = 8192 + (wave * NT * 8) * 64;

    // prologue: stage tile 0 into buffer 0
    #pragma unroll
    for (int p = 0; p < 4; ++p)
        gl2lds16(gA + (size_t)p * 8 * K, ls + lAoff + p * 8 * 64);
    #pragma unroll
    for (int p = 0; p < NT; ++p)
        gl2lds16(gB + (size_t)p * 8 * K, ls + lBoff + p * 8 * 64);
    __syncthreads();                     // drain + publish tile 0

    const int NK = K / 64;
    for (int t = 0; t < NK; ++t) {
        ushort* cb = ls + (t & 1) * BUF;
        ushort* nb = ls + ((t + 1) & 1) * BUF;

        if (t + 1 < NK) {                // issue next tile's DMA (no wait)
            const int k1 = (t + 1) * 64;
            #pragma unroll
            for (int p = 0; p < 4; ++p)
                gl2lds16(gA + (size_t)p * 8 * K + k1, nb + lAoff + p * 8 * 64);
            #pragma unroll
            for (int p = 0; p < NT; ++p)
                gl2lds16(gB + (size_t)p * 8 * K + k1, nb + lBoff + p * 8 * 64);
        }

        const ushort* lsA = cb;
        const ushort* lsB = cb + 8192;
        #pragma unroll
        for (int ks = 0; ks < 2; ++ks) {
            bf16x8 af[4], bfr[NT];
            #pragma unroll
            for (int mt = 0; mt < 4; ++mt)
                af[mt] = frag(lsA, wm * 64 + mt * 16 + l16, ks * 4 + quad);
            #pragma unroll
            for (int nt = 0; nt < NT; ++nt)
                bfr[nt] = frag(lsB, wn * NT * 16 + nt * 16 + l16, ks * 4 + quad);
            #pragma unroll
            for (int mt = 0; mt < 4; ++mt)
                #pragma unroll
                for (int nt = 0; nt < NT; ++nt)
                    acc[mt][nt] = __builtin_amdgcn_mfma_f32_16x16x32_bf16(
                        af[mt], bfr[nt], acc[mt][nt], 0, 0, 0);
        }

        __syncthreads();                 // vmcnt(0): prefetch landed; publish
    }
}

// ---------------------------------------------------------------------------
// MFMA GEMM body — 2-PHASE double-buffered, BK=32 (lean-LDS variant).
// Buffers: A[128][32] = 4096 ushorts @0, B[NT*32][32] @4096; BUF = 4096+1024*NT.
// For NT=4: 16 KB/buffer, 32 KB both -> with the 34 KB epilogue union the
// block is 34.8 KB -> 3+ blocks/CU co-resident (the r12 post-mortem lever:
// qkv was block-wave-packing-bound, capacity 1-2 vs 2.25 avg blocks/CU).
// Staging: 16 rows per 1KB DMA; lane -> row lane>>2, phys slot lane&3 holds
// logical chunk (lane&3)^((lane>>2)&3); read via frag32. No counted vmcnt.
// ---------------------------------------------------------------------------
template<int NT>
__device__ __forceinline__ void gemm_body_2ph32(
    const ushort* __restrict__ A, const ushort* __restrict__ Bt, int K,
    int m0, int n0, floatx4 acc[4][NT], ushort* ls)
{
    const int BUF = 4096 + 1024 * NT;    // ushorts per buffer

    const int tid  = threadIdx.x;
    const int lane = tid & 63;
    const int wave = tid >> 6;
    const int wm = wave >> 1, wn = wave & 1;
    const int quad = lane >> 4, l16 = lane & 15;

    const int lrow = lane >> 2;          // 0..15
    const int csw  = ((lane & 3) ^ (lrow & 3)) * 8;   // 2-bit XOR pre-swizzle

    const ushort* gA = A  + (size_t)(m0 + wave * 32 + lrow) * K + csw;
    const ushort* gB = Bt + (size_t)(n0 + wave * NT * 8 + lrow) * K + csw;
    const int lAoff = wave * 1024;               // 32 rows * 32 ushorts
    const int lBoff = 4096 + wave * NT * 256;    // NT*8 rows * 32 ushorts

    // prologue: stage tile 0 into buffer 0
    #pragma unroll
    for (int p = 0; p < 2; ++p)
        gl2lds16(gA + (size_t)p * 16 * K, ls + lAoff + p * 512);
    #pragma unroll
    for (int p = 0; p < NT / 2; ++p)
        gl2lds16(gB + (size_t)p * 16 * K, ls + lBoff + p * 512);
    __syncthreads();

    const int NK = K / 32;
    for (int t = 0; t < NK; ++t) {
        ushort* cb = ls + (t & 1) * BUF;
        ushort* nb = ls + ((t + 1) & 1) * BUF;

        if (t + 1 < NK) {                // issue next tile's DMA (no wait)
            const int k1 = (t + 1) * 32;
            #pragma unroll
            for (int p = 0; p < 2; ++p)
                gl2lds16(gA + (size_t)p * 16 * K + k1, nb + lAoff + p * 512);
            #pragma unroll
            for (int p = 0; p < NT / 2; ++p)
                gl2lds16(gB + (size_t)p * 16 * K + k1, nb + lBoff + p * 512);
        }

        const ushort* lsA = cb;
        const ushort* lsB = cb + 4096;
        bf16x8 af[4], bfr[NT];
        #pragma unroll
        for (int mt = 0; mt < 4; ++mt)
            af[mt] = frag32(lsA, wm * 64 + mt * 16 + l16, quad);
        #pragma unroll
        for (int nt = 0; nt < NT; ++nt)
            bfr[nt] = frag32(lsB, wn * NT * 16 + nt * 16 + l16, quad);
        #pragma unroll
        for (int mt = 0; mt < 4; ++mt)
            #pragma unroll
            for (int nt = 0; nt < NT; ++nt)
                acc[mt][nt] = __builtin_amdgcn_mfma_f32_16x16x32_bf16(
                    af[mt], bfr[nt], acc[mt][nt], 0, 0, 0);

        __syncthreads();                 // prefetch landed; publish
    }
}

// ---------------------------------------------------------------------------
// qkv GEMM v4: back to the r11-proven 128x128 / 576-block structure, with the
// BK=32 body -> 34.8 KB LDS -> 3 blocks/CU capacity (launch_bounds(256,3)).
// 576 blocks at 2.25 avg/CU now fully co-resident in ONE dispatch wave
// (r12's capacity-1 forced 2 serial block-waves = the measured plateau).
// XCD m-strip swizzle (576 = 8 XCDs x 72) + single-pass retile epilogue.
// ---------------------------------------------------------------------------
__global__ __launch_bounds__(256, 3) void gemm_qkv_mfma(
    const ushort* __restrict__ Xb, const ushort* __restrict__ Wt,
    ushort* __restrict__ Qb, ushort* __restrict__ Kb, ushort* __restrict__ Vt)
{
    // bufs: 2 x 8192 ushorts (32 KB) | epilogue retile [128][136] = 17408
    __shared__ __align__(16) ushort ls[17408];   // 34.8 KB
    const int lin = blockIdx.x + blockIdx.y * 18;     // dispatch-linear id
    const int w   = (lin & 7) * 72 + (lin >> 3);      // bijective XCD chunking
    const int m0  = (w / 18) * 128;
    const int n0  = (w % 18) * 128;

    floatx4 acc[4][4] = {};
    gemm_body_2ph32<4>(Xb, Wt, DMODEL, m0, n0, acc, ls);

    const int tid  = threadIdx.x;
    const int lane = tid & 63;
    const int wave = tid >> 6;
    const int wm = wave >> 1, wn = wave & 1;
    const int quad = lane >> 4, l16 = lane & 15;

    if (n0 < 2 * DMODEL) {
        // ---- Q or K: single pass over all 128 rows ----
        const float scale = (n0 < DMODEL) ? QSCALE_LOG2E : 1.0f;
        ushort* outp = (n0 < DMODEL) ? Qb : Kb;
        const int colg = (n0 < DMODEL) ? n0 : n0 - DMODEL;
        __syncthreads();                    // all waves done with GEMM tiles
        #pragma unroll
        for (int mt = 0; mt < 4; ++mt)
            #pragma unroll
            for (int nt = 0; nt < 4; ++nt) {
                const int row = wm * 64 + mt * 16 + quad * 4;
                const int col = wn * 64 + nt * 16 + l16;
                #pragma unroll
                for (int r = 0; r < 4; ++r)
                    ls[(row + r) * 136 + col] = f2bf(acc[mt][nt][r] * scale);
            }
        __syncthreads();
        #pragma unroll
        for (int p2 = 0; p2 < 8; ++p2) {
            const int row = (tid >> 4) + p2 * 16;
            const int c8  = (tid & 15) * 8;
            *(uint4*)(outp + (size_t)(m0 + row) * DMODEL + colg + c8) =
                *(const uint4*)(ls + row * 136 + c8);
        }
    } else {
        // ---- V transposed: single pass over all 128 hd-rows ----
        const int hd0 = n0 - 2 * DMODEL;
        __syncthreads();
        #pragma unroll
        for (int mt = 0; mt < 4; ++mt)
            #pragma unroll
            for (int nt = 0; nt < 4; ++nt) {
                const int hd  = wn * 64 + nt * 16 + l16;
                const int tok = wm * 64 + mt * 16 + quad * 4;
                #pragma unroll
                for (int r = 0; r < 4; ++r)
                    ls[hd * 136 + tok + r] = f2bf(acc[mt][nt][r]);
            }
        __syncthreads();
        #pragma unroll
        for (int p2 = 0; p2 < 8; ++p2) {
            const int row = (tid >> 4) + p2 * 16;    // local hd
            const int c8  = (tid & 15) * 8;          // token chunk
            *(uint4*)(Vt + (size_t)(hd0 + row) * TOKENS + m0 + c8) =
                *(const uint4*)(ls + row * 136 + c8);
        }
    }
}

// ---------------------------------------------------------------------------
// proj GEMM: 128x64 tiles, XCD m-strip swizzle (384 = 8 x 48),
// 2-phase double-buffered BK=64 body (48 KB LDS, 3/CU capacity vs 1.5 avg —
// already packed). Unchanged from r11/r12.
// ---------------------------------------------------------------------------
__global__ __launch_bounds__(256) void gemm_proj_mfma(
    const ushort* __restrict__ Ab, const ushort* __restrict__ Wt,
    const float* __restrict__ bias, float* __restrict__ out)
{
    __shared__ __align__(16) ushort ls[24576];   // 48 KB: 2 x 24 KB tile bufs
    const int lin = blockIdx.x + blockIdx.y * 12;
    const int w   = (lin & 7) * 48 + (lin >> 3);
    const int m0  = (w / 12) * 128;
    const int n0  = (w % 12) * 64;

    floatx4 acc[4][2] = {};
    gemm_body_2ph<2>(Ab, Wt, DMODEL, m0, n0, acc, ls);

    const int lane = threadIdx.x & 63;
    const int wave = threadIdx.x >> 6;
    const int wm = wave >> 1, wn = wave & 1;
    const int quad = lane >> 4, l16 = lane & 15;
    const int row0 = m0 + wm * 64 + quad * 4;
    const int col0 = n0 + wn * 32;

    #pragma unroll
    for (int nt = 0; nt < 2; ++nt) {
        const int col = col0 + nt * 16 + l16;
        const float bv = bias[col];
        #pragma unroll
        for (int mt = 0; mt < 4; ++mt)
            #pragma unroll
            for (int r = 0; r < 4; ++r)
                out[(size_t)(row0 + mt * 16 + r) * DMODEL + col] =
                    acc[mt][nt][r] + bv;
    }
}

// ---------------------------------------------------------------------------
// MFMA flash attention — r10/r11/r12-verified kernel VERBATIM (attn ~77us =
// structural floor of this design per r7/r9/r10/r11/r12).
// ---------------------------------------------------------------------------
__global__ __launch_bounds__(256, 3) void attn_mfma_kernel(
    const ushort* __restrict__ Qb, const ushort* __restrict__ Kb,
    const ushort* __restrict__ Vt, ushort* __restrict__ attn_out)
{
    // main loop: 4 waves x 6144 ushorts (K0,K1 @0,1024; V0..V3 @2048+s*1024)
    // epilogue:  3 x [64][66] f32 + 192 f32 = 12864 floats = 25728 ushorts
    __shared__ __align__(16) ushort lds[25728];   // 51.5 KB

    const int tid  = threadIdx.x;
    const int wave = tid >> 6;
    const int lane = tid & 63;
    const int quad = lane >> 4;
    const int l16  = lane & 15;

    // XCD head-locality swizzle (bijective: 768 = 8 XCDs x 96 blocks)
    const int lin = blockIdx.x + blockIdx.y * 64;    // dispatch-linear id
    const int wsw = (lin & 7) * 96 + (lin >> 3);     // chunked per-XCD remap
    const int h   = wsw >> 6;                        // head 0..11
    const int i0  = (wsw & 63) * 64;                 // query-tile base

    // Q fragments: all 4 q-tiles register-resident (B-operand: col=l16)
    bf16x8 qf[4][2];
    #pragma unroll
    for (int jt = 0; jt < 4; ++jt) {
        const ushort* qb = Qb + (size_t)(i0 + jt * 16 + l16) * DMODEL + h * HDIM;
        qf[jt][0] = *(const bf16x8*)(qb + quad * 8);
        qf[jt][1] = *(const bf16x8*)(qb + 32 + quad * 8);
    }

    bf16x8 ones;
    #pragma unroll
    for (int i = 0; i < 8; ++i) ones[i] = (short)0x3F80;   // bf16 1.0

    floatx4 O[4][4] = {};    // [q-tile][d-tile], partial over this wave's keys
    floatx4 Ol[4]   = {};    // [q-tile] partial row-sums

    ushort* wls = lds + wave * 6144;                 // private region

    // K staging source (3-bit XOR chunk pre-swizzle; wave's key = t*64+wave*16+row)
    const int lrow8 = lane >> 3;                     // 0..7
    const int csw8  = ((lane & 7) ^ lrow8) * 8;
    const ushort* gK0 = Kb + (size_t)(wave * 16 + lrow8) * DMODEL + h * HDIM + csw8;
    const ushort* gK1 = gK0 + (size_t)8 * DMODEL;

    // V staging source: lane -> d=lane>>1, PHYSICAL tok-pair=lane&1 holds
    // LOGICAL pair (lane&1)^((d>>2)&1) = (lane&1)^((lane>>3)&1)
    const ushort* gV0 = Vt + (size_t)(h * HDIM + (lane >> 1)) * TOKENS
                           + wave * 16 + (((lane & 1) ^ ((lane >> 3) & 1)) * 8);
    const ushort* gV1 = gV0 + (size_t)32 * TOKENS;

    // V read offset (loop-invariant): logical pair quad>>1 of row nt*16+l16
    // sits at physical pair (quad>>1)^((l16>>2)&1); 8B half = quad&1
    const int vo = ((quad >> 1) ^ ((l16 >> 2) & 1)) * 8 + (quad & 1) * 4;

    // persistent P operand, packed across an even/odd chunk pair
    union { bf16x8 v; unsigned u[4]; } pa[4];

    // prologue: stage t=0 (K -> buf0, V -> slot0); 4 DMA outstanding
    gl2lds16(gK0, wls);
    gl2lds16(gK1, wls + 512);
    gl2lds16(gV0, wls + 2048);
    gl2lds16(gV1, wls + 2048 + 512);

    for (int u = 0; u < 32; ++u) {                   // pair u: t0=2u, t1=2u+1
        const int s0 = (u & 1) << 1;                 // V slot of t0 (0 or 2)
        ushort* Kc0 = wls;
        ushort* Kc1 = wls + 1024;
        ushort* V0  = wls + 2048 + s0 * 1024;
        ushort* V1  = wls + 2048 + (s0 + 1) * 1024;
        ushort* Vn  = wls + 2048 + ((s0 + 2) & 3) * 1024;

        // ======== t0 = 2u (even): prefetch t1, QK on Kc0 -> pa low half ====
        {
            const size_t t1 = (size_t)(2 * u + 1) * 64;
            gl2lds16(gK0 + t1 * DMODEL, Kc1);
            gl2lds16(gK1 + t1 * DMODEL, Kc1 + 512);
            gl2lds16(gV0 + t1, V1);
            gl2lds16(gV1 + t1, V1 + 512);
        }
        asm volatile("s_waitcnt vmcnt(4)" ::: "memory");   // t0's 4 DMA done

        {
            const bf16x8 a0 = frag(Kc0, l16, quad);
            const bf16x8 a1 = frag(Kc0, l16, 4 + quad);
            __builtin_amdgcn_s_setprio(1);
            #pragma unroll
            for (int jt = 0; jt < 4; ++jt) {
                floatx4 s = {0.f, 0.f, 0.f, 0.f};
                s = __builtin_amdgcn_mfma_f32_16x16x32_bf16(a0, qf[jt][0], s, 0, 0, 0);
                s = __builtin_amdgcn_mfma_f32_16x16x32_bf16(a1, qf[jt][1], s, 0, 0, 0);
                pa[jt].u[0] = cvt_pk_bf16(__builtin_amdgcn_exp2f(s[0]),
                                          __builtin_amdgcn_exp2f(s[1]));
                pa[jt].u[1] = cvt_pk_bf16(__builtin_amdgcn_exp2f(s[2]),
                                          __builtin_amdgcn_exp2f(s[3]));
            }
            __builtin_amdgcn_s_setprio(0);
        }

        // ======== t1 = 2u+1 (odd): prefetch next t0, QK on Kc1 -> pa high,
        //          then PV + Ol over the 32-key pair ========================
        if (u < 31) {
            const size_t t2 = (size_t)(2 * u + 2) * 64;
            gl2lds16(gK0 + t2 * DMODEL, Kc0);
            gl2lds16(gK1 + t2 * DMODEL, Kc0 + 512);
            gl2lds16(gV0 + t2, Vn);
            gl2lds16(gV1 + t2, Vn + 512);
            asm volatile("s_waitcnt vmcnt(4)" ::: "memory");  // t1's 4 DMA done
        } else {
            asm volatile("s_waitcnt vmcnt(0)" ::: "memory");
        }

        {
            const bf16x8 a0 = frag(Kc1, l16, quad);
            const bf16x8 a1 = frag(Kc1, l16, 4 + quad);
            __builtin_amdgcn_s_setprio(1);
            #pragma unroll
            for (int jt = 0; jt < 4; ++jt) {
                floatx4 s = {0.f, 0.f, 0.f, 0.f};
                s = __builtin_amdgcn_mfma_f32_16x16x32_bf16(a0, qf[jt][0], s, 0, 0, 0);
                s = __builtin_amdgcn_mfma_f32_16x16x32_bf16(a1, qf[jt][1], s, 0, 0, 0);
                pa[jt].u[2] = cvt_pk_bf16(__builtin_amdgcn_exp2f(s[0]),
                                          __builtin_amdgcn_exp2f(s[1]));
                pa[jt].u[3] = cvt_pk_bf16(__builtin_amdgcn_exp2f(s[2]),
                                          __builtin_amdgcn_exp2f(s[3]));
            }
            __builtin_amdgcn_s_setprio(0);
        }

        __builtin_amdgcn_s_setprio(1);
        #pragma unroll
        for (int nt = 0; nt < 4; ++nt) {
            const int ro = (nt * 16 + l16) * 16 + vo;   // pair-swizzled slot
            union { bf16x8 v; uint2 d[2]; } vu;
            vu.d[0] = *(const uint2*)(V0 + ro);   // even-chunk tokens (k-slots 0-3)
            vu.d[1] = *(const uint2*)(V1 + ro);   // odd-chunk tokens  (k-slots 4-7)
            #pragma unroll
            for (int jt = 0; jt < 4; ++jt)
                O[jt][nt] = __builtin_amdgcn_mfma_f32_16x16x32_bf16(
                    pa[jt].v, vu.v, O[jt][nt], 0, 0, 0);
        }
        #pragma unroll
        for (int jt = 0; jt < 4; ++jt)
            Ol[jt] = __builtin_amdgcn_mfma_f32_16x16x32_bf16(
                pa[jt].v, ones, Ol[jt], 0, 0, 0);
        __builtin_amdgcn_s_setprio(0);
    }

    // ---- cross-wave reduction + store (proven 4-way epilogue) ----
    __syncthreads();                       // all compute done, LDS reusable
    float* Of  = (float*)lds;              // 3 regions of [64][66] f32
    float* Olf = ((float*)lds) + 3 * 64 * 66;   // 3 x [64] f32
    if (wave != 0) {
        const int rg = (wave - 1) * 64 * 66;
        #pragma unroll
        for (int jt = 0; jt < 4; ++jt) {
            #pragma unroll
            for (int nt = 0; nt < 4; ++nt)
                #pragma unroll
                for (int r = 0; r < 4; ++r)
                    Of[rg + (jt * 16 + quad * 4 + r) * 66 + nt * 16 + l16] = O[jt][nt][r];
            if (l16 == 0) {
                #pragma unroll
                for (int r = 0; r < 4; ++r)
                    Olf[(wave - 1) * 64 + jt * 16 + quad * 4 + r] = Ol[jt][r];
            }
        }
    }
    __syncthreads();
    if (wave == 0) {
        #pragma unroll
        for (int jt = 0; jt < 4; ++jt) {
            const int qr = jt * 16 + quad * 4;
            float linv[4];
            #pragma unroll
            for (int r = 0; r < 4; ++r) {
                const float l = Ol[jt][r] + Olf[qr + r] + Olf[64 + qr + r]
                              + Olf[128 + qr + r];
                linv[r] = __builtin_amdgcn_rcpf(l);
            }
            #pragma unroll
            for (int nt = 0; nt < 4; ++nt) {
                const int d = h * HDIM + nt * 16 + l16;
                #pragma unroll
                for (int r = 0; r < 4; ++r) {
                    const float o = O[jt][nt][r]
                        + Of[(qr + r) * 66 + nt * 16 + l16]
                        + Of[64 * 66 + (qr + r) * 66 + nt * 16 + l16]
                        + Of[2 * 64 * 66 + (qr + r) * 66 + nt * 16 + l16];
                    attn_out[(size_t)(i0 + qr + r) * DMODEL + d] = f2bf(o * linv[r]);
                }
            }
        }
    }
}

// ---------------------------------------------------------------------------
extern "C" void kernel_launch(void* const* d_in, const int* in_sizes, int n_in,
                              void* d_out, int out_size, void* d_ws, size_t ws_size,
                              hipStream_t stream)
{
    const float* x     = (const float*)d_in[0];
    const float* Wqkv  = (const float*)d_in[1];
    const float* Wproj = (const float*)d_in[2];
    const float* bproj = (const float*)d_in[3];
    float* out = (float*)d_out;

    ushort* Xb     = (ushort*)d_ws;                          // [4096][768]
    ushort* WqkvT  = Xb    + (size_t)TOKENS * DMODEL;        // [2304][768]
    ushort* WprojT = WqkvT + (size_t)QKV_N * DMODEL;         // [768][768]
    ushort* Qb     = WprojT + (size_t)DMODEL * DMODEL;       // [4096][768]
    ushort* Kb     = Qb    + (size_t)TOKENS * DMODEL;        // [4096][768]
    ushort* Vt     = Kb    + (size_t)TOKENS * DMODEL;        // [768][4096]
    ushort* attn   = Vt    + (size_t)TOKENS * DMODEL;        // [4096][768]

    prep_kernel<<<dim3(5376), 256, 0, stream>>>(
        x, Wqkv, Wproj, Xb, WqkvT, WprojT);

    gemm_qkv_mfma<<<dim3(QKV_N / 128, TOKENS / 128), 256, 0, stream>>>(
        Xb, WqkvT, Qb, Kb, Vt);

    attn_mfma_kernel<<<dim3(TOKENS / 64, NHEADS), 256, 0, stream>>>(
        Qb, Kb, Vt, attn);

    gemm_proj_mfma<<<dim3(DMODEL / 64, TOKENS / 128), 256, 0, stream>>>(
        attn, WprojT, bproj, out);
}

// Round 15
// 175.894 us; speedup vs baseline: 1.1545x; 1.0038x over previous
//
#include <hip/hip_runtime.h>
#include <math.h>

#define TOKENS 4096
#define DMODEL 768
#define NHEADS 12
#define HDIM   64
#define QKV_N  2304          // 3*DMODEL
#define ATTN_SCALE 0.125f    // HDIM^-0.5
// fold log2(e) into Q so softmax uses v_exp_f32 (2^x) directly
#define QSCALE_LOG2E (0.125f * 1.44269504088896340736f)

typedef __attribute__((ext_vector_type(8))) short bf16x8;   // 8 bf16 = 4 VGPRs
typedef __attribute__((ext_vector_type(4))) float floatx4;

__device__ __forceinline__ ushort f2bf(float f) {
    union { float f; unsigned u; } cv; cv.f = f;
    unsigned u = cv.u;
    u += 0x7fffu + ((u >> 16) & 1u);   // round-to-nearest-even
    return (ushort)(u >> 16);
}

// pack two fp32 -> two bf16 (RNE) in one dword via v_cvt_pk_bf16_f32
__device__ __forceinline__ unsigned cvt_pk_bf16(float a, float b) {
    unsigned r;
    asm("v_cvt_pk_bf16_f32 %0, %1, %2" : "=v"(r) : "v"(a), "v"(b));
    return r;
}

// async 16B global->LDS (lane i lands at ldsbase + i*16)
__device__ __forceinline__ void gl2lds16(const ushort* g, ushort* l) {
    __builtin_amdgcn_global_load_lds(
        (const __attribute__((address_space(1))) void*)g,
        (__attribute__((address_space(3))) void*)l, 16, 0, 0);
}

// fragment read (64-ushort rows): logical chunk c of row r at phys (c ^ (r&7))
__device__ __forceinline__ bf16x8 frag(const ushort* ls, int row, int chunk) {
    return *(const bf16x8*)(ls + row * 64 + ((chunk ^ (row & 7)) * 8));
}

// fragment read (32-ushort rows, BK=32): phys chunk = c ^ (row&3), c in 0..3
__device__ __forceinline__ bf16x8 frag32(const ushort* ls, int row, int chunk) {
    return *(const bf16x8*)(ls + row * 32 + ((chunk ^ (row & 3)) * 8));
}

// ---------------------------------------------------------------------------
// fused prep: fp32->bf16 cvt of x (widened: 16B stores/lane)  +  both
// weight transpose-converts. Grid 3840 (was 5376).
// ---------------------------------------------------------------------------
__global__ __launch_bounds__(256) void prep_kernel(
    const float* __restrict__ x, const float* __restrict__ Wqkv,
    const float* __restrict__ Wproj, ushort* __restrict__ Xb,
    ushort* __restrict__ WqkvT, ushort* __restrict__ WprojT)
{
    __shared__ ushort tile[32][33];
    const int bid = blockIdx.x;
    const int tid = threadIdx.x;

    if (bid < 1536) {                     // ---- cvt x: 1536*256*8 = 4096*768
        const int i = bid * 256 + tid;
        const float4 v0 = ((const float4*)x)[2 * i];
        const float4 v1 = ((const float4*)x)[2 * i + 1];
        uint4 h;
        h.x = cvt_pk_bf16(v0.x, v0.y);
        h.y = cvt_pk_bf16(v0.z, v0.w);
        h.z = cvt_pk_bf16(v1.x, v1.y);
        h.w = cvt_pk_bf16(v1.z, v1.w);
        ((uint4*)Xb)[i] = h;
        return;
    }

    const float* in; ushort* out; int C, bx, by;
    if (bid < 1536 + 1728) {              // ---- Wqkv [768][2304] -> [2304][768]
        const int b = bid - 1536;
        in = Wqkv; out = WqkvT; C = QKV_N;
        bx = b % 72; by = b / 72;
    } else {                              // ---- Wproj [768][768] -> [768][768]
        const int b = bid - 3264;
        in = Wproj; out = WprojT; C = DMODEL;
        bx = b % 24; by = b / 24;
    }
    const int R  = DMODEL;
    const int tx = tid & 31;
    const int ty8 = tid >> 5;             // 0..7
    const int c0 = bx * 32;
    const int r0 = by * 32;
    #pragma unroll
    for (int p = 0; p < 4; ++p) {
        const int r = ty8 + p * 8;
        tile[r][tx] = f2bf(in[(size_t)(r0 + r) * C + c0 + tx]);
    }
    __syncthreads();
    #pragma unroll
    for (int p = 0; p < 4; ++p) {
        const int c = ty8 + p * 8;
        out[(size_t)(c0 + c) * R + r0 + tx] = tile[tx][c];
    }
}

// ---------------------------------------------------------------------------
// MFMA GEMM body — 2-PHASE double-buffered, BK=64 (r11-verified). proj uses.
// ---------------------------------------------------------------------------
template<int NT>
__device__ __forceinline__ void gemm_body_2ph(
    const ushort* __restrict__ A, const ushort* __restrict__ Bt, int K,
    int m0, int n0, floatx4 acc[4][NT], ushort* ls)
{
    const int BUF = 8192 + 2048 * NT;    // ushorts per buffer

    const int tid  = threadIdx.x;
    const int lane = tid & 63;
    const int wave = tid >> 6;
    const int wm = wave >> 1, wn = wave & 1;
    const int quad = lane >> 4, l16 = lane & 15;

    const int lrow = lane >> 3;          // 0..7
    const int csw  = ((lane & 7) ^ lrow) * 8;   // swizzled global chunk (ushorts)

    const ushort* gA = A  + (size_t)(m0 + wave * 32 + lrow) * K + csw;
    const ushort* gB = Bt + (size_t)(n0 + wave * NT * 8 + lrow) * K + csw;
    const int lAoff = (wave * 32) * 64;
    const int lBoff = 8192 + (wave * NT * 8) * 64;

    // prologue: stage tile 0 into buffer 0
    #pragma unroll
    for (int p = 0; p < 4; ++p)
        gl2lds16(gA + (size_t)p * 8 * K, ls + lAoff + p * 8 * 64);
    #pragma unroll
    for (int p = 0; p < NT; ++p)
        gl2lds16(gB + (size_t)p * 8 * K, ls + lBoff + p * 8 * 64);
    __syncthreads();                     // drain + publish tile 0

    const int NK = K / 64;
    for (int t = 0; t < NK; ++t) {
        ushort* cb = ls + (t & 1) * BUF;
        ushort* nb = ls + ((t + 1) & 1) * BUF;

        if (t + 1 < NK) {                // issue next tile's DMA (no wait)
            const int k1 = (t + 1) * 64;
            #pragma unroll
            for (int p = 0; p < 4; ++p)
                gl2lds16(gA + (size_t)p * 8 * K + k1, nb + lAoff + p * 8 * 64);
            #pragma unroll
            for (int p = 0; p < NT; ++p)
                gl2lds16(gB + (size_t)p * 8 * K + k1, nb + lBoff + p * 8 * 64);
        }

        const ushort* lsA = cb;
        const ushort* lsB = cb + 8192;
        #pragma unroll
        for (int ks = 0; ks < 2; ++ks) {
            bf16x8 af[4], bfr[NT];
            #pragma unroll
            for (int mt = 0; mt < 4; ++mt)
                af[mt] = frag(lsA, wm * 64 + mt * 16 + l16, ks * 4 + quad);
            #pragma unroll
            for (int nt = 0; nt < NT; ++nt)
                bfr[nt] = frag(lsB, wn * NT * 16 + nt * 16 + l16, ks * 4 + quad);
            #pragma unroll
            for (int mt = 0; mt < 4; ++mt)
                #pragma unroll
                for (int nt = 0; nt < NT; ++nt)
                    acc[mt][nt] = __builtin_amdgcn_mfma_f32_16x16x32_bf16(
                        af[mt], bfr[nt], acc[mt][nt], 0, 0, 0);
        }

        __syncthreads();                 // vmcnt(0): prefetch landed; publish
    }
}

// ---------------------------------------------------------------------------
// MFMA GEMM body — 2-PHASE double-buffered, BK=32 (lean-LDS, r13-verified).
// ---------------------------------------------------------------------------
template<int NT>
__device__ __forceinline__ void gemm_body_2ph32(
    const ushort* __restrict__ A, const ushort* __restrict__ Bt, int K,
    int m0, int n0, floatx4 acc[4][NT], ushort* ls)
{
    const int BUF = 4096 + 1024 * NT;    // ushorts per buffer

    const int tid  = threadIdx.x;
    const int lane = tid & 63;
    const int wave = tid >> 6;
    const int wm = wave >> 1, wn = wave & 1;
    const int quad = lane >> 4, l16 = lane & 15;

    const int lrow = lane >> 2;          // 0..15
    const int csw  = ((lane & 3) ^ (lrow & 3)) * 8;   // 2-bit XOR pre-swizzle

    const ushort* gA = A  + (size_t)(m0 + wave * 32 + lrow) * K + csw;
    const ushort* gB = Bt + (size_t)(n0 + wave * NT * 8 + lrow) * K + csw;
    const int lAoff = wave * 1024;               // 32 rows * 32 ushorts
    const int lBoff = 4096 + wave * NT * 256;    // NT*8 rows * 32 ushorts

    // prologue: stage tile 0 into buffer 0
    #pragma unroll
    for (int p = 0; p < 2; ++p)
        gl2lds16(gA + (size_t)p * 16 * K, ls + lAoff + p * 512);
    #pragma unroll
    for (int p = 0; p < NT / 2; ++p)
        gl2lds16(gB + (size_t)p * 16 * K, ls + lBoff + p * 512);
    __syncthreads();

    const int NK = K / 32;
    for (int t = 0; t < NK; ++t) {
        ushort* cb = ls + (t & 1) * BUF;
        ushort* nb = ls + ((t + 1) & 1) * BUF;

        if (t + 1 < NK) {                // issue next tile's DMA (no wait)
            const int k1 = (t + 1) * 32;
            #pragma unroll
            for (int p = 0; p < 2; ++p)
                gl2lds16(gA + (size_t)p * 16 * K + k1, nb + lAoff + p * 512);
            #pragma unroll
            for (int p = 0; p < NT / 2; ++p)
                gl2lds16(gB + (size_t)p * 16 * K + k1, nb + lBoff + p * 512);
        }

        const ushort* lsA = cb;
        const ushort* lsB = cb + 4096;
        bf16x8 af[4], bfr[NT];
        #pragma unroll
        for (int mt = 0; mt < 4; ++mt)
            af[mt] = frag32(lsA, wm * 64 + mt * 16 + l16, quad);
        #pragma unroll
        for (int nt = 0; nt < NT; ++nt)
            bfr[nt] = frag32(lsB, wn * NT * 16 + nt * 16 + l16, quad);
        #pragma unroll
        for (int mt = 0; mt < 4; ++mt)
            #pragma unroll
            for (int nt = 0; nt < NT; ++nt)
                acc[mt][nt] = __builtin_amdgcn_mfma_f32_16x16x32_bf16(
                    af[mt], bfr[nt], acc[mt][nt], 0, 0, 0);

        __syncthreads();                 // prefetch landed; publish
    }
}

// ---------------------------------------------------------------------------
// qkv GEMM: 128x128 / 576 blocks, BK=32 body, 34.8 KB LDS, 3 blocks/CU
// (r13-verified). XCD m-strip swizzle + single-pass retile epilogue.
// ---------------------------------------------------------------------------
__global__ __launch_bounds__(256, 3) void gemm_qkv_mfma(
    const ushort* __restrict__ Xb, const ushort* __restrict__ Wt,
    ushort* __restrict__ Qb, ushort* __restrict__ Kb, ushort* __restrict__ Vt)
{
    // bufs: 2 x 8192 ushorts (32 KB) | epilogue retile [128][136] = 17408
    __shared__ __align__(16) ushort ls[17408];   // 34.8 KB
    const int lin = blockIdx.x + blockIdx.y * 18;     // dispatch-linear id
    const int w   = (lin & 7) * 72 + (lin >> 3);      // bijective XCD chunking
    const int m0  = (w / 18) * 128;
    const int n0  = (w % 18) * 128;

    floatx4 acc[4][4] = {};
    gemm_body_2ph32<4>(Xb, Wt, DMODEL, m0, n0, acc, ls);

    const int tid  = threadIdx.x;
    const int lane = tid & 63;
    const int wave = tid >> 6;
    const int wm = wave >> 1, wn = wave & 1;
    const int quad = lane >> 4, l16 = lane & 15;

    if (n0 < 2 * DMODEL) {
        // ---- Q or K: single pass over all 128 rows ----
        const float scale = (n0 < DMODEL) ? QSCALE_LOG2E : 1.0f;
        ushort* outp = (n0 < DMODEL) ? Qb : Kb;
        const int colg = (n0 < DMODEL) ? n0 : n0 - DMODEL;
        __syncthreads();                    // all waves done with GEMM tiles
        #pragma unroll
        for (int mt = 0; mt < 4; ++mt)
            #pragma unroll
            for (int nt = 0; nt < 4; ++nt) {
                const int row = wm * 64 + mt * 16 + quad * 4;
                const int col = wn * 64 + nt * 16 + l16;
                #pragma unroll
                for (int r = 0; r < 4; ++r)
                    ls[(row + r) * 136 + col] = f2bf(acc[mt][nt][r] * scale);
            }
        __syncthreads();
        #pragma unroll
        for (int p2 = 0; p2 < 8; ++p2) {
            const int row = (tid >> 4) + p2 * 16;
            const int c8  = (tid & 15) * 8;
            *(uint4*)(outp + (size_t)(m0 + row) * DMODEL + colg + c8) =
                *(const uint4*)(ls + row * 136 + c8);
        }
    } else {
        // ---- V transposed: single pass over all 128 hd-rows ----
        const int hd0 = n0 - 2 * DMODEL;
        __syncthreads();
        #pragma unroll
        for (int mt = 0; mt < 4; ++mt)
            #pragma unroll
            for (int nt = 0; nt < 4; ++nt) {
                const int hd  = wn * 64 + nt * 16 + l16;
                const int tok = wm * 64 + mt * 16 + quad * 4;
                #pragma unroll
                for (int r = 0; r < 4; ++r)
                    ls[hd * 136 + tok + r] = f2bf(acc[mt][nt][r]);
            }
        __syncthreads();
        #pragma unroll
        for (int p2 = 0; p2 < 8; ++p2) {
            const int row = (tid >> 4) + p2 * 16;    // local hd
            const int c8  = (tid & 15) * 8;          // token chunk
            *(uint4*)(Vt + (size_t)(hd0 + row) * TOKENS + m0 + c8) =
                *(const uint4*)(ls + row * 136 + c8);
        }
    }
}

// ---------------------------------------------------------------------------
// proj GEMM: 128x64 tiles, XCD m-strip swizzle, 2ph BK=64 (r11-verified).
// ---------------------------------------------------------------------------
__global__ __launch_bounds__(256) void gemm_proj_mfma(
    const ushort* __restrict__ Ab, const ushort* __restrict__ Wt,
    const float* __restrict__ bias, float* __restrict__ out)
{
    __shared__ __align__(16) ushort ls[24576];   // 48 KB: 2 x 24 KB tile bufs
    const int lin = blockIdx.x + blockIdx.y * 12;
    const int w   = (lin & 7) * 48 + (lin >> 3);
    const int m0  = (w / 12) * 128;
    const int n0  = (w % 12) * 64;

    floatx4 acc[4][2] = {};
    gemm_body_2ph<2>(Ab, Wt, DMODEL, m0, n0, acc, ls);

    const int lane = threadIdx.x & 63;
    const int wave = threadIdx.x >> 6;
    const int wm = wave >> 1, wn = wave & 1;
    const int quad = lane >> 4, l16 = lane & 15;
    const int row0 = m0 + wm * 64 + quad * 4;
    const int col0 = n0 + wn * 32;

    #pragma unroll
    for (int nt = 0; nt < 2; ++nt) {
        const int col = col0 + nt * 16 + l16;
        const float bv = bias[col];
        #pragma unroll
        for (int mt = 0; mt < 4; ++mt)
            #pragma unroll
            for (int r = 0; r < 4; ++r)
                out[(size_t)(row0 + mt * 16 + r) * DMODEL + col] =
                    acc[mt][nt][r] + bv;
    }
}

// ---------------------------------------------------------------------------
// MFMA flash attention — r13-verified kernel VERBATIM (77.5us).
//
// r14 post-mortem: the 32x32x16 port NaN'd — its A/B operand k-layout was
// extrapolated, not verified (only C/D was measurement-backed). SESSION RULE:
// an MFMA-shape port needs a verified operand layout for that exact shape.
// This 16x16x32 design is the 5x-probed structural floor (~77us).
// ---------------------------------------------------------------------------
__global__ __launch_bounds__(256, 3) void attn_mfma_kernel(
    const ushort* __restrict__ Qb, const ushort* __restrict__ Kb,
    const ushort* __restrict__ Vt, ushort* __restrict__ attn_out)
{
    // main loop: 4 waves x 6144 ushorts (K0,K1 @0,1024; V0..V3 @2048+s*1024)
    // epilogue:  3 x [64][66] f32 + 192 f32 = 12864 floats = 25728 ushorts
    __shared__ __align__(16) ushort lds[25728];   // 51.5 KB

    const int tid  = threadIdx.x;
    const int wave = tid >> 6;
    const int lane = tid & 63;
    const int quad = lane >> 4;
    const int l16  = lane & 15;

    // XCD head-locality swizzle (bijective: 768 = 8 XCDs x 96 blocks)
    const int lin = blockIdx.x + blockIdx.y * 64;    // dispatch-linear id
    const int wsw = (lin & 7) * 96 + (lin >> 3);     // chunked per-XCD remap
    const int h   = wsw >> 6;                        // head 0..11
    const int i0  = (wsw & 63) * 64;                 // query-tile base

    // Q fragments: all 4 q-tiles register-resident (B-operand: col=l16)
    bf16x8 qf[4][2];
    #pragma unroll
    for (int jt = 0; jt < 4; ++jt) {
        const ushort* qb = Qb + (size_t)(i0 + jt * 16 + l16) * DMODEL + h * HDIM;
        qf[jt][0] = *(const bf16x8*)(qb + quad * 8);
        qf[jt][1] = *(const bf16x8*)(qb + 32 + quad * 8);
    }

    bf16x8 ones;
    #pragma unroll
    for (int i = 0; i < 8; ++i) ones[i] = (short)0x3F80;   // bf16 1.0

    floatx4 O[4][4] = {};    // [q-tile][d-tile], partial over this wave's keys
    floatx4 Ol[4]   = {};    // [q-tile] partial row-sums

    ushort* wls = lds + wave * 6144;                 // private region

    // K staging source (3-bit XOR chunk pre-swizzle; wave's key = t*64+wave*16+row)
    const int lrow8 = lane >> 3;                     // 0..7
    const int csw8  = ((lane & 7) ^ lrow8) * 8;
    const ushort* gK0 = Kb + (size_t)(wave * 16 + lrow8) * DMODEL + h * HDIM + csw8;
    const ushort* gK1 = gK0 + (size_t)8 * DMODEL;

    // V staging source: lane -> d=lane>>1, PHYSICAL tok-pair=lane&1 holds
    // LOGICAL pair (lane&1)^((d>>2)&1) = (lane&1)^((lane>>3)&1)
    const ushort* gV0 = Vt + (size_t)(h * HDIM + (lane >> 1)) * TOKENS
                           + wave * 16 + (((lane & 1) ^ ((lane >> 3) & 1)) * 8);
    const ushort* gV1 = gV0 + (size_t)32 * TOKENS;

    // V read offset (loop-invariant): logical pair quad>>1 of row nt*16+l16
    // sits at physical pair (quad>>1)^((l16>>2)&1); 8B half = quad&1
    const int vo = ((quad >> 1) ^ ((l16 >> 2) & 1)) * 8 + (quad & 1) * 4;

    // persistent P operand, packed across an even/odd chunk pair
    union { bf16x8 v; unsigned u[4]; } pa[4];

    // prologue: stage t=0 (K -> buf0, V -> slot0); 4 DMA outstanding
    gl2lds16(gK0, wls);
    gl2lds16(gK1, wls + 512);
    gl2lds16(gV0, wls + 2048);
    gl2lds16(gV1, wls + 2048 + 512);

    for (int u = 0; u < 32; ++u) {                   // pair u: t0=2u, t1=2u+1
        const int s0 = (u & 1) << 1;                 // V slot of t0 (0 or 2)
        ushort* Kc0 = wls;
        ushort* Kc1 = wls + 1024;
        ushort* V0  = wls + 2048 + s0 * 1024;
        ushort* V1  = wls + 2048 + (s0 + 1) * 1024;
        ushort* Vn  = wls + 2048 + ((s0 + 2) & 3) * 1024;

        // ======== t0 = 2u (even): prefetch t1, QK on Kc0 -> pa low half ====
        {
            const size_t t1 = (size_t)(2 * u + 1) * 64;
            gl2lds16(gK0 + t1 * DMODEL, Kc1);
            gl2lds16(gK1 + t1 * DMODEL, Kc1 + 512);
            gl2lds16(gV0 + t1, V1);
            gl2lds16(gV1 + t1, V1 + 512);
        }
        asm volatile("s_waitcnt vmcnt(4)" ::: "memory");   // t0's 4 DMA done

        {
            const bf16x8 a0 = frag(Kc0, l16, quad);
            const bf16x8 a1 = frag(Kc0, l16, 4 + quad);
            __builtin_amdgcn_s_setprio(1);
            #pragma unroll
            for (int jt = 0; jt < 4; ++jt) {
                floatx4 s = {0.f, 0.f, 0.f, 0.f};
                s = __builtin_amdgcn_mfma_f32_16x16x32_bf16(a0, qf[jt][0], s, 0, 0, 0);
                s = __builtin_amdgcn_mfma_f32_16x16x32_bf16(a1, qf[jt][1], s, 0, 0, 0);
                pa[jt].u[0] = cvt_pk_bf16(__builtin_amdgcn_exp2f(s[0]),
                                          __builtin_amdgcn_exp2f(s[1]));
                pa[jt].u[1] = cvt_pk_bf16(__builtin_amdgcn_exp2f(s[2]),
                                          __builtin_amdgcn_exp2f(s[3]));
            }
            __builtin_amdgcn_s_setprio(0);
        }

        // ======== t1 = 2u+1 (odd): prefetch next t0, QK on Kc1 -> pa high,
        //          then PV + Ol over the 32-key pair ========================
        if (u < 31) {
            const size_t t2 = (size_t)(2 * u + 2) * 64;
            gl2lds16(gK0 + t2 * DMODEL, Kc0);
            gl2lds16(gK1 + t2 * DMODEL, Kc0 + 512);
            gl2lds16(gV0 + t2, Vn);
            gl2lds16(gV1 + t2, Vn + 512);
            asm volatile("s_waitcnt vmcnt(4)" ::: "memory");  // t1's 4 DMA done
        } else {
            asm volatile("s_waitcnt vmcnt(0)" ::: "memory");
        }

        {
            const bf16x8 a0 = frag(Kc1, l16, quad);
            const bf16x8 a1 = frag(Kc1, l16, 4 + quad);
            __builtin_amdgcn_s_setprio(1);
            #pragma unroll
            for (int jt = 0; jt < 4; ++jt) {
                floatx4 s = {0.f, 0.f, 0.f, 0.f};
                s = __builtin_amdgcn_mfma_f32_16x16x32_bf16(a0, qf[jt][0], s, 0, 0, 0);
                s = __builtin_amdgcn_mfma_f32_16x16x32_bf16(a1, qf[jt][1], s, 0, 0, 0);
                pa[jt].u[2] = cvt_pk_bf16(__builtin_amdgcn_exp2f(s[0]),
                                          __builtin_amdgcn_exp2f(s[1]));
                pa[jt].u[3] = cvt_pk_bf16(__builtin_amdgcn_exp2f(s[2]),
                                          __builtin_amdgcn_exp2f(s[3]));
            }
            __builtin_amdgcn_s_setprio(0);
        }

        __builtin_amdgcn_s_setprio(1);
        #pragma unroll
        for (int nt = 0; nt < 4; ++nt) {
            const int ro = (nt * 16 + l16) * 16 + vo;   // pair-swizzled slot
            union { bf16x8 v; uint2 d[2]; } vu;
            vu.d[0] = *(const uint2*)(V0 + ro);   // even-chunk tokens (k-slots 0-3)
            vu.d[1] = *(const uint2*)(V1 + ro);   // odd-chunk tokens  (k-slots 4-7)
            #pragma unroll
            for (int jt = 0; jt < 4; ++jt)
                O[jt][nt] = __builtin_amdgcn_mfma_f32_16x16x32_bf16(
                    pa[jt].v, vu.v, O[jt][nt], 0, 0, 0);
        }
        #pragma unroll
        for (int jt = 0; jt < 4; ++jt)
            Ol[jt] = __builtin_amdgcn_mfma_f32_16x16x32_bf16(
                pa[jt].v, ones, Ol[jt], 0, 0, 0);
        __builtin_amdgcn_s_setprio(0);
    }

    // ---- cross-wave reduction + store (proven 4-way epilogue) ----
    __syncthreads();                       // all compute done, LDS reusable
    float* Of  = (float*)lds;              // 3 regions of [64][66] f32
    float* Olf = ((float*)lds) + 3 * 64 * 66;   // 3 x [64] f32
    if (wave != 0) {
        const int rg = (wave - 1) * 64 * 66;
        #pragma unroll
        for (int jt = 0; jt < 4; ++jt) {
            #pragma unroll
            for (int nt = 0; nt < 4; ++nt)
                #pragma unroll
                for (int r = 0; r < 4; ++r)
                    Of[rg + (jt * 16 + quad * 4 + r) * 66 + nt * 16 + l16] = O[jt][nt][r];
            if (l16 == 0) {
                #pragma unroll
                for (int r = 0; r < 4; ++r)
                    Olf[(wave - 1) * 64 + jt * 16 + quad * 4 + r] = Ol[jt][r];
            }
        }
    }
    __syncthreads();
    if (wave == 0) {
        #pragma unroll
        for (int jt = 0; jt < 4; ++jt) {
            const int qr = jt * 16 + quad * 4;
            float linv[4];
            #pragma unroll
            for (int r = 0; r < 4; ++r) {
                const float l = Ol[jt][r] + Olf[qr + r] + Olf[64 + qr + r]
                              + Olf[128 + qr + r];
                linv[r] = __builtin_amdgcn_rcpf(l);
            }
            #pragma unroll
            for (int nt = 0; nt < 4; ++nt) {
                const int d = h * HDIM + nt * 16 + l16;
                #pragma unroll
                for (int r = 0; r < 4; ++r) {
                    const float o = O[jt][nt][r]
                        + Of[(qr + r) * 66 + nt * 16 + l16]
                        + Of[64 * 66 + (qr + r) * 66 + nt * 16 + l16]
                        + Of[2 * 64 * 66 + (qr + r) * 66 + nt * 16 + l16];
                    attn_out[(size_t)(i0 + qr + r) * DMODEL + d] = f2bf(o * linv[r]);
                }
            }
        }
    }
}

// ---------------------------------------------------------------------------
extern "C" void kernel_launch(void* const* d_in, const int* in_sizes, int n_in,
                              void* d_out, int out_size, void* d_ws, size_t ws_size,
                              hipStream_t stream)
{
    const float* x     = (const float*)d_in[0];
    const float* Wqkv  = (const float*)d_in[1];
    const float* Wproj = (const float*)d_in[2];
    const float* bproj = (const float*)d_in[3];
    float* out = (float*)d_out;

    ushort* Xb     = (ushort*)d_ws;                          // [4096][768]
    ushort* WqkvT  = Xb    + (size_t)TOKENS * DMODEL;        // [2304][768]
    ushort* WprojT = WqkvT + (size_t)QKV_N * DMODEL;         // [768][768]
    ushort* Qb     = WprojT + (size_t)DMODEL * DMODEL;       // [4096][768]
    ushort* Kb     = Qb    + (size_t)TOKENS * DMODEL;        // [4096][768]
    ushort* Vt     = Kb    + (size_t)TOKENS * DMODEL;        // [768][4096]
    ushort* attn   = Vt    + (size_t)TOKENS * DMODEL;        // [4096][768]

    prep_kernel<<<dim3(3840), 256, 0, stream>>>(
        x, Wqkv, Wproj, Xb, WqkvT, WprojT);

    gemm_qkv_mfma<<<dim3(QKV_N / 128, TOKENS / 128), 256, 0, stream>>>(
        Xb, WqkvT, Qb, Kb, Vt);

    attn_mfma_kernel<<<dim3(TOKENS / 64, NHEADS), 256, 0, stream>>>(
        Qb, Kb, Vt, attn);

    gemm_proj_mfma<<<dim3(DMODEL / 64, TOKENS / 128), 256, 0, stream>>>(
        attn, WprojT, bproj, out);
}

// Round 18
// 175.714 us; speedup vs baseline: 1.1557x; 1.0010x over previous
//
#include <hip/hip_runtime.h>
#include <math.h>

#define TOKENS 4096
#define DMODEL 768
#define NHEADS 12
#define HDIM   64
#define QKV_N  2304          // 3*DMODEL
#define ATTN_SCALE 0.125f    // HDIM^-0.5
// fold log2(e) into Q so softmax uses v_exp_f32 (2^x) directly
#define QSCALE_LOG2E (0.125f * 1.44269504088896340736f)

typedef __attribute__((ext_vector_type(8))) short bf16x8;   // 8 bf16 = 4 VGPRs
typedef __attribute__((ext_vector_type(4))) float floatx4;

__device__ __forceinline__ ushort f2bf(float f) {
    union { float f; unsigned u; } cv; cv.f = f;
    unsigned u = cv.u;
    u += 0x7fffu + ((u >> 16) & 1u);   // round-to-nearest-even
    return (ushort)(u >> 16);
}

// pack two fp32 -> two bf16 (RNE) in one dword via v_cvt_pk_bf16_f32
__device__ __forceinline__ unsigned cvt_pk_bf16(float a, float b) {
    unsigned r;
    asm("v_cvt_pk_bf16_f32 %0, %1, %2" : "=v"(r) : "v"(a), "v"(b));
    return r;
}

// async 16B global->LDS (lane i lands at ldsbase + i*16)
__device__ __forceinline__ void gl2lds16(const ushort* g, ushort* l) {
    __builtin_amdgcn_global_load_lds(
        (const __attribute__((address_space(1))) void*)g,
        (__attribute__((address_space(3))) void*)l, 16, 0, 0);
}

// fragment read (64-ushort rows): logical chunk c of row r at phys (c ^ (r&7))
__device__ __forceinline__ bf16x8 frag(const ushort* ls, int row, int chunk) {
    return *(const bf16x8*)(ls + row * 64 + ((chunk ^ (row & 7)) * 8));
}

// fragment read (32-ushort rows, BK=32): phys chunk = c ^ (row&3), c in 0..3
__device__ __forceinline__ bf16x8 frag32(const ushort* ls, int row, int chunk) {
    return *(const bf16x8*)(ls + row * 32 + ((chunk ^ (row & 3)) * 8));
}

// ---------------------------------------------------------------------------
// fused prep: fp32->bf16 cvt of x (widened: 16B stores/lane)  +  both
// weight transpose-converts. Grid 3840. r15-verified.
// ---------------------------------------------------------------------------
__global__ __launch_bounds__(256) void prep_kernel(
    const float* __restrict__ x, const float* __restrict__ Wqkv,
    const float* __restrict__ Wproj, ushort* __restrict__ Xb,
    ushort* __restrict__ WqkvT, ushort* __restrict__ WprojT)
{
    __shared__ ushort tile[32][33];
    const int bid = blockIdx.x;
    const int tid = threadIdx.x;

    if (bid < 1536) {                     // ---- cvt x: 1536*256*8 = 4096*768
        const int i = bid * 256 + tid;
        const float4 v0 = ((const float4*)x)[2 * i];
        const float4 v1 = ((const float4*)x)[2 * i + 1];
        uint4 h;
        h.x = cvt_pk_bf16(v0.x, v0.y);
        h.y = cvt_pk_bf16(v0.z, v0.w);
        h.z = cvt_pk_bf16(v1.x, v1.y);
        h.w = cvt_pk_bf16(v1.z, v1.w);
        ((uint4*)Xb)[i] = h;
        return;
    }

    const float* in; ushort* out; int C, bx, by;
    if (bid < 1536 + 1728) {              // ---- Wqkv [768][2304] -> [2304][768]
        const int b = bid - 1536;
        in = Wqkv; out = WqkvT; C = QKV_N;
        bx = b % 72; by = b / 72;
    } else {                              // ---- Wproj [768][768] -> [768][768]
        const int b = bid - 3264;
        in = Wproj; out = WprojT; C = DMODEL;
        bx = b % 24; by = b / 24;
    }
    const int R  = DMODEL;
    const int tx = tid & 31;
    const int ty8 = tid >> 5;             // 0..7
    const int c0 = bx * 32;
    const int r0 = by * 32;
    #pragma unroll
    for (int p = 0; p < 4; ++p) {
        const int r = ty8 + p * 8;
        tile[r][tx] = f2bf(in[(size_t)(r0 + r) * C + c0 + tx]);
    }
    __syncthreads();
    #pragma unroll
    for (int p = 0; p < 4; ++p) {
        const int c = ty8 + p * 8;
        out[(size_t)(c0 + c) * R + r0 + tx] = tile[tx][c];
    }
}

// ---------------------------------------------------------------------------
// MFMA GEMM body — 2-PHASE double-buffered, BK=64 (r11-verified). proj uses.
// ---------------------------------------------------------------------------
template<int NT>
__device__ __forceinline__ void gemm_body_2ph(
    const ushort* __restrict__ A, const ushort* __restrict__ Bt, int K,
    int m0, int n0, floatx4 acc[4][NT], ushort* ls)
{
    const int BUF = 8192 + 2048 * NT;    // ushorts per buffer

    const int tid  = threadIdx.x;
    const int lane = tid & 63;
    const int wave = tid >> 6;
    const int wm = wave >> 1, wn = wave & 1;
    const int quad = lane >> 4, l16 = lane & 15;

    const int lrow = lane >> 3;          // 0..7
    const int csw  = ((lane & 7) ^ lrow) * 8;   // swizzled global chunk (ushorts)

    const ushort* gA = A  + (size_t)(m0 + wave * 32 + lrow) * K + csw;
    const ushort* gB = Bt + (size_t)(n0 + wave * NT * 8 + lrow) * K + csw;
    const int lAoff = (wave * 32) * 64;
    const int lBoff = 8192 + (wave * NT * 8) * 64;

    // prologue: stage tile 0 into buffer 0
    #pragma unroll
    for (int p = 0; p < 4; ++p)
        gl2lds16(gA + (size_t)p * 8 * K, ls + lAoff + p * 8 * 64);
    #pragma unroll
    for (int p = 0; p < NT; ++p)
        gl2lds16(gB + (size_t)p * 8 * K, ls + lBoff + p * 8 * 64);
    __syncthreads();                     // drain + publish tile 0

    const int NK = K / 64;
    for (int t = 0; t < NK; ++t) {
        ushort* cb = ls + (t & 1) * BUF;
        ushort* nb = ls + ((t + 1) & 1) * BUF;

        if (t + 1 < NK) {                // issue next tile's DMA (no wait)
            const int k1 = (t + 1) * 64;
            #pragma unroll
            for (int p = 0; p < 4; ++p)
                gl2lds16(gA + (size_t)p * 8 * K + k1, nb + lAoff + p * 8 * 64);
            #pragma unroll
            for (int p = 0; p < NT; ++p)
                gl2lds16(gB + (size_t)p * 8 * K + k1, nb + lBoff + p * 8 * 64);
        }

        const ushort* lsA = cb;
        const ushort* lsB = cb + 8192;
        #pragma unroll
        for (int ks = 0; ks < 2; ++ks) {
            bf16x8 af[4], bfr[NT];
            #pragma unroll
            for (int mt = 0; mt < 4; ++mt)
                af[mt] = frag(lsA, wm * 64 + mt * 16 + l16, ks * 4 + quad);
            #pragma unroll
            for (int nt = 0; nt < NT; ++nt)
                bfr[nt] = frag(lsB, wn * NT * 16 + nt * 16 + l16, ks * 4 + quad);
            #pragma unroll
            for (int mt = 0; mt < 4; ++mt)
                #pragma unroll
                for (int nt = 0; nt < NT; ++nt)
                    acc[mt][nt] = __builtin_amdgcn_mfma_f32_16x16x32_bf16(
                        af[mt], bfr[nt], acc[mt][nt], 0, 0, 0);
        }

        __syncthreads();                 // vmcnt(0): prefetch landed; publish
    }
}

// ---------------------------------------------------------------------------
// MFMA GEMM body — 2-PHASE double-buffered, BK=32 (lean-LDS, r13-verified).
// ---------------------------------------------------------------------------
template<int NT>
__device__ __forceinline__ void gemm_body_2ph32(
    const ushort* __restrict__ A, const ushort* __restrict__ Bt, int K,
    int m0, int n0, floatx4 acc[4][NT], ushort* ls)
{
    const int BUF = 4096 + 1024 * NT;    // ushorts per buffer

    const int tid  = threadIdx.x;
    const int lane = tid & 63;
    const int wave = tid >> 6;
    const int wm = wave >> 1, wn = wave & 1;
    const int quad = lane >> 4, l16 = lane & 15;

    const int lrow = lane >> 2;          // 0..15
    const int csw  = ((lane & 3) ^ (lrow & 3)) * 8;   // 2-bit XOR pre-swizzle

    const ushort* gA = A  + (size_t)(m0 + wave * 32 + lrow) * K + csw;
    const ushort* gB = Bt + (size_t)(n0 + wave * NT * 8 + lrow) * K + csw;
    const int lAoff = wave * 1024;               // 32 rows * 32 ushorts
    const int lBoff = 4096 + wave * NT * 256;    // NT*8 rows * 32 ushorts

    // prologue: stage tile 0 into buffer 0
    #pragma unroll
    for (int p = 0; p < 2; ++p)
        gl2lds16(gA + (size_t)p * 16 * K, ls + lAoff + p * 512);
    #pragma unroll
    for (int p = 0; p < NT / 2; ++p)
        gl2lds16(gB + (size_t)p * 16 * K, ls + lBoff + p * 512);
    __syncthreads();

    const int NK = K / 32;
    for (int t = 0; t < NK; ++t) {
        ushort* cb = ls + (t & 1) * BUF;
        ushort* nb = ls + ((t + 1) & 1) * BUF;

        if (t + 1 < NK) {                // issue next tile's DMA (no wait)
            const int k1 = (t + 1) * 32;
            #pragma unroll
            for (int p = 0; p < 2; ++p)
                gl2lds16(gA + (size_t)p * 16 * K + k1, nb + lAoff + p * 512);
            #pragma unroll
            for (int p = 0; p < NT / 2; ++p)
                gl2lds16(gB + (size_t)p * 16 * K + k1, nb + lBoff + p * 512);
        }

        const ushort* lsA = cb;
        const ushort* lsB = cb + 4096;
        bf16x8 af[4], bfr[NT];
        #pragma unroll
        for (int mt = 0; mt < 4; ++mt)
            af[mt] = frag32(lsA, wm * 64 + mt * 16 + l16, quad);
        #pragma unroll
        for (int nt = 0; nt < NT; ++nt)
            bfr[nt] = frag32(lsB, wn * NT * 16 + nt * 16 + l16, quad);
        #pragma unroll
        for (int mt = 0; mt < 4; ++mt)
            #pragma unroll
            for (int nt = 0; nt < NT; ++nt)
                acc[mt][nt] = __builtin_amdgcn_mfma_f32_16x16x32_bf16(
                    af[mt], bfr[nt], acc[mt][nt], 0, 0, 0);

        __syncthreads();                 // prefetch landed; publish
    }
}

// ---------------------------------------------------------------------------
// qkv GEMM: 128x128 / 576 blocks, BK=32 body, 34.8 KB LDS, 3 blocks/CU
// (r13-verified). XCD m-strip swizzle + single-pass retile epilogue.
// ---------------------------------------------------------------------------
__global__ __launch_bounds__(256, 3) void gemm_qkv_mfma(
    const ushort* __restrict__ Xb, const ushort* __restrict__ Wt,
    ushort* __restrict__ Qb, ushort* __restrict__ Kb, ushort* __restrict__ Vt)
{
    // bufs: 2 x 8192 ushorts (32 KB) | epilogue retile [128][136] = 17408
    __shared__ __align__(16) ushort ls[17408];   // 34.8 KB
    const int lin = blockIdx.x + blockIdx.y * 18;     // dispatch-linear id
    const int w   = (lin & 7) * 72 + (lin >> 3);      // bijective XCD chunking
    const int m0  = (w / 18) * 128;
    const int n0  = (w % 18) * 128;

    floatx4 acc[4][4] = {};
    gemm_body_2ph32<4>(Xb, Wt, DMODEL, m0, n0, acc, ls);

    const int tid  = threadIdx.x;
    const int lane = tid & 63;
    const int wave = tid >> 6;
    const int wm = wave >> 1, wn = wave & 1;
    const int quad = lane >> 4, l16 = lane & 15;

    if (n0 < 2 * DMODEL) {
        // ---- Q or K: single pass over all 128 rows ----
        const float scale = (n0 < DMODEL) ? QSCALE_LOG2E : 1.0f;
        ushort* outp = (n0 < DMODEL) ? Qb : Kb;
        const int colg = (n0 < DMODEL) ? n0 : n0 - DMODEL;
        __syncthreads();                    // all waves done with GEMM tiles
        #pragma unroll
        for (int mt = 0; mt < 4; ++mt)
            #pragma unroll
            for (int nt = 0; nt < 4; ++nt) {
                const int row = wm * 64 + mt * 16 + quad * 4;
                const int col = wn * 64 + nt * 16 + l16;
                #pragma unroll
                for (int r = 0; r < 4; ++r)
                    ls[(row + r) * 136 + col] = f2bf(acc[mt][nt][r] * scale);
            }
        __syncthreads();
        #pragma unroll
        for (int p2 = 0; p2 < 8; ++p2) {
            const int row = (tid >> 4) + p2 * 16;
            const int c8  = (tid & 15) * 8;
            *(uint4*)(outp + (size_t)(m0 + row) * DMODEL + colg + c8) =
                *(const uint4*)(ls + row * 136 + c8);
        }
    } else {
        // ---- V transposed: single pass over all 128 hd-rows ----
        const int hd0 = n0 - 2 * DMODEL;
        __syncthreads();
        #pragma unroll
        for (int mt = 0; mt < 4; ++mt)
            #pragma unroll
            for (int nt = 0; nt < 4; ++nt) {
                const int hd  = wn * 64 + nt * 16 + l16;
                const int tok = wm * 64 + mt * 16 + quad * 4;
                #pragma unroll
                for (int r = 0; r < 4; ++r)
                    ls[hd * 136 + tok + r] = f2bf(acc[mt][nt][r]);
            }
        __syncthreads();
        #pragma unroll
        for (int p2 = 0; p2 < 8; ++p2) {
            const int row = (tid >> 4) + p2 * 16;    // local hd
            const int c8  = (tid & 15) * 8;          // token chunk
            *(uint4*)(Vt + (size_t)(hd0 + row) * TOKENS + m0 + c8) =
                *(const uint4*)(ls + row * 136 + c8);
        }
    }
}

// ---------------------------------------------------------------------------
// proj GEMM: 128x64 tiles, XCD m-strip swizzle, 2ph BK=64 (r11-verified).
// ---------------------------------------------------------------------------
__global__ __launch_bounds__(256) void gemm_proj_mfma(
    const ushort* __restrict__ Ab, const ushort* __restrict__ Wt,
    const float* __restrict__ bias, float* __restrict__ out)
{
    __shared__ __align__(16) ushort ls[24576];   // 48 KB: 2 x 24 KB tile bufs
    const int lin = blockIdx.x + blockIdx.y * 12;
    const int w   = (lin & 7) * 48 + (lin >> 3);
    const int m0  = (w / 12) * 128;
    const int n0  = (w % 12) * 64;

    floatx4 acc[4][2] = {};
    gemm_body_2ph<2>(Ab, Wt, DMODEL, m0, n0, acc, ls);

    const int lane = threadIdx.x & 63;
    const int wave = threadIdx.x >> 6;
    const int wm = wave >> 1, wn = wave & 1;
    const int quad = lane >> 4, l16 = lane & 15;
    const int row0 = m0 + wm * 64 + quad * 4;
    const int col0 = n0 + wn * 32;

    #pragma unroll
    for (int nt = 0; nt < 2; ++nt) {
        const int col = col0 + nt * 16 + l16;
        const float bv = bias[col];
        #pragma unroll
        for (int mt = 0; mt < 4; ++mt)
            #pragma unroll
            for (int r = 0; r < 4; ++r)
                out[(size_t)(row0 + mt * 16 + r) * DMODEL + col] =
                    acc[mt][nt][r] + bv;
    }
}

// ---------------------------------------------------------------------------
// MFMA flash attention — r13/r15-verified kernel VERBATIM (77.5us).
//
// The counted-vmcnt loop body is correctness-frozen (r8/r16: two
// paper-identical scheduling edits silently corrupted results). ~77us is
// this design's floor (6x probed) AND its edit boundary.
// ---------------------------------------------------------------------------
__global__ __launch_bounds__(256, 3) void attn_mfma_kernel(
    const ushort* __restrict__ Qb, const ushort* __restrict__ Kb,
    const ushort* __restrict__ Vt, ushort* __restrict__ attn_out)
{
    // main loop: 4 waves x 6144 ushorts (K0,K1 @0,1024; V0..V3 @2048+s*1024)
    // epilogue:  3 x [64][66] f32 + 192 f32 = 12864 floats = 25728 ushorts
    __shared__ __align__(16) ushort lds[25728];   // 51.5 KB

    const int tid  = threadIdx.x;
    const int wave = tid >> 6;
    const int lane = tid & 63;
    const int quad = lane >> 4;
    const int l16  = lane & 15;

    // XCD head-locality swizzle (bijective: 768 = 8 XCDs x 96 blocks)
    const int lin = blockIdx.x + blockIdx.y * 64;    // dispatch-linear id
    const int wsw = (lin & 7) * 96 + (lin >> 3);     // chunked per-XCD remap
    const int h   = wsw >> 6;                        // head 0..11
    const int i0  = (wsw & 63) * 64;                 // query-tile base

    // Q fragments: all 4 q-tiles register-resident (B-operand: col=l16)
    bf16x8 qf[4][2];
    #pragma unroll
    for (int jt = 0; jt < 4; ++jt) {
        const ushort* qb = Qb + (size_t)(i0 + jt * 16 + l16) * DMODEL + h * HDIM;
        qf[jt][0] = *(const bf16x8*)(qb + quad * 8);
        qf[jt][1] = *(const bf16x8*)(qb + 32 + quad * 8);
    }

    bf16x8 ones;
    #pragma unroll
    for (int i = 0; i < 8; ++i) ones[i] = (short)0x3F80;   // bf16 1.0

    floatx4 O[4][4] = {};    // [q-tile][d-tile], partial over this wave's keys
    floatx4 Ol[4]   = {};    // [q-tile] partial row-sums

    ushort* wls = lds + wave * 6144;                 // private region

    // K staging source (3-bit XOR chunk pre-swizzle; wave's key = t*64+wave*16+row)
    const int lrow8 = lane >> 3;                     // 0..7
    const int csw8  = ((lane & 7) ^ lrow8) * 8;
    const ushort* gK0 = Kb + (size_t)(wave * 16 + lrow8) * DMODEL + h * HDIM + csw8;
    const ushort* gK1 = gK0 + (size_t)8 * DMODEL;

    // V staging source: lane -> d=lane>>1, PHYSICAL tok-pair=lane&1 holds
    // LOGICAL pair (lane&1)^((d>>2)&1) = (lane&1)^((lane>>3)&1)
    const ushort* gV0 = Vt + (size_t)(h * HDIM + (lane >> 1)) * TOKENS
                           + wave * 16 + (((lane & 1) ^ ((lane >> 3) & 1)) * 8);
    const ushort* gV1 = gV0 + (size_t)32 * TOKENS;

    // V read offset (loop-invariant): logical pair quad>>1 of row nt*16+l16
    // sits at physical pair (quad>>1)^((l16>>2)&1); 8B half = quad&1
    const int vo = ((quad >> 1) ^ ((l16 >> 2) & 1)) * 8 + (quad & 1) * 4;

    // persistent P operand, packed across an even/odd chunk pair
    union { bf16x8 v; unsigned u[4]; } pa[4];

    // prologue: stage t=0 (K -> buf0, V -> slot0); 4 DMA outstanding
    gl2lds16(gK0, wls);
    gl2lds16(gK1, wls + 512);
    gl2lds16(gV0, wls + 2048);
    gl2lds16(gV1, wls + 2048 + 512);

    for (int u = 0; u < 32; ++u) {                   // pair u: t0=2u, t1=2u+1
        const int s0 = (u & 1) << 1;                 // V slot of t0 (0 or 2)
        ushort* Kc0 = wls;
        ushort* Kc1 = wls + 1024;
        ushort* V0  = wls + 2048 + s0 * 1024;
        ushort* V1  = wls + 2048 + (s0 + 1) * 1024;
        ushort* Vn  = wls + 2048 + ((s0 + 2) & 3) * 1024;

        // ======== t0 = 2u (even): prefetch t1, QK on Kc0 -> pa low half ====
        {
            const size_t t1 = (size_t)(2 * u + 1) * 64;
            gl2lds16(gK0 + t1 * DMODEL, Kc1);
            gl2lds16(gK1 + t1 * DMODEL, Kc1 + 512);
            gl2lds16(gV0 + t1, V1);
            gl2lds16(gV1 + t1, V1 + 512);
        }
        asm volatile("s_waitcnt vmcnt(4)" ::: "memory");   // t0's 4 DMA done

        {
            const bf16x8 a0 = frag(Kc0, l16, quad);
            const bf16x8 a1 = frag(Kc0, l16, 4 + quad);
            __builtin_amdgcn_s_setprio(1);
            #pragma unroll
            for (int jt = 0; jt < 4; ++jt) {
                floatx4 s = {0.f, 0.f, 0.f, 0.f};
                s = __builtin_amdgcn_mfma_f32_16x16x32_bf16(a0, qf[jt][0], s, 0, 0, 0);
                s = __builtin_amdgcn_mfma_f32_16x16x32_bf16(a1, qf[jt][1], s, 0, 0, 0);
                pa[jt].u[0] = cvt_pk_bf16(__builtin_amdgcn_exp2f(s[0]),
                                          __builtin_amdgcn_exp2f(s[1]));
                pa[jt].u[1] = cvt_pk_bf16(__builtin_amdgcn_exp2f(s[2]),
                                          __builtin_amdgcn_exp2f(s[3]));
            }
            __builtin_amdgcn_s_setprio(0);
        }

        // ======== t1 = 2u+1 (odd): prefetch next t0, QK on Kc1 -> pa high,
        //          then PV + Ol over the 32-key pair ========================
        if (u < 31) {
            const size_t t2 = (size_t)(2 * u + 2) * 64;
            gl2lds16(gK0 + t2 * DMODEL, Kc0);
            gl2lds16(gK1 + t2 * DMODEL, Kc0 + 512);
            gl2lds16(gV0 + t2, Vn);
            gl2lds16(gV1 + t2, Vn + 512);
            asm volatile("s_waitcnt vmcnt(4)" ::: "memory");  // t1's 4 DMA done
        } else {
            asm volatile("s_waitcnt vmcnt(0)" ::: "memory");
        }

        {
            const bf16x8 a0 = frag(Kc1, l16, quad);
            const bf16x8 a1 = frag(Kc1, l16, 4 + quad);
            __builtin_amdgcn_s_setprio(1);
            #pragma unroll
            for (int jt = 0; jt < 4; ++jt) {
                floatx4 s = {0.f, 0.f, 0.f, 0.f};
                s = __builtin_amdgcn_mfma_f32_16x16x32_bf16(a0, qf[jt][0], s, 0, 0, 0);
                s = __builtin_amdgcn_mfma_f32_16x16x32_bf16(a1, qf[jt][1], s, 0, 0, 0);
                pa[jt].u[2] = cvt_pk_bf16(__builtin_amdgcn_exp2f(s[0]),
                                          __builtin_amdgcn_exp2f(s[1]));
                pa[jt].u[3] = cvt_pk_bf16(__builtin_amdgcn_exp2f(s[2]),
                                          __builtin_amdgcn_exp2f(s[3]));
            }
            __builtin_amdgcn_s_setprio(0);
        }

        __builtin_amdgcn_s_setprio(1);
        #pragma unroll
        for (int nt = 0; nt < 4; ++nt) {
            const int ro = (nt * 16 + l16) * 16 + vo;   // pair-swizzled slot
            union { bf16x8 v; uint2 d[2]; } vu;
            vu.d[0] = *(const uint2*)(V0 + ro);   // even-chunk tokens (k-slots 0-3)
            vu.d[1] = *(const uint2*)(V1 + ro);   // odd-chunk tokens  (k-slots 4-7)
            #pragma unroll
            for (int jt = 0; jt < 4; ++jt)
                O[jt][nt] = __builtin_amdgcn_mfma_f32_16x16x32_bf16(
                    pa[jt].v, vu.v, O[jt][nt], 0, 0, 0);
        }
        #pragma unroll
        for (int jt = 0; jt < 4; ++jt)
            Ol[jt] = __builtin_amdgcn_mfma_f32_16x16x32_bf16(
                pa[jt].v, ones, Ol[jt], 0, 0, 0);
        __builtin_amdgcn_s_setprio(0);
    }

    // ---- cross-wave reduction + store (proven 4-way epilogue) ----
    __syncthreads();                       // all compute done, LDS reusable
    float* Of  = (float*)lds;              // 3 regions of [64][66] f32
    float* Olf = ((float*)lds) + 3 * 64 * 66;   // 3 x [64] f32
    if (wave != 0) {
        const int rg = (wave - 1) * 64 * 66;
        #pragma unroll
        for (int jt = 0; jt < 4; ++jt) {
            #pragma unroll
            for (int nt = 0; nt < 4; ++nt)
                #pragma unroll
                for (int r = 0; r < 4; ++r)
                    Of[rg + (jt * 16 + quad * 4 + r) * 66 + nt * 16 + l16] = O[jt][nt][r];
            if (l16 == 0) {
                #pragma unroll
                for (int r = 0; r < 4; ++r)
                    Olf[(wave - 1) * 64 + jt * 16 + quad * 4 + r] = Ol[jt][r];
            }
        }
    }
    __syncthreads();
    if (wave == 0) {
        #pragma unroll
        for (int jt = 0; jt < 4; ++jt) {
            const int qr = jt * 16 + quad * 4;
            float linv[4];
            #pragma unroll
            for (int r = 0; r < 4; ++r) {
                const float l = Ol[jt][r] + Olf[qr + r] + Olf[64 + qr + r]
                              + Olf[128 + qr + r];
                linv[r] = __builtin_amdgcn_rcpf(l);
            }
            #pragma unroll
            for (int nt = 0; nt < 4; ++nt) {
                const int d = h * HDIM + nt * 16 + l16;
                #pragma unroll
                for (int r = 0; r < 4; ++r) {
                    const float o = O[jt][nt][r]
                        + Of[(qr + r) * 66 + nt * 16 + l16]
                        + Of[64 * 66 + (qr + r) * 66 + nt * 16 + l16]
                        + Of[2 * 64 * 66 + (qr + r) * 66 + nt * 16 + l16];
                    attn_out[(size_t)(i0 + qr + r) * DMODEL + d] = f2bf(o * linv[r]);
                }
            }
        }
    }
}

// ---------------------------------------------------------------------------
extern "C" void kernel_launch(void* const* d_in, const int* in_sizes, int n_in,
                              void* d_out, int out_size, void* d_ws, size_t ws_size,
                              hipStream_t stream)
{
    const float* x     = (const float*)d_in[0];
    const float* Wqkv  = (const float*)d_in[1];
    const float* Wproj = (const float*)d_in[2];
    const float* bproj = (const float*)d_in[3];
    float* out = (float*)d_out;

    ushort* Xb     = (ushort*)d_ws;                          // [4096][768]
    ushort* WqkvT  = Xb    + (size_t)TOKENS * DMODEL;        // [2304][768]
    ushort* WprojT = WqkvT + (size_t)QKV_N * DMODEL;         // [768][768]
    ushort* Qb     = WprojT + (size_t)DMODEL * DMODEL;       // [4096][768]
    ushort* Kb     = Qb    + (size_t)TOKENS * DMODEL;        // [4096][768]
    ushort* Vt     = Kb    + (size_t)TOKENS * DMODEL;        // [768][4096]
    ushort* attn   = Vt    + (size_t)TOKENS * DMODEL;        // [4096][768]

    prep_kernel<<<dim3(3840), 256, 0, stream>>>(
        x, Wqkv, Wproj, Xb, WqkvT, WprojT);

    gemm_qkv_mfma<<<dim3(QKV_N / 128, TOKENS / 128), 256, 0, stream>>>(
        Xb, WqkvT, Qb, Kb, Vt);

    attn_mfma_kernel<<<dim3(TOKENS / 64, NHEADS), 256, 0, stream>>>(
        Qb, Kb, Vt, attn);

    gemm_proj_mfma<<<dim3(DMODEL / 64, TOKENS / 128), 256, 0, stream>>>(
        attn, WprojT, bproj, out);
}